// Round 1
// 2290.201 us; speedup vs baseline: 2.0735x; 2.0735x over previous
//
#include <hip/hip_runtime.h>
#include <hip/hip_bf16.h>
#include <math.h>

constexpr int LYR = 6;
constexpr int E   = 768;
constexpr int NH  = 12;
constexpr int FFD = 3072;
constexpr int HD  = 64;
constexpr int BB  = 2;
constexpr int SS  = 1024;
constexpr int T   = BB * SS;     // 2048 tokens
constexpr int E3  = 3 * E;       // 2304
constexpr int FH  = FFD / 2;     // 1536 (FFN slice width, legacy fast path)

#define LN_EPS 1e-5f

typedef __attribute__((ext_vector_type(8))) short    short8v;
typedef __attribute__((ext_vector_type(8))) unsigned short ushort8v;
typedef __attribute__((ext_vector_type(4))) unsigned short ushort4v;
typedef __attribute__((ext_vector_type(4))) float    f32x4;

__device__ __forceinline__ float bf2f(__hip_bfloat16 x) { return __bfloat162float(x); }
__device__ __forceinline__ float bfr2f(unsigned short u) {
    union { unsigned int i; float f; } v; v.i = ((unsigned int)u) << 16; return v.f;
}
__device__ __forceinline__ __hip_bfloat16 f2bf(float f) { return __float2bfloat16(f); }
// bf16 bits with round-to-nearest-even (finite inputs only)
__device__ __forceinline__ unsigned short f2bfbits(float f) {
    union { float f; unsigned int i; } v; v.f = f;
    unsigned int r = (v.i + 0x7fffu + ((v.i >> 16) & 1u)) >> 16;
    return (unsigned short)r;
}

// ---------------- block reductions (256 threads = 4 waves of 64) ----------------
__device__ __forceinline__ float block_sum(float v, float* sm) {
    #pragma unroll
    for (int o = 32; o > 0; o >>= 1) v += __shfl_down(v, o, 64);
    int lane = threadIdx.x & 63, wid = threadIdx.x >> 6;
    if (lane == 0) sm[wid] = v;
    __syncthreads();
    float r = sm[0] + sm[1] + sm[2] + sm[3];
    __syncthreads();
    return r;
}

__device__ __forceinline__ float block_max(float v, float* sm) {
    #pragma unroll
    for (int o = 32; o > 0; o >>= 1) v = fmaxf(v, __shfl_down(v, o, 64));
    int lane = threadIdx.x & 63, wid = threadIdx.x >> 6;
    if (lane == 0) sm[wid] = v;
    __syncthreads();
    float r = fmaxf(fmaxf(sm[0], sm[1]), fmaxf(sm[2], sm[3]));
    __syncthreads();
    return r;
}

// ---------------- f32 copy (embeddings -> residual stream), float4 ----------------
__global__ void copy4_kernel(const float4* __restrict__ in, float4* __restrict__ out, int n4) {
    int i = blockIdx.x * 256 + threadIdx.x;
    if (i < n4) out[i] = in[i];
}

// ---------------- per-row LN stats: musig[row] = (mu, rstd)  (legacy fast path) ---
__global__ void rowstat_kernel(const float* __restrict__ x, float2* __restrict__ musig) {
    __shared__ float sm[4];
    int row = blockIdx.x;
    const float* xr = x + (size_t)row * E;
    float s = 0.f;
    for (int i = threadIdx.x; i < E; i += 256) s += xr[i];
    float mu = block_sum(s, sm) * (1.0f / E);
    float v = 0.f;
    for (int i = threadIdx.x; i < E; i += 256) { float d = xr[i] - mu; v += d * d; }
    float rstd = rsqrtf(block_sum(v, sm) * (1.0f / E) + LN_EPS);
    if (threadIdx.x == 0) musig[row] = make_float2(mu, rstd);
}

// ---------------- LayerNorm: one block per row; x f32 -> out bf16 or f32 --------
template <typename OT>
__global__ void ln_kernel(const float* __restrict__ x, OT* __restrict__ out,
                          const float* __restrict__ g, const float* __restrict__ b) {
    __shared__ float sm[4];
    int row = blockIdx.x;
    const float* xr = x + (size_t)row * E;
    float s = 0.f;
    for (int i = threadIdx.x; i < E; i += 256) s += xr[i];
    float mu = block_sum(s, sm) * (1.0f / E);
    float v = 0.f;
    for (int i = threadIdx.x; i < E; i += 256) { float d = xr[i] - mu; v += d * d; }
    float rstd = rsqrtf(block_sum(v, sm) * (1.0f / E) + LN_EPS);
    for (int i = threadIdx.x; i < E; i += 256) {
        float o = (xr[i] - mu) * rstd * g[i] + b[i];
        if constexpr (sizeof(OT) == 2) out[(size_t)row * E + i] = f2bf(o);
        else                           out[(size_t)row * E + i] = o;
    }
}

// =================================================================================
// Weight transpose+convert: W f32 [K][N] (row-major, n contiguous)
//                        -> Wt bf16 bits [N][K] (k contiguous)
// 32x32 LDS tile, 256 threads. K%32==0, N%32==0.
// =================================================================================
__global__ void transpose_cvt(const float* __restrict__ W, unsigned short* __restrict__ Wt,
                              int K, int N) {
    __shared__ float tile[32][33];
    int n0 = blockIdx.x * 32, k0 = blockIdx.y * 32;
    int tx = threadIdx.x & 31, ty = threadIdx.x >> 5;   // ty 0..7
    #pragma unroll
    for (int i = 0; i < 4; i++)
        tile[ty + i * 8][tx] = W[(size_t)(k0 + ty + i * 8) * N + n0 + tx];
    __syncthreads();
    #pragma unroll
    for (int i = 0; i < 4; i++)
        Wt[(size_t)(n0 + ty + i * 8) * K + k0 + tx] = f2bfbits(tile[tx][ty + i * 8]);
}

// =================================================================================
// MFMA GEMM, both operands bf16, B pre-transposed: C[M,N] = A @ Bt^T + epilogue.
//   A  : bf16 bits [M][lda]   (k contiguous)
//   Bt : bf16 bits [N][ldb]   (k contiguous; ldb == K)
// Tile BM x BN, BK=64, 256 threads (4 waves, 2x2 over the tile).
// LDS rows padded to 80 ushorts (160 B): 16B-aligned for b128 AND bank-uniform
// (dword bank span (8*ln16 + 4q) mod 32 -> exactly 8 lanes per 4-bank span = floor).
//   FUSE 0: C = A@B + bias                 -> bf16 bits C
//   FUSE 1: C = gelu(A@B + bias)           -> bf16 bits C
//   FUSE 2: C = C + A@B + bias             -> f32 C (in-place residual)
// Requires M%BM==0, N%BN==0, K%64==0.
// =================================================================================
template <int FUSE, int BM, int BN>
__global__ __launch_bounds__(256) void gemm_bt(
        const unsigned short* __restrict__ A, int lda,
        const unsigned short* __restrict__ Bt, int ldb,
        const float* __restrict__ bias,
        void* __restrict__ Cptr, int ldc, int K) {
    constexpr int PAD = 80;                       // ushorts per LDS row
    constexpr int MFR = BM / 32, NFR = BN / 32;   // 16x16 frags per wave (m, n)
    constexpr int AIT = BM / 32, BIT = BN / 32;   // staging iters (256 thr x 8 elems)
    __shared__ unsigned short As[BM * PAD];
    __shared__ unsigned short Bs[BN * PAD];

    int tid = threadIdx.x;
    int bm = blockIdx.y * BM, bn = blockIdx.x * BN;
    int w = tid >> 6, lane = tid & 63, ln16 = lane & 15, q = lane >> 4;
    int wm = (w & 1) * (BM / 2), wn = (w >> 1) * (BN / 2);

    f32x4 acc[MFR][NFR];
    #pragma unroll
    for (int i = 0; i < MFR; i++)
        #pragma unroll
        for (int j = 0; j < NFR; j++) acc[i][j] = (f32x4){0.f, 0.f, 0.f, 0.f};

    for (int k0 = 0; k0 < K; k0 += 64) {
        // ---- stage A (pure bf16 copies, 16B ld / 16B LDS st) ----
        #pragma unroll
        for (int i = 0; i < AIT; i++) {
            int idx = tid + i * 256;
            int row = idx >> 3, ko = (idx & 7) * 8;
            *(ushort8v*)(&As[row * PAD + ko]) =
                *(const ushort8v*)(A + (size_t)(bm + row) * lda + k0 + ko);
        }
        // ---- stage B ----
        #pragma unroll
        for (int i = 0; i < BIT; i++) {
            int idx = tid + i * 256;
            int row = idx >> 3, ko = (idx & 7) * 8;
            *(ushort8v*)(&Bs[row * PAD + ko]) =
                *(const ushort8v*)(Bt + (size_t)(bn + row) * ldb + k0 + ko);
        }
        __syncthreads();

        // ---- fragments + MFMA, two k-halves of 32 ----
        #pragma unroll
        for (int kk = 0; kk < 64; kk += 32) {
            short8v afr[MFR], bfr[NFR];
            #pragma unroll
            for (int i = 0; i < MFR; i++)
                afr[i] = *(const short8v*)(&As[(wm + i * 16 + ln16) * PAD + kk + q * 8]);
            #pragma unroll
            for (int j = 0; j < NFR; j++)
                bfr[j] = *(const short8v*)(&Bs[(wn + j * 16 + ln16) * PAD + kk + q * 8]);
            #pragma unroll
            for (int i = 0; i < MFR; i++)
                #pragma unroll
                for (int j = 0; j < NFR; j++)
                    acc[i][j] = __builtin_amdgcn_mfma_f32_16x16x32_bf16(afr[i], bfr[j], acc[i][j], 0, 0, 0);
        }
        __syncthreads();
    }

    // ---- epilogue ----
    #pragma unroll
    for (int j = 0; j < NFR; j++) {
        int col = bn + wn + j * 16 + ln16;
        float bv = bias[col];
        #pragma unroll
        for (int i = 0; i < MFR; i++) {
            #pragma unroll
            for (int r = 0; r < 4; r++) {
                int row = bm + wm + i * 16 + q * 4 + r;
                float v = acc[i][j][r] + bv;
                if (FUSE == 1) v = 0.5f * v * (1.0f + erff(v * 0.70710678118654752f));
                if (FUSE == 0 || FUSE == 1) {
                    ((unsigned short*)Cptr)[(size_t)row * ldc + col] = f2bfbits(v);
                } else {
                    ((float*)Cptr)[(size_t)row * ldc + col] += v;
                }
            }
        }
    }
}

// =================================================================================
// Legacy fast-path MFMA GEMM (f32 weights converted in-kernel) — fallback only.
// =================================================================================
template <int AMODE, int FUSE>
__global__ void gemm_mfma(const void* __restrict__ Aptr, int lda,
                          const float* __restrict__ W, int ldw,
                          const float* __restrict__ bias,
                          const float2* __restrict__ musig,
                          const float* __restrict__ lng, const float* __restrict__ lnb,
                          void* __restrict__ Cptr, int ldc, int K) {
    __shared__ unsigned short As[128 * 40];
    __shared__ unsigned short Bs[32 * 130];

    int tid = threadIdx.x;
    int bm = blockIdx.y * 128, bn = blockIdx.x * 128;
    int w = tid >> 6, lane = tid & 63, ln16 = lane & 15, q = lane >> 4;
    int wm = (w & 1) * 64, wn = (w >> 1) * 64;

    f32x4 acc[4][4];
    #pragma unroll
    for (int i = 0; i < 4; i++)
        #pragma unroll
        for (int j = 0; j < 4; j++) acc[i][j] = (f32x4){0.f, 0.f, 0.f, 0.f};

    for (int k0 = 0; k0 < K; k0 += 32) {
        if (AMODE == 0) {
            const unsigned short* A = (const unsigned short*)Aptr;
            #pragma unroll
            for (int i = 0; i < 2; i++) {
                int idx = tid + i * 256;
                int row = idx >> 2, ko = (idx & 3) * 8;
                ushort8v v = *(const ushort8v*)(A + (size_t)(bm + row) * lda + k0 + ko);
                *(ushort8v*)(&As[row * 40 + ko]) = v;
            }
        } else {
            const float* A = (const float*)Aptr;
            #pragma unroll
            for (int i = 0; i < 4; i++) {
                int idx = tid + i * 256;
                int row = idx >> 3, ko = (idx & 7) * 4;
                float4 xv = *(const float4*)(A + (size_t)(bm + row) * lda + k0 + ko);
                float2 ms = musig[bm + row];
                float4 gv = *(const float4*)(lng + k0 + ko);
                float4 bv = *(const float4*)(lnb + k0 + ko);
                ushort4v o;
                o[0] = f2bfbits((xv.x - ms.x) * ms.y * gv.x + bv.x);
                o[1] = f2bfbits((xv.y - ms.x) * ms.y * gv.y + bv.y);
                o[2] = f2bfbits((xv.z - ms.x) * ms.y * gv.z + bv.z);
                o[3] = f2bfbits((xv.w - ms.x) * ms.y * gv.w + bv.w);
                *(ushort4v*)(&As[row * 40 + ko]) = o;
            }
        }
        #pragma unroll
        for (int i = 0; i < 16; i++) {
            int idx = tid + i * 256;
            int kr = idx >> 7, n = idx & 127;
            float wv = W[(size_t)(k0 + kr) * ldw + bn + n];
            Bs[kr * 130 + n] = f2bfbits(wv);
        }
        __syncthreads();

        short8v afr[4], bfr[4];
        #pragma unroll
        for (int i = 0; i < 4; i++)
            afr[i] = *(const short8v*)(&As[(wm + i * 16 + ln16) * 40 + q * 8]);
        #pragma unroll
        for (int j = 0; j < 4; j++) {
            int n = wn + j * 16 + ln16;
            #pragma unroll
            for (int jj = 0; jj < 8; jj++)
                bfr[j][jj] = (short)Bs[(q * 8 + jj) * 130 + n];
        }
        #pragma unroll
        for (int i = 0; i < 4; i++)
            #pragma unroll
            for (int j = 0; j < 4; j++)
                acc[i][j] = __builtin_amdgcn_mfma_f32_16x16x32_bf16(afr[i], bfr[j], acc[i][j], 0, 0, 0);
        __syncthreads();
    }

    #pragma unroll
    for (int j = 0; j < 4; j++) {
        int col = bn + wn + j * 16 + ln16;
        float bv = (FUSE == 3) ? 0.f : bias[col];
        #pragma unroll
        for (int i = 0; i < 4; i++) {
            #pragma unroll
            for (int r = 0; r < 4; r++) {
                int row = bm + wm + i * 16 + q * 4 + r;
                float v = acc[i][j][r] + bv;
                if (FUSE == 1) v = 0.5f * v * (1.0f + erff(v * 0.70710678118654752f));
                if (FUSE == 0 || FUSE == 1) {
                    ((unsigned short*)Cptr)[(size_t)row * ldc + col] = f2bfbits(v);
                } else {
                    float* C = (float*)Cptr;
                    C[(size_t)row * ldc + col] += v;
                }
            }
        }
    }
}

// =================================================================================
// Flash attention: one block per (b, h, 32-query tile); qkv bf16 bits [T][E3].
// Output written IN PLACE into the q-slot (cols h*64..h*64+63 of rows owned).
// =================================================================================
__global__ void attn_flash(unsigned short* __restrict__ qkv,
                           const float* __restrict__ mask) {
    __shared__ float Qs[32][68];
    __shared__ float Ks[64][68];
    __shared__ float Vs[64][68];
    __shared__ float Ps[32][68];

    int bid = blockIdx.x;                 // b(2) x h(12) x qt(32)
    int qt = bid & 31;
    int h  = (bid >> 5) % NH;
    int b  = bid / (32 * NH);
    int tid = threadIdx.x;
    int ql = tid >> 3, grp = tid & 7;

    #pragma unroll
    for (int i = 0; i < 8; i++) {
        int idx = tid + i * 256;
        int rq = idx >> 6, d = idx & 63;
        int grow = b * SS + qt * 32 + rq;
        Qs[rq][d] = bfr2f(qkv[(size_t)grow * E3 + h * HD + d]) * 0.125f;
    }

    float m_run = -1e30f, l_run = 0.f;
    float O[8] = {0.f, 0.f, 0.f, 0.f, 0.f, 0.f, 0.f, 0.f};

    for (int c = 0; c < 16; c++) {
        int j0 = c * 64;
        #pragma unroll
        for (int i = 0; i < 4; i++) {
            int idx = tid + i * 256;
            int jj = idx >> 4, d4 = (idx & 15) * 4;
            size_t base = (size_t)(b * SS + j0 + jj) * E3 + h * HD + d4;
            ushort4v kv = *(const ushort4v*)(qkv + base + E);
            ushort4v vv = *(const ushort4v*)(qkv + base + 2 * E);
            *(float4*)&Ks[jj][d4] = make_float4(bfr2f(kv[0]), bfr2f(kv[1]), bfr2f(kv[2]), bfr2f(kv[3]));
            *(float4*)&Vs[jj][d4] = make_float4(bfr2f(vv[0]), bfr2f(vv[1]), bfr2f(vv[2]), bfr2f(vv[3]));
        }
        __syncthreads();

        float s[8] = {0.f, 0.f, 0.f, 0.f, 0.f, 0.f, 0.f, 0.f};
        #pragma unroll
        for (int d0 = 0; d0 < 64; d0 += 4) {
            float4 q4 = *(const float4*)&Qs[ql][d0];
            #pragma unroll
            for (int jl = 0; jl < 8; jl++) {
                float4 k4 = *(const float4*)&Ks[grp + jl * 8][d0];
                s[jl] += q4.x * k4.x + q4.y * k4.y + q4.z * k4.z + q4.w * k4.w;
            }
        }
        #pragma unroll
        for (int jl = 0; jl < 8; jl++)
            s[jl] += (1.0f - mask[b * SS + j0 + grp + jl * 8]) * -10000.0f;

        float cm = s[0];
        #pragma unroll
        for (int jl = 1; jl < 8; jl++) cm = fmaxf(cm, s[jl]);
        cm = fmaxf(cm, __shfl_xor(cm, 1, 64));
        cm = fmaxf(cm, __shfl_xor(cm, 2, 64));
        cm = fmaxf(cm, __shfl_xor(cm, 4, 64));

        float mnew = fmaxf(m_run, cm);
        float alpha = __expf(m_run - mnew);
        float ps = 0.f;
        #pragma unroll
        for (int jl = 0; jl < 8; jl++) {
            float p = __expf(s[jl] - mnew);
            Ps[ql][grp + jl * 8] = p;
            ps += p;
        }
        ps += __shfl_xor(ps, 1, 64);
        ps += __shfl_xor(ps, 2, 64);
        ps += __shfl_xor(ps, 4, 64);
        l_run = l_run * alpha + ps;
        m_run = mnew;
        #pragma unroll
        for (int e = 0; e < 8; e++) O[e] *= alpha;

        #pragma unroll 4
        for (int jj = 0; jj < 64; jj++) {
            float p = Ps[ql][jj];
            float4 v0 = *(const float4*)&Vs[jj][grp * 8];
            float4 v1 = *(const float4*)&Vs[jj][grp * 8 + 4];
            O[0] += p * v0.x; O[1] += p * v0.y; O[2] += p * v0.z; O[3] += p * v0.w;
            O[4] += p * v1.x; O[5] += p * v1.y; O[6] += p * v1.z; O[7] += p * v1.w;
        }
        __syncthreads();
    }

    float inv = 1.0f / l_run;
    int grow = b * SS + qt * 32 + ql;
    size_t obase = (size_t)grow * E3 + h * HD + grp * 8;
    #pragma unroll
    for (int e = 0; e < 8; e++)
        qkv[obase + e] = f2bfbits(O[e] * inv);
}

// =================================================================================
// Legacy (R4-proven) kernels — deep fallback if workspace is tiny
// =================================================================================
template <int FUSE, typename CT>
__global__ void gemm_legacy(const __hip_bfloat16* __restrict__ A, int lda,
                            const float* __restrict__ W, int ldw,
                            const float* __restrict__ bias,
                            CT* __restrict__ C, int ldc,
                            const float* __restrict__ resid,
                            int M, int N, int K) {
    __shared__ float As[16][65];
    __shared__ float Bs[16][65];
    int bm = blockIdx.y * 64, bn = blockIdx.x * 64;
    int tid = threadIdx.x;
    int ty = tid >> 4, tx = tid & 15;
    int ar = tid >> 2, ak = (tid & 3) << 2;
    int wk = tid >> 4, wn = (tid & 15) << 2;

    float acc[4][4] = {};
    for (int k0 = 0; k0 < K; k0 += 16) {
        ushort4 av = *(const ushort4*)(A + (size_t)(bm + ar) * lda + k0 + ak);
        As[ak + 0][ar] = bfr2f(av.x);
        As[ak + 1][ar] = bfr2f(av.y);
        As[ak + 2][ar] = bfr2f(av.z);
        As[ak + 3][ar] = bfr2f(av.w);
        float4 wv = *(const float4*)(W + (size_t)(k0 + wk) * ldw + bn + wn);
        Bs[wk][wn + 0] = wv.x;
        Bs[wk][wn + 1] = wv.y;
        Bs[wk][wn + 2] = wv.z;
        Bs[wk][wn + 3] = wv.w;
        __syncthreads();
        #pragma unroll
        for (int kk = 0; kk < 16; kk++) {
            float a[4], bv[4];
            #pragma unroll
            for (int i = 0; i < 4; i++) { a[i] = As[kk][ty * 4 + i]; bv[i] = Bs[kk][tx * 4 + i]; }
            #pragma unroll
            for (int i = 0; i < 4; i++)
                #pragma unroll
                for (int j = 0; j < 4; j++) acc[i][j] += a[i] * bv[j];
        }
        __syncthreads();
    }
    #pragma unroll
    for (int i = 0; i < 4; i++) {
        int row = bm + ty * 4 + i;
        #pragma unroll
        for (int j = 0; j < 4; j++) {
            int col = bn + tx * 4 + j;
            float v = acc[i][j];
            if (FUSE != 3) v += bias[col];
            if (FUSE == 1) v = 0.5f * v * (1.0f + erff(v * 0.70710678118654752f));
            if (FUSE == 2 || FUSE == 3) v += resid[(size_t)row * ldc + col];
            if constexpr (sizeof(CT) == 2) C[(size_t)row * ldc + col] = f2bf(v);
            else                           C[(size_t)row * ldc + col] = v;
        }
    }
}

__global__ void attn_legacy(const __hip_bfloat16* __restrict__ qkv,
                            const float* __restrict__ mask,
                            __hip_bfloat16* __restrict__ out) {
    __shared__ float sc[SS];
    __shared__ float qv[HD];
    __shared__ float oacc[4][HD];
    __shared__ float redbuf[4];

    int q = blockIdx.x & (SS - 1);
    int h = blockIdx.x >> 10;
    int tid = threadIdx.x;

    const __hip_bfloat16* qrow = qkv + (size_t)q * E3 + h * HD;
    if (tid < HD) qv[tid] = bf2f(qrow[tid]) * 0.125f;
    __syncthreads();

    for (int j = tid; j < SS; j += 256) {
        const __hip_bfloat16* krow = qkv + (size_t)j * E3 + E + h * HD;
        float d = 0.f;
        #pragma unroll
        for (int t = 0; t < HD; t += 4) {
            ushort4 kv4 = *(const ushort4*)(krow + t);
            d += qv[t] * bfr2f(kv4.x) + qv[t + 1] * bfr2f(kv4.y)
               + qv[t + 2] * bfr2f(kv4.z) + qv[t + 3] * bfr2f(kv4.w);
        }
        d += (1.0f - mask[j]) * -10000.0f;
        sc[j] = d;
    }
    __syncthreads();

    float m = -1e30f;
    for (int j = tid; j < SS; j += 256) m = fmaxf(m, sc[j]);
    m = block_max(m, redbuf);
    float s = 0.f;
    for (int j = tid; j < SS; j += 256) { float e = __expf(sc[j] - m); sc[j] = e; s += e; }
    s = block_sum(s, redbuf);
    float inv = 1.0f / s;
    __syncthreads();

    int d = tid & 63, c = tid >> 6;
    float acc = 0.f;
    int j0 = c * 256;
    for (int j = j0; j < j0 + 256; j++) {
        const __hip_bfloat16* vrow = qkv + (size_t)j * E3 + 2 * E + h * HD;
        acc += sc[j] * bf2f(vrow[d]);
    }
    oacc[c][d] = acc;
    __syncthreads();
    if (tid < HD) {
        float o = (oacc[0][tid] + oacc[1][tid] + oacc[2][tid] + oacc[3][tid]) * inv;
        out[(size_t)q * E + h * HD + tid] = f2bf(o);
    }
}

__global__ void copy_kernel(const float* __restrict__ in, float* __restrict__ out, int n) {
    int i = blockIdx.x * 256 + threadIdx.x;
    if (i < n) out[i] = in[i];
}

// =================================================================================
extern "C" void kernel_launch(void* const* d_in, const int* in_sizes, int n_in,
                              void* d_out, int out_size, void* d_ws, size_t ws_size,
                              hipStream_t stream) {
    const float* emb   = (const float*)d_in[0];
    const float* mask  = (const float*)d_in[1];
    const float* Wqkv  = (const float*)d_in[2];
    const float* bqkv  = (const float*)d_in[3];
    const float* Wo    = (const float*)d_in[4];
    const float* bo    = (const float*)d_in[5];
    const float* ln1g  = (const float*)d_in[6];
    const float* ln1b  = (const float*)d_in[7];
    const float* ln2g  = (const float*)d_in[8];
    const float* ln2b  = (const float*)d_in[9];
    const float* Wfc   = (const float*)d_in[10];
    const float* bfc   = (const float*)d_in[11];
    const float* Wmo   = (const float*)d_in[12];
    const float* bmo   = (const float*)d_in[13];
    const float* lnfg  = (const float*)d_in[14];
    const float* lnfb  = (const float*)d_in[15];

    // fast2 path: x f32 [T][E] + h bf16 [T][E] + buf bf16 [T][FFD] (qkv/ff union)
    //           + weight scratch bf16 (max E*FFD)
    const size_t NEED_FAST2 = sizeof(float) * (size_t)T * E
                            + 2ull * (size_t)T * E
                            + 2ull * (size_t)T * FFD
                            + 2ull * (size_t)E * FFD;
    // fast path (previous session): x + qkv + musig
    const size_t NEED_FAST = sizeof(float) * (size_t)T * E
                           + 2ull * (size_t)T * E3
                           + sizeof(float2) * (size_t)T;

    if (ws_size >= NEED_FAST2) {
        // ---------------- FAST2 PATH: bf16 transposed weights ----------------
        float* x            = (float*)d_ws;
        unsigned short* h   = (unsigned short*)(x + (size_t)T * E);       // [T,E]
        unsigned short* buf = h + (size_t)T * E;                          // [T,FFD] union
        unsigned short* wt  = buf + (size_t)T * FFD;                      // [<=E*FFD]
        unsigned short* qkv = buf;                                        // [T,E3]
        unsigned short* ff  = buf;                                        // [T,FFD]

        copy4_kernel<<<dim3(T * E / 4 / 256), dim3(256), 0, stream>>>(
            (const float4*)emb, (float4*)x, T * E / 4);

        for (int l = 0; l < LYR; l++) {
            const float* wqkv_l = Wqkv + (size_t)l * E * E3;
            const float* wo_l   = Wo   + (size_t)l * E * E;
            const float* wfc_l  = Wfc  + (size_t)l * E * FFD;
            const float* wmo_l  = Wmo  + (size_t)l * FFD * E;

            // h = LN1(x)  (materialized once; removes per-tile LN recompute)
            ln_kernel<__hip_bfloat16><<<dim3(T), dim3(256), 0, stream>>>(
                x, (__hip_bfloat16*)h, ln1g + l * E, ln1b + l * E);
            // wt = Wqkv^T bf16; qkv = h @ Wqkv + bqkv
            transpose_cvt<<<dim3(E3 / 32, E / 32), dim3(256), 0, stream>>>(wqkv_l, wt, E, E3);
            gemm_bt<0, 128, 128><<<dim3(E3 / 128, T / 128), dim3(256), 0, stream>>>(
                h, E, wt, E, bqkv + l * E3, qkv, E3, E);
            // attention in-place (o -> q slot)
            attn_flash<<<dim3(BB * NH * 32), dim3(256), 0, stream>>>(qkv, mask);
            // x += attnout @ Wo + bo   (64x128 tile -> 192 blocks, better CU fill)
            transpose_cvt<<<dim3(E / 32, E / 32), dim3(256), 0, stream>>>(wo_l, wt, E, E);
            gemm_bt<2, 64, 128><<<dim3(E / 128, T / 64), dim3(256), 0, stream>>>(
                qkv, E3, wt, E, bo + l * E, x, E, E);

            // ---- FFN, full width (qkv dead; ff reuses buf) ----
            ln_kernel<__hip_bfloat16><<<dim3(T), dim3(256), 0, stream>>>(
                x, (__hip_bfloat16*)h, ln2g + l * E, ln2b + l * E);
            transpose_cvt<<<dim3(FFD / 32, E / 32), dim3(256), 0, stream>>>(wfc_l, wt, E, FFD);
            gemm_bt<1, 128, 128><<<dim3(FFD / 128, T / 128), dim3(256), 0, stream>>>(
                h, E, wt, E, bfc + l * FFD, ff, FFD, E);
            transpose_cvt<<<dim3(E / 32, FFD / 32), dim3(256), 0, stream>>>(wmo_l, wt, FFD, E);
            gemm_bt<2, 64, 128><<<dim3(E / 128, T / 64), dim3(256), 0, stream>>>(
                ff, FFD, wt, FFD, bmo + l * E, x, E, FFD);
        }
        ln_kernel<float><<<dim3(T), dim3(256), 0, stream>>>(x, (float*)d_out, lnfg, lnfb);
    } else if (ws_size >= NEED_FAST) {
        // ---------------- FAST PATH (previous session, proven) ----------------
        float* x              = (float*)d_ws;
        unsigned short* qkv   = (unsigned short*)(x + (size_t)T * E);
        float2* musig         = (float2*)(qkv + (size_t)T * E3);

        copy4_kernel<<<dim3(T * E / 4 / 256), dim3(256), 0, stream>>>(
            (const float4*)emb, (float4*)x, T * E / 4);

        for (int l = 0; l < LYR; l++) {
            const float* wqkv_l = Wqkv + (size_t)l * E * E3;
            const float* wo_l   = Wo   + (size_t)l * E * E;
            const float* wfc_l  = Wfc  + (size_t)l * E * FFD;
            const float* wmo_l  = Wmo  + (size_t)l * FFD * E;

            rowstat_kernel<<<dim3(T), dim3(256), 0, stream>>>(x, musig);
            gemm_mfma<1, 0><<<dim3(E3 / 128, T / 128), dim3(256), 0, stream>>>(
                x, E, wqkv_l, E3, bqkv + l * E3, musig, ln1g + l * E, ln1b + l * E,
                qkv, E3, E);
            attn_flash<<<dim3(BB * NH * 32), dim3(256), 0, stream>>>(qkv, mask);
            gemm_mfma<0, 2><<<dim3(E / 128, T / 128), dim3(256), 0, stream>>>(
                qkv, E3, wo_l, E, bo + l * E, nullptr, nullptr, nullptr, x, E, E);

            unsigned short* ffp = qkv;
            unsigned short* hp  = qkv + (size_t)T * FH;
            ln_kernel<__hip_bfloat16><<<dim3(T), dim3(256), 0, stream>>>(
                x, (__hip_bfloat16*)hp, ln2g + l * E, ln2b + l * E);
            for (int f = 0; f < 2; f++) {
                gemm_mfma<0, 1><<<dim3(FH / 128, T / 128), dim3(256), 0, stream>>>(
                    hp, E, wfc_l + f * FH, FFD, bfc + l * FFD + f * FH,
                    nullptr, nullptr, nullptr, ffp, FH, E);
                if (f == 0)
                    gemm_mfma<0, 3><<<dim3(E / 128, T / 128), dim3(256), 0, stream>>>(
                        ffp, FH, wmo_l + (size_t)f * FH * E, E, nullptr, nullptr, nullptr, nullptr,
                        x, E, FH);
                else
                    gemm_mfma<0, 2><<<dim3(E / 128, T / 128), dim3(256), 0, stream>>>(
                        ffp, FH, wmo_l + (size_t)f * FH * E, E, bmo + l * E, nullptr, nullptr, nullptr,
                        x, E, FH);
            }
        }
        ln_kernel<float><<<dim3(T), dim3(256), 0, stream>>>(x, (float*)d_out, lnfg, lnfb);
    } else {
        // ---------------- LEGACY PATH (R4-proven, 12.58 MB) ----------------
        float* x           = (float*)d_ws;
        __hip_bfloat16* hb = (__hip_bfloat16*)(x + (size_t)T * E);
        __hip_bfloat16* qb = hb + (size_t)SS * E;

        int n = T * E;
        copy_kernel<<<dim3((n + 255) / 256), dim3(256), 0, stream>>>(emb, x, n);

        for (int l = 0; l < LYR; l++) {
            const float* wqkv_l = Wqkv + (size_t)l * E * E3;
            const float* wo_l   = Wo   + (size_t)l * E * E;
            const float* wfc_l  = Wfc  + (size_t)l * E * FFD;
            const float* wmo_l  = Wmo  + (size_t)l * FFD * E;

            for (int b = 0; b < BB; b++) {
                float* xb = x + (size_t)b * SS * E;
                ln_kernel<__hip_bfloat16><<<dim3(SS), dim3(256), 0, stream>>>(
                    xb, hb, ln1g + l * E, ln1b + l * E);
                gemm_legacy<0, __hip_bfloat16><<<dim3(E3 / 64, SS / 64), dim3(256), 0, stream>>>(
                    hb, E, wqkv_l, E3, bqkv + l * E3, qb, E3, nullptr, SS, E3, E);
                attn_legacy<<<dim3(NH * SS), dim3(256), 0, stream>>>(qb, mask + b * SS, hb);
                gemm_legacy<2, float><<<dim3(E / 64, SS / 64), dim3(256), 0, stream>>>(
                    hb, E, wo_l, E, bo + l * E, xb, E, xb, SS, E, E);
            }
            for (int b = 0; b < BB; b++) {
                float* xb = x + (size_t)b * SS * E;
                ln_kernel<__hip_bfloat16><<<dim3(SS), dim3(256), 0, stream>>>(
                    xb, hb, ln2g + l * E, ln2b + l * E);
                for (int f = 0; f < 2; f++) {
                    gemm_legacy<1, __hip_bfloat16><<<dim3(FH / 64, SS / 64), dim3(256), 0, stream>>>(
                        hb, E, wfc_l + f * FH, FFD, bfc + l * FFD + f * FH, qb, FH, nullptr,
                        SS, FH, E);
                    if (f == 0)
                        gemm_legacy<3, float><<<dim3(E / 64, SS / 64), dim3(256), 0, stream>>>(
                            qb, FH, wmo_l + (size_t)f * FH * E, E, nullptr, xb, E, xb, SS, E, FH);
                    else
                        gemm_legacy<2, float><<<dim3(E / 64, SS / 64), dim3(256), 0, stream>>>(
                            qb, FH, wmo_l + (size_t)f * FH * E, E, bmo + l * E, xb, E, xb, SS, E, FH);
                }
            }
        }
        ln_kernel<float><<<dim3(T), dim3(256), 0, stream>>>(x, (float*)d_out, lnfg, lnfb);
    }
}

// Round 2
// 1723.305 us; speedup vs baseline: 2.7557x; 1.3290x over previous
//
#include <hip/hip_runtime.h>
#include <hip/hip_bf16.h>
#include <math.h>

constexpr int LYR = 6;
constexpr int E   = 768;
constexpr int NH  = 12;
constexpr int FFD = 3072;
constexpr int HD  = 64;
constexpr int BB  = 2;
constexpr int SS  = 1024;
constexpr int T   = BB * SS;     // 2048 tokens
constexpr int E3  = 3 * E;       // 2304
constexpr int FH  = FFD / 2;     // 1536 (FFN slice width, legacy fast path)

#define LN_EPS 1e-5f

typedef __attribute__((ext_vector_type(8))) short    short8v;
typedef __attribute__((ext_vector_type(8))) unsigned short ushort8v;
typedef __attribute__((ext_vector_type(4))) unsigned short ushort4v;
typedef __attribute__((ext_vector_type(4))) float    f32x4;

__device__ __forceinline__ float bf2f(__hip_bfloat16 x) { return __bfloat162float(x); }
__device__ __forceinline__ float bfr2f(unsigned short u) {
    union { unsigned int i; float f; } v; v.i = ((unsigned int)u) << 16; return v.f;
}
__device__ __forceinline__ __hip_bfloat16 f2bf(float f) { return __float2bfloat16(f); }
// bf16 bits with round-to-nearest-even (finite inputs only)
__device__ __forceinline__ unsigned short f2bfbits(float f) {
    union { float f; unsigned int i; } v; v.f = f;
    unsigned int r = (v.i + 0x7fffu + ((v.i >> 16) & 1u)) >> 16;
    return (unsigned short)r;
}

// ---------------- block reductions (256 threads = 4 waves of 64) ----------------
__device__ __forceinline__ float block_sum(float v, float* sm) {
    #pragma unroll
    for (int o = 32; o > 0; o >>= 1) v += __shfl_down(v, o, 64);
    int lane = threadIdx.x & 63, wid = threadIdx.x >> 6;
    if (lane == 0) sm[wid] = v;
    __syncthreads();
    float r = sm[0] + sm[1] + sm[2] + sm[3];
    __syncthreads();
    return r;
}

__device__ __forceinline__ float block_max(float v, float* sm) {
    #pragma unroll
    for (int o = 32; o > 0; o >>= 1) v = fmaxf(v, __shfl_down(v, o, 64));
    int lane = threadIdx.x & 63, wid = threadIdx.x >> 6;
    if (lane == 0) sm[wid] = v;
    __syncthreads();
    float r = fmaxf(fmaxf(sm[0], sm[1]), fmaxf(sm[2], sm[3]));
    __syncthreads();
    return r;
}

// ---------------- f32 copy (embeddings -> residual stream), float4 ----------------
__global__ void copy4_kernel(const float4* __restrict__ in, float4* __restrict__ out, int n4) {
    int i = blockIdx.x * 256 + threadIdx.x;
    if (i < n4) out[i] = in[i];
}

// ---------------- per-row LN stats: musig[row] = (mu, rstd)  (legacy fast path) ---
__global__ void rowstat_kernel(const float* __restrict__ x, float2* __restrict__ musig) {
    __shared__ float sm[4];
    int row = blockIdx.x;
    const float* xr = x + (size_t)row * E;
    float s = 0.f;
    for (int i = threadIdx.x; i < E; i += 256) s += xr[i];
    float mu = block_sum(s, sm) * (1.0f / E);
    float v = 0.f;
    for (int i = threadIdx.x; i < E; i += 256) { float d = xr[i] - mu; v += d * d; }
    float rstd = rsqrtf(block_sum(v, sm) * (1.0f / E) + LN_EPS);
    if (threadIdx.x == 0) musig[row] = make_float2(mu, rstd);
}

// ---------------- LayerNorm: one block per row; x f32 -> out bf16 or f32 --------
template <typename OT>
__global__ void ln_kernel(const float* __restrict__ x, OT* __restrict__ out,
                          const float* __restrict__ g, const float* __restrict__ b) {
    __shared__ float sm[4];
    int row = blockIdx.x;
    const float* xr = x + (size_t)row * E;
    float s = 0.f;
    for (int i = threadIdx.x; i < E; i += 256) s += xr[i];
    float mu = block_sum(s, sm) * (1.0f / E);
    float v = 0.f;
    for (int i = threadIdx.x; i < E; i += 256) { float d = xr[i] - mu; v += d * d; }
    float rstd = rsqrtf(block_sum(v, sm) * (1.0f / E) + LN_EPS);
    for (int i = threadIdx.x; i < E; i += 256) {
        float o = (xr[i] - mu) * rstd * g[i] + b[i];
        if constexpr (sizeof(OT) == 2) out[(size_t)row * E + i] = f2bf(o);
        else                           out[(size_t)row * E + i] = o;
    }
}

// =================================================================================
// Weight transpose+convert: W f32 [K][N] -> Wt bf16 bits [N][K]
// =================================================================================
__global__ void transpose_cvt(const float* __restrict__ W, unsigned short* __restrict__ Wt,
                              int K, int N) {
    __shared__ float tile[32][33];
    int n0 = blockIdx.x * 32, k0 = blockIdx.y * 32;
    int tx = threadIdx.x & 31, ty = threadIdx.x >> 5;   // ty 0..7
    #pragma unroll
    for (int i = 0; i < 4; i++)
        tile[ty + i * 8][tx] = W[(size_t)(k0 + ty + i * 8) * N + n0 + tx];
    __syncthreads();
    #pragma unroll
    for (int i = 0; i < 4; i++)
        Wt[(size_t)(n0 + ty + i * 8) * K + k0 + tx] = f2bfbits(tile[tx][ty + i * 8]);
}

// =================================================================================
// MFMA GEMM, both operands bf16, B pre-transposed: C[M,N] = A @ Bt^T + epilogue.
// (see Round-1 notes; LDS rows padded to 80 ushorts = 160B, conflict-floor b128)
//   FUSE 0: C = A@B + bias -> bf16 | 1: gelu(...) -> bf16 | 2: C += A@B + bias (f32)
// =================================================================================
template <int FUSE, int BM, int BN>
__global__ __launch_bounds__(256) void gemm_bt(
        const unsigned short* __restrict__ A, int lda,
        const unsigned short* __restrict__ Bt, int ldb,
        const float* __restrict__ bias,
        void* __restrict__ Cptr, int ldc, int K) {
    constexpr int PAD = 80;
    constexpr int MFR = BM / 32, NFR = BN / 32;
    constexpr int AIT = BM / 32, BIT = BN / 32;
    __shared__ unsigned short As[BM * PAD];
    __shared__ unsigned short Bs[BN * PAD];

    int tid = threadIdx.x;
    int bm = blockIdx.y * BM, bn = blockIdx.x * BN;
    int w = tid >> 6, lane = tid & 63, ln16 = lane & 15, q = lane >> 4;
    int wm = (w & 1) * (BM / 2), wn = (w >> 1) * (BN / 2);

    f32x4 acc[MFR][NFR];
    #pragma unroll
    for (int i = 0; i < MFR; i++)
        #pragma unroll
        for (int j = 0; j < NFR; j++) acc[i][j] = (f32x4){0.f, 0.f, 0.f, 0.f};

    for (int k0 = 0; k0 < K; k0 += 64) {
        #pragma unroll
        for (int i = 0; i < AIT; i++) {
            int idx = tid + i * 256;
            int row = idx >> 3, ko = (idx & 7) * 8;
            *(ushort8v*)(&As[row * PAD + ko]) =
                *(const ushort8v*)(A + (size_t)(bm + row) * lda + k0 + ko);
        }
        #pragma unroll
        for (int i = 0; i < BIT; i++) {
            int idx = tid + i * 256;
            int row = idx >> 3, ko = (idx & 7) * 8;
            *(ushort8v*)(&Bs[row * PAD + ko]) =
                *(const ushort8v*)(Bt + (size_t)(bn + row) * ldb + k0 + ko);
        }
        __syncthreads();

        #pragma unroll
        for (int kk = 0; kk < 64; kk += 32) {
            short8v afr[MFR], bfr[NFR];
            #pragma unroll
            for (int i = 0; i < MFR; i++)
                afr[i] = *(const short8v*)(&As[(wm + i * 16 + ln16) * PAD + kk + q * 8]);
            #pragma unroll
            for (int j = 0; j < NFR; j++)
                bfr[j] = *(const short8v*)(&Bs[(wn + j * 16 + ln16) * PAD + kk + q * 8]);
            #pragma unroll
            for (int i = 0; i < MFR; i++)
                #pragma unroll
                for (int j = 0; j < NFR; j++)
                    acc[i][j] = __builtin_amdgcn_mfma_f32_16x16x32_bf16(afr[i], bfr[j], acc[i][j], 0, 0, 0);
        }
        __syncthreads();
    }

    #pragma unroll
    for (int j = 0; j < NFR; j++) {
        int col = bn + wn + j * 16 + ln16;
        float bv = bias[col];
        #pragma unroll
        for (int i = 0; i < MFR; i++) {
            #pragma unroll
            for (int r = 0; r < 4; r++) {
                int row = bm + wm + i * 16 + q * 4 + r;
                float v = acc[i][j][r] + bv;
                if (FUSE == 1) v = 0.5f * v * (1.0f + erff(v * 0.70710678118654752f));
                if (FUSE == 0 || FUSE == 1) {
                    ((unsigned short*)Cptr)[(size_t)row * ldc + col] = f2bfbits(v);
                } else {
                    ((float*)Cptr)[(size_t)row * ldc + col] += v;
                }
            }
        }
    }
}

// =================================================================================
// MFMA flash attention: one block per (b, h, 64-query tile); 4 waves, 16 q-rows each.
// qkv bf16 bits [T][E3]; output written in place into the q-slot.
//   QK^T: A = Q frags (regs), B = K from LDS [j][d] (both k=d contiguous).
//   softmax: lane owns 4 q-rows x 16 j; shfl_xor over 16-lane group.
//   PV:   A = P from LDS [q][j] (bf16), B = V transposed in LDS Vt[d][j] (k=j contig).
// Same fragment convention as gemm_bt (harness-verified).
// =================================================================================
__global__ __launch_bounds__(256) void attn_mfma(unsigned short* __restrict__ qkv,
                                                 const float* __restrict__ mask) {
    constexpr int KP = 80;   // Ks row pitch (ushorts)
    constexpr int VP = 82;   // Vt row pitch
    constexpr int PP = 82;   // Ps row pitch
    __shared__ unsigned short Ks[64 * KP];
    __shared__ unsigned short Vt[64 * VP];
    __shared__ unsigned short Ps[64 * PP];
    __shared__ float Ms[64];

    int bid = blockIdx.x;                 // b(2) x h(12) x qt(16)
    int qt = bid & 15;
    int h  = (bid >> 4) % NH;
    int b  = bid / (16 * NH);
    int tid = threadIdx.x;
    int w = tid >> 6, lane = tid & 63, ln16 = lane & 15, q4 = lane >> 4;

    // Q fragments in registers: A-row = w*16 + ln16, k-chunks q4*8 (+0 / +32)
    int qrow = b * SS + qt * 64 + w * 16 + ln16;
    const unsigned short* qbase = qkv + (size_t)qrow * E3 + h * HD;
    short8v qfr0 = *(const short8v*)(qbase + q4 * 8);
    short8v qfr1 = *(const short8v*)(qbase + 32 + q4 * 8);

    f32x4 sacc[4];           // QK^T acc: 4 j-frags (cols jf*16+ln16, rows q4*4+r)
    f32x4 oacc[4];           // PV acc:   4 d-frags (cols df*16+ln16, rows q4*4+r)
    float m_run[4], l_run[4];
    #pragma unroll
    for (int r = 0; r < 4; r++) { m_run[r] = -1e30f; l_run[r] = 0.f; }
    #pragma unroll
    for (int i = 0; i < 4; i++) oacc[i] = (f32x4){0.f, 0.f, 0.f, 0.f};

    for (int t = 0; t < 16; t++) {
        int j0 = t * 64;
        // ---- stage K (vector rows) + V transposed (scalar) ----
        #pragma unroll
        for (int i = 0; i < 2; i++) {
            int idx = tid + i * 256;                  // 0..511
            int row = idx >> 3, ko = (idx & 7) * 8;   // j-row, d-chunk
            size_t gb = (size_t)(b * SS + j0 + row) * E3 + h * HD;
            *(ushort8v*)(&Ks[row * KP + ko]) = *(const ushort8v*)(qkv + gb + E + ko);
            ushort8v vv = *(const ushort8v*)(qkv + gb + 2 * E + ko);
            #pragma unroll
            for (int e = 0; e < 8; e++)
                Vt[(ko + e) * VP + row] = vv[e];
        }
        if (tid < 64) Ms[tid] = (1.0f - mask[b * SS + j0 + tid]) * -10000.0f;
        __syncthreads();

        // ---- QK^T ----
        #pragma unroll
        for (int jf = 0; jf < 4; jf++) sacc[jf] = (f32x4){0.f, 0.f, 0.f, 0.f};
        #pragma unroll
        for (int jf = 0; jf < 4; jf++) {
            short8v k0f = *(const short8v*)(&Ks[(jf * 16 + ln16) * KP + q4 * 8]);
            short8v k1f = *(const short8v*)(&Ks[(jf * 16 + ln16) * KP + 32 + q4 * 8]);
            sacc[jf] = __builtin_amdgcn_mfma_f32_16x16x32_bf16(qfr0, k0f, sacc[jf], 0, 0, 0);
            sacc[jf] = __builtin_amdgcn_mfma_f32_16x16x32_bf16(qfr1, k1f, sacc[jf], 0, 0, 0);
        }

        // ---- scale + mask ----
        float madd[4];
        #pragma unroll
        for (int jf = 0; jf < 4; jf++) madd[jf] = Ms[jf * 16 + ln16];
        #pragma unroll
        for (int jf = 0; jf < 4; jf++)
            #pragma unroll
            for (int r = 0; r < 4; r++)
                sacc[jf][r] = sacc[jf][r] * 0.125f + madd[jf];

        // ---- online softmax (per owned row r) ----
        #pragma unroll
        for (int r = 0; r < 4; r++) {
            float mx = fmaxf(fmaxf(sacc[0][r], sacc[1][r]), fmaxf(sacc[2][r], sacc[3][r]));
            mx = fmaxf(mx, __shfl_xor(mx, 1, 64));
            mx = fmaxf(mx, __shfl_xor(mx, 2, 64));
            mx = fmaxf(mx, __shfl_xor(mx, 4, 64));
            mx = fmaxf(mx, __shfl_xor(mx, 8, 64));
            float mnew = fmaxf(m_run[r], mx);
            float alpha = __expf(m_run[r] - mnew);
            m_run[r] = mnew;
            float ps = 0.f;
            #pragma unroll
            for (int jf = 0; jf < 4; jf++) {
                float p = __expf(sacc[jf][r] - mnew);
                sacc[jf][r] = p;
                ps += p;
            }
            ps += __shfl_xor(ps, 1, 64);
            ps += __shfl_xor(ps, 2, 64);
            ps += __shfl_xor(ps, 4, 64);
            ps += __shfl_xor(ps, 8, 64);
            l_run[r] = l_run[r] * alpha + ps;
            #pragma unroll
            for (int df = 0; df < 4; df++) oacc[df][r] *= alpha;
        }

        // ---- write P (bf16) to LDS; wave-local region, no barrier needed ----
        #pragma unroll
        for (int jf = 0; jf < 4; jf++)
            #pragma unroll
            for (int r = 0; r < 4; r++)
                Ps[(w * 16 + q4 * 4 + r) * PP + jf * 16 + ln16] = f2bfbits(sacc[jf][r]);

        // ---- PV ----
        short8v pa0 = *(const short8v*)(&Ps[(w * 16 + ln16) * PP + q4 * 8]);
        short8v pa1 = *(const short8v*)(&Ps[(w * 16 + ln16) * PP + 32 + q4 * 8]);
        #pragma unroll
        for (int df = 0; df < 4; df++) {
            short8v v0f = *(const short8v*)(&Vt[(df * 16 + ln16) * VP + q4 * 8]);
            short8v v1f = *(const short8v*)(&Vt[(df * 16 + ln16) * VP + 32 + q4 * 8]);
            oacc[df] = __builtin_amdgcn_mfma_f32_16x16x32_bf16(pa0, v0f, oacc[df], 0, 0, 0);
            oacc[df] = __builtin_amdgcn_mfma_f32_16x16x32_bf16(pa1, v1f, oacc[df], 0, 0, 0);
        }
        __syncthreads();   // guard Ks/Vt/Ps overwrite next tile
    }

    // ---- normalize + write back into q-slot ----
    #pragma unroll
    for (int r = 0; r < 4; r++) {
        float inv = 1.0f / l_run[r];
        int row = b * SS + qt * 64 + w * 16 + q4 * 4 + r;
        size_t ob = (size_t)row * E3 + h * HD;
        #pragma unroll
        for (int df = 0; df < 4; df++)
            qkv[ob + df * 16 + ln16] = f2bfbits(oacc[df][r] * inv);
    }
}

// =================================================================================
// Legacy fast-path MFMA GEMM (f32 weights converted in-kernel) — fallback only.
// =================================================================================
template <int AMODE, int FUSE>
__global__ void gemm_mfma(const void* __restrict__ Aptr, int lda,
                          const float* __restrict__ W, int ldw,
                          const float* __restrict__ bias,
                          const float2* __restrict__ musig,
                          const float* __restrict__ lng, const float* __restrict__ lnb,
                          void* __restrict__ Cptr, int ldc, int K) {
    __shared__ unsigned short As[128 * 40];
    __shared__ unsigned short Bs[32 * 130];

    int tid = threadIdx.x;
    int bm = blockIdx.y * 128, bn = blockIdx.x * 128;
    int w = tid >> 6, lane = tid & 63, ln16 = lane & 15, q = lane >> 4;
    int wm = (w & 1) * 64, wn = (w >> 1) * 64;

    f32x4 acc[4][4];
    #pragma unroll
    for (int i = 0; i < 4; i++)
        #pragma unroll
        for (int j = 0; j < 4; j++) acc[i][j] = (f32x4){0.f, 0.f, 0.f, 0.f};

    for (int k0 = 0; k0 < K; k0 += 32) {
        if (AMODE == 0) {
            const unsigned short* A = (const unsigned short*)Aptr;
            #pragma unroll
            for (int i = 0; i < 2; i++) {
                int idx = tid + i * 256;
                int row = idx >> 2, ko = (idx & 3) * 8;
                ushort8v v = *(const ushort8v*)(A + (size_t)(bm + row) * lda + k0 + ko);
                *(ushort8v*)(&As[row * 40 + ko]) = v;
            }
        } else {
            const float* A = (const float*)Aptr;
            #pragma unroll
            for (int i = 0; i < 4; i++) {
                int idx = tid + i * 256;
                int row = idx >> 3, ko = (idx & 7) * 4;
                float4 xv = *(const float4*)(A + (size_t)(bm + row) * lda + k0 + ko);
                float2 ms = musig[bm + row];
                float4 gv = *(const float4*)(lng + k0 + ko);
                float4 bv = *(const float4*)(lnb + k0 + ko);
                ushort4v o;
                o[0] = f2bfbits((xv.x - ms.x) * ms.y * gv.x + bv.x);
                o[1] = f2bfbits((xv.y - ms.x) * ms.y * gv.y + bv.y);
                o[2] = f2bfbits((xv.z - ms.x) * ms.y * gv.z + bv.z);
                o[3] = f2bfbits((xv.w - ms.x) * ms.y * gv.w + bv.w);
                *(ushort4v*)(&As[row * 40 + ko]) = o;
            }
        }
        #pragma unroll
        for (int i = 0; i < 16; i++) {
            int idx = tid + i * 256;
            int kr = idx >> 7, n = idx & 127;
            float wv = W[(size_t)(k0 + kr) * ldw + bn + n];
            Bs[kr * 130 + n] = f2bfbits(wv);
        }
        __syncthreads();

        short8v afr[4], bfr[4];
        #pragma unroll
        for (int i = 0; i < 4; i++)
            afr[i] = *(const short8v*)(&As[(wm + i * 16 + ln16) * 40 + q * 8]);
        #pragma unroll
        for (int j = 0; j < 4; j++) {
            int n = wn + j * 16 + ln16;
            #pragma unroll
            for (int jj = 0; jj < 8; jj++)
                bfr[j][jj] = (short)Bs[(q * 8 + jj) * 130 + n];
        }
        #pragma unroll
        for (int i = 0; i < 4; i++)
            #pragma unroll
            for (int j = 0; j < 4; j++)
                acc[i][j] = __builtin_amdgcn_mfma_f32_16x16x32_bf16(afr[i], bfr[j], acc[i][j], 0, 0, 0);
        __syncthreads();
    }

    #pragma unroll
    for (int j = 0; j < 4; j++) {
        int col = bn + wn + j * 16 + ln16;
        float bv = (FUSE == 3) ? 0.f : bias[col];
        #pragma unroll
        for (int i = 0; i < 4; i++) {
            #pragma unroll
            for (int r = 0; r < 4; r++) {
                int row = bm + wm + i * 16 + q * 4 + r;
                float v = acc[i][j][r] + bv;
                if (FUSE == 1) v = 0.5f * v * (1.0f + erff(v * 0.70710678118654752f));
                if (FUSE == 0 || FUSE == 1) {
                    ((unsigned short*)Cptr)[(size_t)row * ldc + col] = f2bfbits(v);
                } else {
                    float* C = (float*)Cptr;
                    C[(size_t)row * ldc + col] += v;
                }
            }
        }
    }
}

// =================================================================================
// Legacy VALU flash attention (used by middle fallback path)
// =================================================================================
__global__ void attn_flash(unsigned short* __restrict__ qkv,
                           const float* __restrict__ mask) {
    __shared__ float Qs[32][68];
    __shared__ float Ks[64][68];
    __shared__ float Vs[64][68];
    __shared__ float Ps[32][68];

    int bid = blockIdx.x;                 // b(2) x h(12) x qt(32)
    int qt = bid & 31;
    int h  = (bid >> 5) % NH;
    int b  = bid / (32 * NH);
    int tid = threadIdx.x;
    int ql = tid >> 3, grp = tid & 7;

    #pragma unroll
    for (int i = 0; i < 8; i++) {
        int idx = tid + i * 256;
        int rq = idx >> 6, d = idx & 63;
        int grow = b * SS + qt * 32 + rq;
        Qs[rq][d] = bfr2f(qkv[(size_t)grow * E3 + h * HD + d]) * 0.125f;
    }

    float m_run = -1e30f, l_run = 0.f;
    float O[8] = {0.f, 0.f, 0.f, 0.f, 0.f, 0.f, 0.f, 0.f};

    for (int c = 0; c < 16; c++) {
        int j0 = c * 64;
        #pragma unroll
        for (int i = 0; i < 4; i++) {
            int idx = tid + i * 256;
            int jj = idx >> 4, d4 = (idx & 15) * 4;
            size_t base = (size_t)(b * SS + j0 + jj) * E3 + h * HD + d4;
            ushort4v kv = *(const ushort4v*)(qkv + base + E);
            ushort4v vv = *(const ushort4v*)(qkv + base + 2 * E);
            *(float4*)&Ks[jj][d4] = make_float4(bfr2f(kv[0]), bfr2f(kv[1]), bfr2f(kv[2]), bfr2f(kv[3]));
            *(float4*)&Vs[jj][d4] = make_float4(bfr2f(vv[0]), bfr2f(vv[1]), bfr2f(vv[2]), bfr2f(vv[3]));
        }
        __syncthreads();

        float s[8] = {0.f, 0.f, 0.f, 0.f, 0.f, 0.f, 0.f, 0.f};
        #pragma unroll
        for (int d0 = 0; d0 < 64; d0 += 4) {
            float4 q4 = *(const float4*)&Qs[ql][d0];
            #pragma unroll
            for (int jl = 0; jl < 8; jl++) {
                float4 k4 = *(const float4*)&Ks[grp + jl * 8][d0];
                s[jl] += q4.x * k4.x + q4.y * k4.y + q4.z * k4.z + q4.w * k4.w;
            }
        }
        #pragma unroll
        for (int jl = 0; jl < 8; jl++)
            s[jl] += (1.0f - mask[b * SS + j0 + grp + jl * 8]) * -10000.0f;

        float cm = s[0];
        #pragma unroll
        for (int jl = 1; jl < 8; jl++) cm = fmaxf(cm, s[jl]);
        cm = fmaxf(cm, __shfl_xor(cm, 1, 64));
        cm = fmaxf(cm, __shfl_xor(cm, 2, 64));
        cm = fmaxf(cm, __shfl_xor(cm, 4, 64));

        float mnew = fmaxf(m_run, cm);
        float alpha = __expf(m_run - mnew);
        float ps = 0.f;
        #pragma unroll
        for (int jl = 0; jl < 8; jl++) {
            float p = __expf(s[jl] - mnew);
            Ps[ql][grp + jl * 8] = p;
            ps += p;
        }
        ps += __shfl_xor(ps, 1, 64);
        ps += __shfl_xor(ps, 2, 64);
        ps += __shfl_xor(ps, 4, 64);
        l_run = l_run * alpha + ps;
        m_run = mnew;
        #pragma unroll
        for (int e = 0; e < 8; e++) O[e] *= alpha;

        #pragma unroll 4
        for (int jj = 0; jj < 64; jj++) {
            float p = Ps[ql][jj];
            float4 v0 = *(const float4*)&Vs[jj][grp * 8];
            float4 v1 = *(const float4*)&Vs[jj][grp * 8 + 4];
            O[0] += p * v0.x; O[1] += p * v0.y; O[2] += p * v0.z; O[3] += p * v0.w;
            O[4] += p * v1.x; O[5] += p * v1.y; O[6] += p * v1.z; O[7] += p * v1.w;
        }
        __syncthreads();
    }

    float inv = 1.0f / l_run;
    int grow = b * SS + qt * 32 + ql;
    size_t obase = (size_t)grow * E3 + h * HD + grp * 8;
    #pragma unroll
    for (int e = 0; e < 8; e++)
        qkv[obase + e] = f2bfbits(O[e] * inv);
}

// =================================================================================
// Legacy (R4-proven) kernels — deep fallback if workspace is tiny
// =================================================================================
template <int FUSE, typename CT>
__global__ void gemm_legacy(const __hip_bfloat16* __restrict__ A, int lda,
                            const float* __restrict__ W, int ldw,
                            const float* __restrict__ bias,
                            CT* __restrict__ C, int ldc,
                            const float* __restrict__ resid,
                            int M, int N, int K) {
    __shared__ float As[16][65];
    __shared__ float Bs[16][65];
    int bm = blockIdx.y * 64, bn = blockIdx.x * 64;
    int tid = threadIdx.x;
    int ty = tid >> 4, tx = tid & 15;
    int ar = tid >> 2, ak = (tid & 3) << 2;
    int wk = tid >> 4, wn = (tid & 15) << 2;

    float acc[4][4] = {};
    for (int k0 = 0; k0 < K; k0 += 16) {
        ushort4 av = *(const ushort4*)(A + (size_t)(bm + ar) * lda + k0 + ak);
        As[ak + 0][ar] = bfr2f(av.x);
        As[ak + 1][ar] = bfr2f(av.y);
        As[ak + 2][ar] = bfr2f(av.z);
        As[ak + 3][ar] = bfr2f(av.w);
        float4 wv = *(const float4*)(W + (size_t)(k0 + wk) * ldw + bn + wn);
        Bs[wk][wn + 0] = wv.x;
        Bs[wk][wn + 1] = wv.y;
        Bs[wk][wn + 2] = wv.z;
        Bs[wk][wn + 3] = wv.w;
        __syncthreads();
        #pragma unroll
        for (int kk = 0; kk < 16; kk++) {
            float a[4], bv[4];
            #pragma unroll
            for (int i = 0; i < 4; i++) { a[i] = As[kk][ty * 4 + i]; bv[i] = Bs[kk][tx * 4 + i]; }
            #pragma unroll
            for (int i = 0; i < 4; i++)
                #pragma unroll
                for (int j = 0; j < 4; j++) acc[i][j] += a[i] * bv[j];
        }
        __syncthreads();
    }
    #pragma unroll
    for (int i = 0; i < 4; i++) {
        int row = bm + ty * 4 + i;
        #pragma unroll
        for (int j = 0; j < 4; j++) {
            int col = bn + tx * 4 + j;
            float v = acc[i][j];
            if (FUSE != 3) v += bias[col];
            if (FUSE == 1) v = 0.5f * v * (1.0f + erff(v * 0.70710678118654752f));
            if (FUSE == 2 || FUSE == 3) v += resid[(size_t)row * ldc + col];
            if constexpr (sizeof(CT) == 2) C[(size_t)row * ldc + col] = f2bf(v);
            else                           C[(size_t)row * ldc + col] = v;
        }
    }
}

__global__ void attn_legacy(const __hip_bfloat16* __restrict__ qkv,
                            const float* __restrict__ mask,
                            __hip_bfloat16* __restrict__ out) {
    __shared__ float sc[SS];
    __shared__ float qv[HD];
    __shared__ float oacc[4][HD];
    __shared__ float redbuf[4];

    int q = blockIdx.x & (SS - 1);
    int h = blockIdx.x >> 10;
    int tid = threadIdx.x;

    const __hip_bfloat16* qrow = qkv + (size_t)q * E3 + h * HD;
    if (tid < HD) qv[tid] = bf2f(qrow[tid]) * 0.125f;
    __syncthreads();

    for (int j = tid; j < SS; j += 256) {
        const __hip_bfloat16* krow = qkv + (size_t)j * E3 + E + h * HD;
        float d = 0.f;
        #pragma unroll
        for (int t = 0; t < HD; t += 4) {
            ushort4 kv4 = *(const ushort4*)(krow + t);
            d += qv[t] * bfr2f(kv4.x) + qv[t + 1] * bfr2f(kv4.y)
               + qv[t + 2] * bfr2f(kv4.z) + qv[t + 3] * bfr2f(kv4.w);
        }
        d += (1.0f - mask[j]) * -10000.0f;
        sc[j] = d;
    }
    __syncthreads();

    float m = -1e30f;
    for (int j = tid; j < SS; j += 256) m = fmaxf(m, sc[j]);
    m = block_max(m, redbuf);
    float s = 0.f;
    for (int j = tid; j < SS; j += 256) { float e = __expf(sc[j] - m); sc[j] = e; s += e; }
    s = block_sum(s, redbuf);
    float inv = 1.0f / s;
    __syncthreads();

    int d = tid & 63, c = tid >> 6;
    float acc = 0.f;
    int j0 = c * 256;
    for (int j = j0; j < j0 + 256; j++) {
        const __hip_bfloat16* vrow = qkv + (size_t)j * E3 + 2 * E + h * HD;
        acc += sc[j] * bf2f(vrow[d]);
    }
    oacc[c][d] = acc;
    __syncthreads();
    if (tid < HD) {
        float o = (oacc[0][tid] + oacc[1][tid] + oacc[2][tid] + oacc[3][tid]) * inv;
        out[(size_t)q * E + h * HD + tid] = f2bf(o);
    }
}

__global__ void copy_kernel(const float* __restrict__ in, float* __restrict__ out, int n) {
    int i = blockIdx.x * 256 + threadIdx.x;
    if (i < n) out[i] = in[i];
}

// =================================================================================
extern "C" void kernel_launch(void* const* d_in, const int* in_sizes, int n_in,
                              void* d_out, int out_size, void* d_ws, size_t ws_size,
                              hipStream_t stream) {
    const float* emb   = (const float*)d_in[0];
    const float* mask  = (const float*)d_in[1];
    const float* Wqkv  = (const float*)d_in[2];
    const float* bqkv  = (const float*)d_in[3];
    const float* Wo    = (const float*)d_in[4];
    const float* bo    = (const float*)d_in[5];
    const float* ln1g  = (const float*)d_in[6];
    const float* ln1b  = (const float*)d_in[7];
    const float* ln2g  = (const float*)d_in[8];
    const float* ln2b  = (const float*)d_in[9];
    const float* Wfc   = (const float*)d_in[10];
    const float* bfc   = (const float*)d_in[11];
    const float* Wmo   = (const float*)d_in[12];
    const float* bmo   = (const float*)d_in[13];
    const float* lnfg  = (const float*)d_in[14];
    const float* lnfb  = (const float*)d_in[15];

    const size_t NEED_FAST2 = sizeof(float) * (size_t)T * E
                            + 2ull * (size_t)T * E
                            + 2ull * (size_t)T * FFD
                            + 2ull * (size_t)E * FFD;
    const size_t NEED_FAST = sizeof(float) * (size_t)T * E
                           + 2ull * (size_t)T * E3
                           + sizeof(float2) * (size_t)T;

    if (ws_size >= NEED_FAST2) {
        // ---------------- FAST2 PATH: bf16 transposed weights + MFMA attention ----
        float* x            = (float*)d_ws;
        unsigned short* h   = (unsigned short*)(x + (size_t)T * E);       // [T,E]
        unsigned short* buf = h + (size_t)T * E;                          // [T,FFD] union
        unsigned short* wt  = buf + (size_t)T * FFD;                      // [<=E*FFD]
        unsigned short* qkv = buf;                                        // [T,E3]
        unsigned short* ff  = buf;                                        // [T,FFD]

        copy4_kernel<<<dim3(T * E / 4 / 256), dim3(256), 0, stream>>>(
            (const float4*)emb, (float4*)x, T * E / 4);

        for (int l = 0; l < LYR; l++) {
            const float* wqkv_l = Wqkv + (size_t)l * E * E3;
            const float* wo_l   = Wo   + (size_t)l * E * E;
            const float* wfc_l  = Wfc  + (size_t)l * E * FFD;
            const float* wmo_l  = Wmo  + (size_t)l * FFD * E;

            ln_kernel<__hip_bfloat16><<<dim3(T), dim3(256), 0, stream>>>(
                x, (__hip_bfloat16*)h, ln1g + l * E, ln1b + l * E);
            transpose_cvt<<<dim3(E3 / 32, E / 32), dim3(256), 0, stream>>>(wqkv_l, wt, E, E3);
            gemm_bt<0, 128, 128><<<dim3(E3 / 128, T / 128), dim3(256), 0, stream>>>(
                h, E, wt, E, bqkv + l * E3, qkv, E3, E);
            attn_mfma<<<dim3(BB * NH * 16), dim3(256), 0, stream>>>(qkv, mask);
            transpose_cvt<<<dim3(E / 32, E / 32), dim3(256), 0, stream>>>(wo_l, wt, E, E);
            gemm_bt<2, 64, 128><<<dim3(E / 128, T / 64), dim3(256), 0, stream>>>(
                qkv, E3, wt, E, bo + l * E, x, E, E);

            ln_kernel<__hip_bfloat16><<<dim3(T), dim3(256), 0, stream>>>(
                x, (__hip_bfloat16*)h, ln2g + l * E, ln2b + l * E);
            transpose_cvt<<<dim3(FFD / 32, E / 32), dim3(256), 0, stream>>>(wfc_l, wt, E, FFD);
            gemm_bt<1, 128, 128><<<dim3(FFD / 128, T / 128), dim3(256), 0, stream>>>(
                h, E, wt, E, bfc + l * FFD, ff, FFD, E);
            transpose_cvt<<<dim3(E / 32, FFD / 32), dim3(256), 0, stream>>>(wmo_l, wt, FFD, E);
            gemm_bt<2, 64, 128><<<dim3(E / 128, T / 64), dim3(256), 0, stream>>>(
                ff, FFD, wt, FFD, bmo + l * E, x, E, FFD);
        }
        ln_kernel<float><<<dim3(T), dim3(256), 0, stream>>>(x, (float*)d_out, lnfg, lnfb);
    } else if (ws_size >= NEED_FAST) {
        // ---------------- FAST PATH (previous session, proven) ----------------
        float* x              = (float*)d_ws;
        unsigned short* qkv   = (unsigned short*)(x + (size_t)T * E);
        float2* musig         = (float2*)(qkv + (size_t)T * E3);

        copy4_kernel<<<dim3(T * E / 4 / 256), dim3(256), 0, stream>>>(
            (const float4*)emb, (float4*)x, T * E / 4);

        for (int l = 0; l < LYR; l++) {
            const float* wqkv_l = Wqkv + (size_t)l * E * E3;
            const float* wo_l   = Wo   + (size_t)l * E * E;
            const float* wfc_l  = Wfc  + (size_t)l * E * FFD;
            const float* wmo_l  = Wmo  + (size_t)l * FFD * E;

            rowstat_kernel<<<dim3(T), dim3(256), 0, stream>>>(x, musig);
            gemm_mfma<1, 0><<<dim3(E3 / 128, T / 128), dim3(256), 0, stream>>>(
                x, E, wqkv_l, E3, bqkv + l * E3, musig, ln1g + l * E, ln1b + l * E,
                qkv, E3, E);
            attn_flash<<<dim3(BB * NH * 32), dim3(256), 0, stream>>>(qkv, mask);
            gemm_mfma<0, 2><<<dim3(E / 128, T / 128), dim3(256), 0, stream>>>(
                qkv, E3, wo_l, E, bo + l * E, nullptr, nullptr, nullptr, x, E, E);

            unsigned short* ffp = qkv;
            unsigned short* hp  = qkv + (size_t)T * FH;
            ln_kernel<__hip_bfloat16><<<dim3(T), dim3(256), 0, stream>>>(
                x, (__hip_bfloat16*)hp, ln2g + l * E, ln2b + l * E);
            for (int f = 0; f < 2; f++) {
                gemm_mfma<0, 1><<<dim3(FH / 128, T / 128), dim3(256), 0, stream>>>(
                    hp, E, wfc_l + f * FH, FFD, bfc + l * FFD + f * FH,
                    nullptr, nullptr, nullptr, ffp, FH, E);
                if (f == 0)
                    gemm_mfma<0, 3><<<dim3(E / 128, T / 128), dim3(256), 0, stream>>>(
                        ffp, FH, wmo_l + (size_t)f * FH * E, E, nullptr, nullptr, nullptr, nullptr,
                        x, E, FH);
                else
                    gemm_mfma<0, 2><<<dim3(E / 128, T / 128), dim3(256), 0, stream>>>(
                        ffp, FH, wmo_l + (size_t)f * FH * E, E, bmo + l * E, nullptr, nullptr, nullptr,
                        x, E, FH);
            }
        }
        ln_kernel<float><<<dim3(T), dim3(256), 0, stream>>>(x, (float*)d_out, lnfg, lnfb);
    } else {
        // ---------------- LEGACY PATH (R4-proven, 12.58 MB) ----------------
        float* x           = (float*)d_ws;
        __hip_bfloat16* hb = (__hip_bfloat16*)(x + (size_t)T * E);
        __hip_bfloat16* qb = hb + (size_t)SS * E;

        int n = T * E;
        copy_kernel<<<dim3((n + 255) / 256), dim3(256), 0, stream>>>(emb, x, n);

        for (int l = 0; l < LYR; l++) {
            const float* wqkv_l = Wqkv + (size_t)l * E * E3;
            const float* wo_l   = Wo   + (size_t)l * E * E;
            const float* wfc_l  = Wfc  + (size_t)l * E * FFD;
            const float* wmo_l  = Wmo  + (size_t)l * FFD * E;

            for (int b = 0; b < BB; b++) {
                float* xb = x + (size_t)b * SS * E;
                ln_kernel<__hip_bfloat16><<<dim3(SS), dim3(256), 0, stream>>>(
                    xb, hb, ln1g + l * E, ln1b + l * E);
                gemm_legacy<0, __hip_bfloat16><<<dim3(E3 / 64, SS / 64), dim3(256), 0, stream>>>(
                    hb, E, wqkv_l, E3, bqkv + l * E3, qb, E3, nullptr, SS, E3, E);
                attn_legacy<<<dim3(NH * SS), dim3(256), 0, stream>>>(qb, mask + b * SS, hb);
                gemm_legacy<2, float><<<dim3(E / 64, SS / 64), dim3(256), 0, stream>>>(
                    hb, E, wo_l, E, bo + l * E, xb, E, xb, SS, E, E);
            }
            for (int b = 0; b < BB; b++) {
                float* xb = x + (size_t)b * SS * E;
                ln_kernel<__hip_bfloat16><<<dim3(SS), dim3(256), 0, stream>>>(
                    xb, hb, ln2g + l * E, ln2b + l * E);
                for (int f = 0; f < 2; f++) {
                    gemm_legacy<1, __hip_bfloat16><<<dim3(FH / 64, SS / 64), dim3(256), 0, stream>>>(
                        hb, E, wfc_l + f * FH, FFD, bfc + l * FFD + f * FH, qb, FH, nullptr,
                        SS, FH, E);
                    if (f == 0)
                        gemm_legacy<3, float><<<dim3(E / 64, SS / 64), dim3(256), 0, stream>>>(
                            qb, FH, wmo_l + (size_t)f * FH * E, E, nullptr, xb, E, xb, SS, E, FH);
                    else
                        gemm_legacy<2, float><<<dim3(E / 64, SS / 64), dim3(256), 0, stream>>>(
                            qb, FH, wmo_l + (size_t)f * FH * E, E, bmo + l * E, xb, E, xb, SS, E, FH);
                }
            }
        }
        ln_kernel<float><<<dim3(T), dim3(256), 0, stream>>>(x, (float*)d_out, lnfg, lnfb);
    }
}

// Round 3
// 1415.944 us; speedup vs baseline: 3.3538x; 1.2171x over previous
//
#include <hip/hip_runtime.h>
#include <hip/hip_bf16.h>
#include <math.h>

constexpr int LYR = 6;
constexpr int E   = 768;
constexpr int NH  = 12;
constexpr int FFD = 3072;
constexpr int HD  = 64;
constexpr int BB  = 2;
constexpr int SS  = 1024;
constexpr int T   = BB * SS;     // 2048 tokens
constexpr int E3  = 3 * E;       // 2304
constexpr int FH  = FFD / 2;     // 1536 (FFN slice width, legacy fast path)

#define LN_EPS 1e-5f

typedef __attribute__((ext_vector_type(8))) short    short8v;
typedef __attribute__((ext_vector_type(8))) unsigned short ushort8v;
typedef __attribute__((ext_vector_type(4))) unsigned short ushort4v;
typedef __attribute__((ext_vector_type(4))) float    f32x4;

__device__ __forceinline__ float bf2f(__hip_bfloat16 x) { return __bfloat162float(x); }
__device__ __forceinline__ float bfr2f(unsigned short u) {
    union { unsigned int i; float f; } v; v.i = ((unsigned int)u) << 16; return v.f;
}
__device__ __forceinline__ __hip_bfloat16 f2bf(float f) { return __float2bfloat16(f); }
// bf16 bits with round-to-nearest-even (finite inputs only)
__device__ __forceinline__ unsigned short f2bfbits(float f) {
    union { float f; unsigned int i; } v; v.f = f;
    unsigned int r = (v.i + 0x7fffu + ((v.i >> 16) & 1u)) >> 16;
    return (unsigned short)r;
}

// ---------------- block reductions (256 threads = 4 waves of 64) ----------------
__device__ __forceinline__ float block_sum(float v, float* sm) {
    #pragma unroll
    for (int o = 32; o > 0; o >>= 1) v += __shfl_down(v, o, 64);
    int lane = threadIdx.x & 63, wid = threadIdx.x >> 6;
    if (lane == 0) sm[wid] = v;
    __syncthreads();
    float r = sm[0] + sm[1] + sm[2] + sm[3];
    __syncthreads();
    return r;
}

__device__ __forceinline__ float block_max(float v, float* sm) {
    #pragma unroll
    for (int o = 32; o > 0; o >>= 1) v = fmaxf(v, __shfl_down(v, o, 64));
    int lane = threadIdx.x & 63, wid = threadIdx.x >> 6;
    if (lane == 0) sm[wid] = v;
    __syncthreads();
    float r = fmaxf(fmaxf(sm[0], sm[1]), fmaxf(sm[2], sm[3]));
    __syncthreads();
    return r;
}

// ---------------- f32 copy (embeddings -> residual stream), float4 ----------------
__global__ void copy4_kernel(const float4* __restrict__ in, float4* __restrict__ out, int n4) {
    int i = blockIdx.x * 256 + threadIdx.x;
    if (i < n4) out[i] = in[i];
}

// ---------------- per-row LN stats: musig[row] = (mu, rstd)  (legacy fast path) ---
__global__ void rowstat_kernel(const float* __restrict__ x, float2* __restrict__ musig) {
    __shared__ float sm[4];
    int row = blockIdx.x;
    const float* xr = x + (size_t)row * E;
    float s = 0.f;
    for (int i = threadIdx.x; i < E; i += 256) s += xr[i];
    float mu = block_sum(s, sm) * (1.0f / E);
    float v = 0.f;
    for (int i = threadIdx.x; i < E; i += 256) { float d = xr[i] - mu; v += d * d; }
    float rstd = rsqrtf(block_sum(v, sm) * (1.0f / E) + LN_EPS);
    if (threadIdx.x == 0) musig[row] = make_float2(mu, rstd);
}

// ---------------- LayerNorm: one block per row; x f32 -> out bf16 or f32 --------
template <typename OT>
__global__ void ln_kernel(const float* __restrict__ x, OT* __restrict__ out,
                          const float* __restrict__ g, const float* __restrict__ b) {
    __shared__ float sm[4];
    int row = blockIdx.x;
    const float* xr = x + (size_t)row * E;
    float s = 0.f;
    for (int i = threadIdx.x; i < E; i += 256) s += xr[i];
    float mu = block_sum(s, sm) * (1.0f / E);
    float v = 0.f;
    for (int i = threadIdx.x; i < E; i += 256) { float d = xr[i] - mu; v += d * d; }
    float rstd = rsqrtf(block_sum(v, sm) * (1.0f / E) + LN_EPS);
    for (int i = threadIdx.x; i < E; i += 256) {
        float o = (xr[i] - mu) * rstd * g[i] + b[i];
        if constexpr (sizeof(OT) == 2) out[(size_t)row * E + i] = f2bf(o);
        else                           out[(size_t)row * E + i] = o;
    }
}

// =================================================================================
// Weight transpose+convert: W f32 [K][N] -> Wt bf16 bits [N][K]
// =================================================================================
__global__ void transpose_cvt(const float* __restrict__ W, unsigned short* __restrict__ Wt,
                              int K, int N) {
    __shared__ float tile[32][33];
    int n0 = blockIdx.x * 32, k0 = blockIdx.y * 32;
    int tx = threadIdx.x & 31, ty = threadIdx.x >> 5;   // ty 0..7
    #pragma unroll
    for (int i = 0; i < 4; i++)
        tile[ty + i * 8][tx] = W[(size_t)(k0 + ty + i * 8) * N + n0 + tx];
    __syncthreads();
    #pragma unroll
    for (int i = 0; i < 4; i++)
        Wt[(size_t)(n0 + ty + i * 8) * K + k0 + tx] = f2bfbits(tile[tx][ty + i * 8]);
}

// =================================================================================
// MFMA GEMM, both operands bf16, B pre-transposed: C[M,N] = A @ Bt^T + epilogue.
// LDS rows padded to 80 ushorts = 160B (16B-aligned, conflict-floor b128).
// Split-K via gridDim.z (K must divide evenly; z>1 only valid with FUSE=2).
//   FUSE 0: C = A@B + bias -> bf16 | 1: gelu(...) -> bf16
//   FUSE 2: C += A@B + bias (f32, atomicAdd — safe under split-K; bias on z==0)
// =================================================================================
template <int FUSE, int BM, int BN>
__global__ __launch_bounds__(256) void gemm_bt(
        const unsigned short* __restrict__ A, int lda,
        const unsigned short* __restrict__ Bt, int ldb,
        const float* __restrict__ bias,
        void* __restrict__ Cptr, int ldc, int K) {
    constexpr int PAD = 80;
    constexpr int MFR = BM / 32, NFR = BN / 32;
    constexpr int AIT = BM / 32, BIT = BN / 32;
    __shared__ unsigned short As[BM * PAD];
    __shared__ unsigned short Bs[BN * PAD];

    int tid = threadIdx.x;
    int bm = blockIdx.y * BM, bn = blockIdx.x * BN;
    int kchunk = K / gridDim.z;
    int kbeg = blockIdx.z * kchunk, kend = kbeg + kchunk;
    int w = tid >> 6, lane = tid & 63, ln16 = lane & 15, q = lane >> 4;
    int wm = (w & 1) * (BM / 2), wn = (w >> 1) * (BN / 2);

    f32x4 acc[MFR][NFR];
    #pragma unroll
    for (int i = 0; i < MFR; i++)
        #pragma unroll
        for (int j = 0; j < NFR; j++) acc[i][j] = (f32x4){0.f, 0.f, 0.f, 0.f};

    for (int k0 = kbeg; k0 < kend; k0 += 64) {
        #pragma unroll
        for (int i = 0; i < AIT; i++) {
            int idx = tid + i * 256;
            int row = idx >> 3, ko = (idx & 7) * 8;
            *(ushort8v*)(&As[row * PAD + ko]) =
                *(const ushort8v*)(A + (size_t)(bm + row) * lda + k0 + ko);
        }
        #pragma unroll
        for (int i = 0; i < BIT; i++) {
            int idx = tid + i * 256;
            int row = idx >> 3, ko = (idx & 7) * 8;
            *(ushort8v*)(&Bs[row * PAD + ko]) =
                *(const ushort8v*)(Bt + (size_t)(bn + row) * ldb + k0 + ko);
        }
        __syncthreads();

        #pragma unroll
        for (int kk = 0; kk < 64; kk += 32) {
            short8v afr[MFR], bfr[NFR];
            #pragma unroll
            for (int i = 0; i < MFR; i++)
                afr[i] = *(const short8v*)(&As[(wm + i * 16 + ln16) * PAD + kk + q * 8]);
            #pragma unroll
            for (int j = 0; j < NFR; j++)
                bfr[j] = *(const short8v*)(&Bs[(wn + j * 16 + ln16) * PAD + kk + q * 8]);
            #pragma unroll
            for (int i = 0; i < MFR; i++)
                #pragma unroll
                for (int j = 0; j < NFR; j++)
                    acc[i][j] = __builtin_amdgcn_mfma_f32_16x16x32_bf16(afr[i], bfr[j], acc[i][j], 0, 0, 0);
        }
        __syncthreads();
    }

    #pragma unroll
    for (int j = 0; j < NFR; j++) {
        int col = bn + wn + j * 16 + ln16;
        float bv = (blockIdx.z == 0) ? bias[col] : 0.f;
        #pragma unroll
        for (int i = 0; i < MFR; i++) {
            #pragma unroll
            for (int r = 0; r < 4; r++) {
                int row = bm + wm + i * 16 + q * 4 + r;
                float v = acc[i][j][r] + bv;
                if (FUSE == 1) v = 0.5f * v * (1.0f + erff(v * 0.70710678118654752f));
                if (FUSE == 0 || FUSE == 1) {
                    ((unsigned short*)Cptr)[(size_t)row * ldc + col] = f2bfbits(v);
                } else {
                    atomicAdd(&((float*)Cptr)[(size_t)row * ldc + col], v);
                }
            }
        }
    }
}

// =================================================================================
// MFMA flash attention: one block per (b, h, 64-query tile); 4 waves, 16 q-rows each.
// qkv bf16 bits [T][E3]; output written in place into the q-slot.
// =================================================================================
__global__ __launch_bounds__(256) void attn_mfma(unsigned short* __restrict__ qkv,
                                                 const float* __restrict__ mask) {
    constexpr int KP = 80;   // Ks row pitch (ushorts)
    constexpr int VP = 82;   // Vt row pitch
    constexpr int PP = 82;   // Ps row pitch
    __shared__ unsigned short Ks[64 * KP];
    __shared__ unsigned short Vt[64 * VP];
    __shared__ unsigned short Ps[64 * PP];
    __shared__ float Ms[64];

    int bid = blockIdx.x;                 // b(2) x h(12) x qt(16)
    int qt = bid & 15;
    int h  = (bid >> 4) % NH;
    int b  = bid / (16 * NH);
    int tid = threadIdx.x;
    int w = tid >> 6, lane = tid & 63, ln16 = lane & 15, q4 = lane >> 4;

    int qrow = b * SS + qt * 64 + w * 16 + ln16;
    const unsigned short* qbase = qkv + (size_t)qrow * E3 + h * HD;
    short8v qfr0 = *(const short8v*)(qbase + q4 * 8);
    short8v qfr1 = *(const short8v*)(qbase + 32 + q4 * 8);

    f32x4 sacc[4];
    f32x4 oacc[4];
    float m_run[4], l_run[4];
    #pragma unroll
    for (int r = 0; r < 4; r++) { m_run[r] = -1e30f; l_run[r] = 0.f; }
    #pragma unroll
    for (int i = 0; i < 4; i++) oacc[i] = (f32x4){0.f, 0.f, 0.f, 0.f};

    for (int t = 0; t < 16; t++) {
        int j0 = t * 64;
        #pragma unroll
        for (int i = 0; i < 2; i++) {
            int idx = tid + i * 256;                  // 0..511
            int row = idx >> 3, ko = (idx & 7) * 8;   // j-row, d-chunk
            size_t gb = (size_t)(b * SS + j0 + row) * E3 + h * HD;
            *(ushort8v*)(&Ks[row * KP + ko]) = *(const ushort8v*)(qkv + gb + E + ko);
            ushort8v vv = *(const ushort8v*)(qkv + gb + 2 * E + ko);
            #pragma unroll
            for (int e = 0; e < 8; e++)
                Vt[(ko + e) * VP + row] = vv[e];
        }
        if (tid < 64) Ms[tid] = (1.0f - mask[b * SS + j0 + tid]) * -10000.0f;
        __syncthreads();

        #pragma unroll
        for (int jf = 0; jf < 4; jf++) sacc[jf] = (f32x4){0.f, 0.f, 0.f, 0.f};
        #pragma unroll
        for (int jf = 0; jf < 4; jf++) {
            short8v k0f = *(const short8v*)(&Ks[(jf * 16 + ln16) * KP + q4 * 8]);
            short8v k1f = *(const short8v*)(&Ks[(jf * 16 + ln16) * KP + 32 + q4 * 8]);
            sacc[jf] = __builtin_amdgcn_mfma_f32_16x16x32_bf16(qfr0, k0f, sacc[jf], 0, 0, 0);
            sacc[jf] = __builtin_amdgcn_mfma_f32_16x16x32_bf16(qfr1, k1f, sacc[jf], 0, 0, 0);
        }

        float madd[4];
        #pragma unroll
        for (int jf = 0; jf < 4; jf++) madd[jf] = Ms[jf * 16 + ln16];
        #pragma unroll
        for (int jf = 0; jf < 4; jf++)
            #pragma unroll
            for (int r = 0; r < 4; r++)
                sacc[jf][r] = sacc[jf][r] * 0.125f + madd[jf];

        #pragma unroll
        for (int r = 0; r < 4; r++) {
            float mx = fmaxf(fmaxf(sacc[0][r], sacc[1][r]), fmaxf(sacc[2][r], sacc[3][r]));
            mx = fmaxf(mx, __shfl_xor(mx, 1, 64));
            mx = fmaxf(mx, __shfl_xor(mx, 2, 64));
            mx = fmaxf(mx, __shfl_xor(mx, 4, 64));
            mx = fmaxf(mx, __shfl_xor(mx, 8, 64));
            float mnew = fmaxf(m_run[r], mx);
            float alpha = __expf(m_run[r] - mnew);
            m_run[r] = mnew;
            float ps = 0.f;
            #pragma unroll
            for (int jf = 0; jf < 4; jf++) {
                float p = __expf(sacc[jf][r] - mnew);
                sacc[jf][r] = p;
                ps += p;
            }
            ps += __shfl_xor(ps, 1, 64);
            ps += __shfl_xor(ps, 2, 64);
            ps += __shfl_xor(ps, 4, 64);
            ps += __shfl_xor(ps, 8, 64);
            l_run[r] = l_run[r] * alpha + ps;
            #pragma unroll
            for (int df = 0; df < 4; df++) oacc[df][r] *= alpha;
        }

        #pragma unroll
        for (int jf = 0; jf < 4; jf++)
            #pragma unroll
            for (int r = 0; r < 4; r++)
                Ps[(w * 16 + q4 * 4 + r) * PP + jf * 16 + ln16] = f2bfbits(sacc[jf][r]);

        short8v pa0 = *(const short8v*)(&Ps[(w * 16 + ln16) * PP + q4 * 8]);
        short8v pa1 = *(const short8v*)(&Ps[(w * 16 + ln16) * PP + 32 + q4 * 8]);
        #pragma unroll
        for (int df = 0; df < 4; df++) {
            short8v v0f = *(const short8v*)(&Vt[(df * 16 + ln16) * VP + q4 * 8]);
            short8v v1f = *(const short8v*)(&Vt[(df * 16 + ln16) * VP + 32 + q4 * 8]);
            oacc[df] = __builtin_amdgcn_mfma_f32_16x16x32_bf16(pa0, v0f, oacc[df], 0, 0, 0);
            oacc[df] = __builtin_amdgcn_mfma_f32_16x16x32_bf16(pa1, v1f, oacc[df], 0, 0, 0);
        }
        __syncthreads();   // guard Ks/Vt/Ps overwrite next tile
    }

    #pragma unroll
    for (int r = 0; r < 4; r++) {
        float inv = 1.0f / l_run[r];
        int row = b * SS + qt * 64 + w * 16 + q4 * 4 + r;
        size_t ob = (size_t)row * E3 + h * HD;
        #pragma unroll
        for (int df = 0; df < 4; df++)
            qkv[ob + df * 16 + ln16] = f2bfbits(oacc[df][r] * inv);
    }
}

// =================================================================================
// Legacy fast-path MFMA GEMM (f32 weights converted in-kernel) — fallback only.
// =================================================================================
template <int AMODE, int FUSE>
__global__ void gemm_mfma(const void* __restrict__ Aptr, int lda,
                          const float* __restrict__ W, int ldw,
                          const float* __restrict__ bias,
                          const float2* __restrict__ musig,
                          const float* __restrict__ lng, const float* __restrict__ lnb,
                          void* __restrict__ Cptr, int ldc, int K) {
    __shared__ unsigned short As[128 * 40];
    __shared__ unsigned short Bs[32 * 130];

    int tid = threadIdx.x;
    int bm = blockIdx.y * 128, bn = blockIdx.x * 128;
    int w = tid >> 6, lane = tid & 63, ln16 = lane & 15, q = lane >> 4;
    int wm = (w & 1) * 64, wn = (w >> 1) * 64;

    f32x4 acc[4][4];
    #pragma unroll
    for (int i = 0; i < 4; i++)
        #pragma unroll
        for (int j = 0; j < 4; j++) acc[i][j] = (f32x4){0.f, 0.f, 0.f, 0.f};

    for (int k0 = 0; k0 < K; k0 += 32) {
        if (AMODE == 0) {
            const unsigned short* A = (const unsigned short*)Aptr;
            #pragma unroll
            for (int i = 0; i < 2; i++) {
                int idx = tid + i * 256;
                int row = idx >> 2, ko = (idx & 3) * 8;
                ushort8v v = *(const ushort8v*)(A + (size_t)(bm + row) * lda + k0 + ko);
                *(ushort8v*)(&As[row * 40 + ko]) = v;
            }
        } else {
            const float* A = (const float*)Aptr;
            #pragma unroll
            for (int i = 0; i < 4; i++) {
                int idx = tid + i * 256;
                int row = idx >> 3, ko = (idx & 7) * 4;
                float4 xv = *(const float4*)(A + (size_t)(bm + row) * lda + k0 + ko);
                float2 ms = musig[bm + row];
                float4 gv = *(const float4*)(lng + k0 + ko);
                float4 bv = *(const float4*)(lnb + k0 + ko);
                ushort4v o;
                o[0] = f2bfbits((xv.x - ms.x) * ms.y * gv.x + bv.x);
                o[1] = f2bfbits((xv.y - ms.x) * ms.y * gv.y + bv.y);
                o[2] = f2bfbits((xv.z - ms.x) * ms.y * gv.z + bv.z);
                o[3] = f2bfbits((xv.w - ms.x) * ms.y * gv.w + bv.w);
                *(ushort4v*)(&As[row * 40 + ko]) = o;
            }
        }
        #pragma unroll
        for (int i = 0; i < 16; i++) {
            int idx = tid + i * 256;
            int kr = idx >> 7, n = idx & 127;
            float wv = W[(size_t)(k0 + kr) * ldw + bn + n];
            Bs[kr * 130 + n] = f2bfbits(wv);
        }
        __syncthreads();

        short8v afr[4], bfr[4];
        #pragma unroll
        for (int i = 0; i < 4; i++)
            afr[i] = *(const short8v*)(&As[(wm + i * 16 + ln16) * 40 + q * 8]);
        #pragma unroll
        for (int j = 0; j < 4; j++) {
            int n = wn + j * 16 + ln16;
            #pragma unroll
            for (int jj = 0; jj < 8; jj++)
                bfr[j][jj] = (short)Bs[(q * 8 + jj) * 130 + n];
        }
        #pragma unroll
        for (int i = 0; i < 4; i++)
            #pragma unroll
            for (int j = 0; j < 4; j++)
                acc[i][j] = __builtin_amdgcn_mfma_f32_16x16x32_bf16(afr[i], bfr[j], acc[i][j], 0, 0, 0);
        __syncthreads();
    }

    #pragma unroll
    for (int j = 0; j < 4; j++) {
        int col = bn + wn + j * 16 + ln16;
        float bv = (FUSE == 3) ? 0.f : bias[col];
        #pragma unroll
        for (int i = 0; i < 4; i++) {
            #pragma unroll
            for (int r = 0; r < 4; r++) {
                int row = bm + wm + i * 16 + q * 4 + r;
                float v = acc[i][j][r] + bv;
                if (FUSE == 1) v = 0.5f * v * (1.0f + erff(v * 0.70710678118654752f));
                if (FUSE == 0 || FUSE == 1) {
                    ((unsigned short*)Cptr)[(size_t)row * ldc + col] = f2bfbits(v);
                } else {
                    float* C = (float*)Cptr;
                    C[(size_t)row * ldc + col] += v;
                }
            }
        }
    }
}

// =================================================================================
// Legacy VALU flash attention (used by middle fallback path)
// =================================================================================
__global__ void attn_flash(unsigned short* __restrict__ qkv,
                           const float* __restrict__ mask) {
    __shared__ float Qs[32][68];
    __shared__ float Ks[64][68];
    __shared__ float Vs[64][68];
    __shared__ float Ps[32][68];

    int bid = blockIdx.x;                 // b(2) x h(12) x qt(32)
    int qt = bid & 31;
    int h  = (bid >> 5) % NH;
    int b  = bid / (32 * NH);
    int tid = threadIdx.x;
    int ql = tid >> 3, grp = tid & 7;

    #pragma unroll
    for (int i = 0; i < 8; i++) {
        int idx = tid + i * 256;
        int rq = idx >> 6, d = idx & 63;
        int grow = b * SS + qt * 32 + rq;
        Qs[rq][d] = bfr2f(qkv[(size_t)grow * E3 + h * HD + d]) * 0.125f;
    }

    float m_run = -1e30f, l_run = 0.f;
    float O[8] = {0.f, 0.f, 0.f, 0.f, 0.f, 0.f, 0.f, 0.f};

    for (int c = 0; c < 16; c++) {
        int j0 = c * 64;
        #pragma unroll
        for (int i = 0; i < 4; i++) {
            int idx = tid + i * 256;
            int jj = idx >> 4, d4 = (idx & 15) * 4;
            size_t base = (size_t)(b * SS + j0 + jj) * E3 + h * HD + d4;
            ushort4v kv = *(const ushort4v*)(qkv + base + E);
            ushort4v vv = *(const ushort4v*)(qkv + base + 2 * E);
            *(float4*)&Ks[jj][d4] = make_float4(bfr2f(kv[0]), bfr2f(kv[1]), bfr2f(kv[2]), bfr2f(kv[3]));
            *(float4*)&Vs[jj][d4] = make_float4(bfr2f(vv[0]), bfr2f(vv[1]), bfr2f(vv[2]), bfr2f(vv[3]));
        }
        __syncthreads();

        float s[8] = {0.f, 0.f, 0.f, 0.f, 0.f, 0.f, 0.f, 0.f};
        #pragma unroll
        for (int d0 = 0; d0 < 64; d0 += 4) {
            float4 q4 = *(const float4*)&Qs[ql][d0];
            #pragma unroll
            for (int jl = 0; jl < 8; jl++) {
                float4 k4 = *(const float4*)&Ks[grp + jl * 8][d0];
                s[jl] += q4.x * k4.x + q4.y * k4.y + q4.z * k4.z + q4.w * k4.w;
            }
        }
        #pragma unroll
        for (int jl = 0; jl < 8; jl++)
            s[jl] += (1.0f - mask[b * SS + j0 + grp + jl * 8]) * -10000.0f;

        float cm = s[0];
        #pragma unroll
        for (int jl = 1; jl < 8; jl++) cm = fmaxf(cm, s[jl]);
        cm = fmaxf(cm, __shfl_xor(cm, 1, 64));
        cm = fmaxf(cm, __shfl_xor(cm, 2, 64));
        cm = fmaxf(cm, __shfl_xor(cm, 4, 64));

        float mnew = fmaxf(m_run, cm);
        float alpha = __expf(m_run - mnew);
        float ps = 0.f;
        #pragma unroll
        for (int jl = 0; jl < 8; jl++) {
            float p = __expf(s[jl] - mnew);
            Ps[ql][grp + jl * 8] = p;
            ps += p;
        }
        ps += __shfl_xor(ps, 1, 64);
        ps += __shfl_xor(ps, 2, 64);
        ps += __shfl_xor(ps, 4, 64);
        l_run = l_run * alpha + ps;
        m_run = mnew;
        #pragma unroll
        for (int e = 0; e < 8; e++) O[e] *= alpha;

        #pragma unroll 4
        for (int jj = 0; jj < 64; jj++) {
            float p = Ps[ql][jj];
            float4 v0 = *(const float4*)&Vs[jj][grp * 8];
            float4 v1 = *(const float4*)&Vs[jj][grp * 8 + 4];
            O[0] += p * v0.x; O[1] += p * v0.y; O[2] += p * v0.z; O[3] += p * v0.w;
            O[4] += p * v1.x; O[5] += p * v1.y; O[6] += p * v1.z; O[7] += p * v1.w;
        }
        __syncthreads();
    }

    float inv = 1.0f / l_run;
    int grow = b * SS + qt * 32 + ql;
    size_t obase = (size_t)grow * E3 + h * HD + grp * 8;
    #pragma unroll
    for (int e = 0; e < 8; e++)
        qkv[obase + e] = f2bfbits(O[e] * inv);
}

// =================================================================================
// Legacy (R4-proven) kernels — deep fallback if workspace is tiny
// =================================================================================
template <int FUSE, typename CT>
__global__ void gemm_legacy(const __hip_bfloat16* __restrict__ A, int lda,
                            const float* __restrict__ W, int ldw,
                            const float* __restrict__ bias,
                            CT* __restrict__ C, int ldc,
                            const float* __restrict__ resid,
                            int M, int N, int K) {
    __shared__ float As[16][65];
    __shared__ float Bs[16][65];
    int bm = blockIdx.y * 64, bn = blockIdx.x * 64;
    int tid = threadIdx.x;
    int ty = tid >> 4, tx = tid & 15;
    int ar = tid >> 2, ak = (tid & 3) << 2;
    int wk = tid >> 4, wn = (tid & 15) << 2;

    float acc[4][4] = {};
    for (int k0 = 0; k0 < K; k0 += 16) {
        ushort4 av = *(const ushort4*)(A + (size_t)(bm + ar) * lda + k0 + ak);
        As[ak + 0][ar] = bfr2f(av.x);
        As[ak + 1][ar] = bfr2f(av.y);
        As[ak + 2][ar] = bfr2f(av.z);
        As[ak + 3][ar] = bfr2f(av.w);
        float4 wv = *(const float4*)(W + (size_t)(k0 + wk) * ldw + bn + wn);
        Bs[wk][wn + 0] = wv.x;
        Bs[wk][wn + 1] = wv.y;
        Bs[wk][wn + 2] = wv.z;
        Bs[wk][wn + 3] = wv.w;
        __syncthreads();
        #pragma unroll
        for (int kk = 0; kk < 16; kk++) {
            float a[4], bv[4];
            #pragma unroll
            for (int i = 0; i < 4; i++) { a[i] = As[kk][ty * 4 + i]; bv[i] = Bs[kk][tx * 4 + i]; }
            #pragma unroll
            for (int i = 0; i < 4; i++)
                #pragma unroll
                for (int j = 0; j < 4; j++) acc[i][j] += a[i] * bv[j];
        }
        __syncthreads();
    }
    #pragma unroll
    for (int i = 0; i < 4; i++) {
        int row = bm + ty * 4 + i;
        #pragma unroll
        for (int j = 0; j < 4; j++) {
            int col = bn + tx * 4 + j;
            float v = acc[i][j];
            if (FUSE != 3) v += bias[col];
            if (FUSE == 1) v = 0.5f * v * (1.0f + erff(v * 0.70710678118654752f));
            if (FUSE == 2 || FUSE == 3) v += resid[(size_t)row * ldc + col];
            if constexpr (sizeof(CT) == 2) C[(size_t)row * ldc + col] = f2bf(v);
            else                           C[(size_t)row * ldc + col] = v;
        }
    }
}

__global__ void attn_legacy(const __hip_bfloat16* __restrict__ qkv,
                            const float* __restrict__ mask,
                            __hip_bfloat16* __restrict__ out) {
    __shared__ float sc[SS];
    __shared__ float qv[HD];
    __shared__ float oacc[4][HD];
    __shared__ float redbuf[4];

    int q = blockIdx.x & (SS - 1);
    int h = blockIdx.x >> 10;
    int tid = threadIdx.x;

    const __hip_bfloat16* qrow = qkv + (size_t)q * E3 + h * HD;
    if (tid < HD) qv[tid] = bf2f(qrow[tid]) * 0.125f;
    __syncthreads();

    for (int j = tid; j < SS; j += 256) {
        const __hip_bfloat16* krow = qkv + (size_t)j * E3 + E + h * HD;
        float d = 0.f;
        #pragma unroll
        for (int t = 0; t < HD; t += 4) {
            ushort4 kv4 = *(const ushort4*)(krow + t);
            d += qv[t] * bfr2f(kv4.x) + qv[t + 1] * bfr2f(kv4.y)
               + qv[t + 2] * bfr2f(kv4.z) + qv[t + 3] * bfr2f(kv4.w);
        }
        d += (1.0f - mask[j]) * -10000.0f;
        sc[j] = d;
    }
    __syncthreads();

    float m = -1e30f;
    for (int j = tid; j < SS; j += 256) m = fmaxf(m, sc[j]);
    m = block_max(m, redbuf);
    float s = 0.f;
    for (int j = tid; j < SS; j += 256) { float e = __expf(sc[j] - m); sc[j] = e; s += e; }
    s = block_sum(s, redbuf);
    float inv = 1.0f / s;
    __syncthreads();

    int d = tid & 63, c = tid >> 6;
    float acc = 0.f;
    int j0 = c * 256;
    for (int j = j0; j < j0 + 256; j++) {
        const __hip_bfloat16* vrow = qkv + (size_t)j * E3 + 2 * E + h * HD;
        acc += sc[j] * bf2f(vrow[d]);
    }
    oacc[c][d] = acc;
    __syncthreads();
    if (tid < HD) {
        float o = (oacc[0][tid] + oacc[1][tid] + oacc[2][tid] + oacc[3][tid]) * inv;
        out[(size_t)q * E + h * HD + tid] = f2bf(o);
    }
}

__global__ void copy_kernel(const float* __restrict__ in, float* __restrict__ out, int n) {
    int i = blockIdx.x * 256 + threadIdx.x;
    if (i < n) out[i] = in[i];
}

// =================================================================================
extern "C" void kernel_launch(void* const* d_in, const int* in_sizes, int n_in,
                              void* d_out, int out_size, void* d_ws, size_t ws_size,
                              hipStream_t stream) {
    const float* emb   = (const float*)d_in[0];
    const float* mask  = (const float*)d_in[1];
    const float* Wqkv  = (const float*)d_in[2];
    const float* bqkv  = (const float*)d_in[3];
    const float* Wo    = (const float*)d_in[4];
    const float* bo    = (const float*)d_in[5];
    const float* ln1g  = (const float*)d_in[6];
    const float* ln1b  = (const float*)d_in[7];
    const float* ln2g  = (const float*)d_in[8];
    const float* ln2b  = (const float*)d_in[9];
    const float* Wfc   = (const float*)d_in[10];
    const float* bfc   = (const float*)d_in[11];
    const float* Wmo   = (const float*)d_in[12];
    const float* bmo   = (const float*)d_in[13];
    const float* lnfg  = (const float*)d_in[14];
    const float* lnfb  = (const float*)d_in[15];

    const size_t NEED_FAST2 = sizeof(float) * (size_t)T * E
                            + 2ull * (size_t)T * E
                            + 2ull * (size_t)T * FFD
                            + 2ull * (size_t)E * FFD;
    const size_t NEED_FAST = sizeof(float) * (size_t)T * E
                           + 2ull * (size_t)T * E3
                           + sizeof(float2) * (size_t)T;

    if (ws_size >= NEED_FAST2) {
        // ---------------- FAST2 PATH: bf16 transposed weights + MFMA attention ----
        float* x            = (float*)d_ws;
        unsigned short* h   = (unsigned short*)(x + (size_t)T * E);       // [T,E]
        unsigned short* buf = h + (size_t)T * E;                          // [T,FFD] union
        unsigned short* wt  = buf + (size_t)T * FFD;                      // [<=E*FFD]
        unsigned short* qkv = buf;                                        // [T,E3]
        unsigned short* ff  = buf;                                        // [T,FFD]

        copy4_kernel<<<dim3(T * E / 4 / 256), dim3(256), 0, stream>>>(
            (const float4*)emb, (float4*)x, T * E / 4);

        for (int l = 0; l < LYR; l++) {
            const float* wqkv_l = Wqkv + (size_t)l * E * E3;
            const float* wo_l   = Wo   + (size_t)l * E * E;
            const float* wfc_l  = Wfc  + (size_t)l * E * FFD;
            const float* wmo_l  = Wmo  + (size_t)l * FFD * E;

            ln_kernel<__hip_bfloat16><<<dim3(T), dim3(256), 0, stream>>>(
                x, (__hip_bfloat16*)h, ln1g + l * E, ln1b + l * E);
            transpose_cvt<<<dim3(E3 / 32, E / 32), dim3(256), 0, stream>>>(wqkv_l, wt, E, E3);
            // QKV: 64x128 tile -> 576 blocks (was 288): 2+ blocks/CU for TLP
            gemm_bt<0, 64, 128><<<dim3(E3 / 128, T / 64), dim3(256), 0, stream>>>(
                h, E, wt, E, bqkv + l * E3, qkv, E3, E);
            attn_mfma<<<dim3(BB * NH * 16), dim3(256), 0, stream>>>(qkv, mask);
            transpose_cvt<<<dim3(E / 32, E / 32), dim3(256), 0, stream>>>(wo_l, wt, E, E);
            // Wo: split-K x2 -> 384 blocks of 6 K-iters (atomic residual add)
            gemm_bt<2, 64, 128><<<dim3(E / 128, T / 64, 2), dim3(256), 0, stream>>>(
                qkv, E3, wt, E, bo + l * E, x, E, E);

            ln_kernel<__hip_bfloat16><<<dim3(T), dim3(256), 0, stream>>>(
                x, (__hip_bfloat16*)h, ln2g + l * E, ln2b + l * E);
            transpose_cvt<<<dim3(FFD / 32, E / 32), dim3(256), 0, stream>>>(wfc_l, wt, E, FFD);
            // FC: 64x128 tile -> 768 blocks
            gemm_bt<1, 64, 128><<<dim3(FFD / 128, T / 64), dim3(256), 0, stream>>>(
                h, E, wt, E, bfc + l * FFD, ff, FFD, E);
            transpose_cvt<<<dim3(E / 32, FFD / 32), dim3(256), 0, stream>>>(wmo_l, wt, FFD, E);
            // Wmo: split-K x4 -> 768 blocks of 12 K-iters (atomic residual add)
            gemm_bt<2, 64, 128><<<dim3(E / 128, T / 64, 4), dim3(256), 0, stream>>>(
                ff, FFD, wt, FFD, bmo + l * E, x, E, FFD);
        }
        ln_kernel<float><<<dim3(T), dim3(256), 0, stream>>>(x, (float*)d_out, lnfg, lnfb);
    } else if (ws_size >= NEED_FAST) {
        // ---------------- FAST PATH (previous session, proven) ----------------
        float* x              = (float*)d_ws;
        unsigned short* qkv   = (unsigned short*)(x + (size_t)T * E);
        float2* musig         = (float2*)(qkv + (size_t)T * E3);

        copy4_kernel<<<dim3(T * E / 4 / 256), dim3(256), 0, stream>>>(
            (const float4*)emb, (float4*)x, T * E / 4);

        for (int l = 0; l < LYR; l++) {
            const float* wqkv_l = Wqkv + (size_t)l * E * E3;
            const float* wo_l   = Wo   + (size_t)l * E * E;
            const float* wfc_l  = Wfc  + (size_t)l * E * FFD;
            const float* wmo_l  = Wmo  + (size_t)l * FFD * E;

            rowstat_kernel<<<dim3(T), dim3(256), 0, stream>>>(x, musig);
            gemm_mfma<1, 0><<<dim3(E3 / 128, T / 128), dim3(256), 0, stream>>>(
                x, E, wqkv_l, E3, bqkv + l * E3, musig, ln1g + l * E, ln1b + l * E,
                qkv, E3, E);
            attn_flash<<<dim3(BB * NH * 32), dim3(256), 0, stream>>>(qkv, mask);
            gemm_mfma<0, 2><<<dim3(E / 128, T / 128), dim3(256), 0, stream>>>(
                qkv, E3, wo_l, E, bo + l * E, nullptr, nullptr, nullptr, x, E, E);

            unsigned short* ffp = qkv;
            unsigned short* hp  = qkv + (size_t)T * FH;
            ln_kernel<__hip_bfloat16><<<dim3(T), dim3(256), 0, stream>>>(
                x, (__hip_bfloat16*)hp, ln2g + l * E, ln2b + l * E);
            for (int f = 0; f < 2; f++) {
                gemm_mfma<0, 1><<<dim3(FH / 128, T / 128), dim3(256), 0, stream>>>(
                    hp, E, wfc_l + f * FH, FFD, bfc + l * FFD + f * FH,
                    nullptr, nullptr, nullptr, ffp, FH, E);
                if (f == 0)
                    gemm_mfma<0, 3><<<dim3(E / 128, T / 128), dim3(256), 0, stream>>>(
                        ffp, FH, wmo_l + (size_t)f * FH * E, E, nullptr, nullptr, nullptr, nullptr,
                        x, E, FH);
                else
                    gemm_mfma<0, 2><<<dim3(E / 128, T / 128), dim3(256), 0, stream>>>(
                        ffp, FH, wmo_l + (size_t)f * FH * E, E, bmo + l * E, nullptr, nullptr, nullptr,
                        x, E, FH);
            }
        }
        ln_kernel<float><<<dim3(T), dim3(256), 0, stream>>>(x, (float*)d_out, lnfg, lnfb);
    } else {
        // ---------------- LEGACY PATH (R4-proven, 12.58 MB) ----------------
        float* x           = (float*)d_ws;
        __hip_bfloat16* hb = (__hip_bfloat16*)(x + (size_t)T * E);
        __hip_bfloat16* qb = hb + (size_t)SS * E;

        int n = T * E;
        copy_kernel<<<dim3((n + 255) / 256), dim3(256), 0, stream>>>(emb, x, n);

        for (int l = 0; l < LYR; l++) {
            const float* wqkv_l = Wqkv + (size_t)l * E * E3;
            const float* wo_l   = Wo   + (size_t)l * E * E;
            const float* wfc_l  = Wfc  + (size_t)l * E * FFD;
            const float* wmo_l  = Wmo  + (size_t)l * FFD * E;

            for (int b = 0; b < BB; b++) {
                float* xb = x + (size_t)b * SS * E;
                ln_kernel<__hip_bfloat16><<<dim3(SS), dim3(256), 0, stream>>>(
                    xb, hb, ln1g + l * E, ln1b + l * E);
                gemm_legacy<0, __hip_bfloat16><<<dim3(E3 / 64, SS / 64), dim3(256), 0, stream>>>(
                    hb, E, wqkv_l, E3, bqkv + l * E3, qb, E3, nullptr, SS, E3, E);
                attn_legacy<<<dim3(NH * SS), dim3(256), 0, stream>>>(qb, mask + b * SS, hb);
                gemm_legacy<2, float><<<dim3(E / 64, SS / 64), dim3(256), 0, stream>>>(
                    hb, E, wo_l, E, bo + l * E, xb, E, xb, SS, E, E);
            }
            for (int b = 0; b < BB; b++) {
                float* xb = x + (size_t)b * SS * E;
                ln_kernel<__hip_bfloat16><<<dim3(SS), dim3(256), 0, stream>>>(
                    xb, hb, ln2g + l * E, ln2b + l * E);
                for (int f = 0; f < 2; f++) {
                    gemm_legacy<1, __hip_bfloat16><<<dim3(FH / 64, SS / 64), dim3(256), 0, stream>>>(
                        hb, E, wfc_l + f * FH, FFD, bfc + l * FFD + f * FH, qb, FH, nullptr,
                        SS, FH, E);
                    if (f == 0)
                        gemm_legacy<3, float><<<dim3(E / 64, SS / 64), dim3(256), 0, stream>>>(
                            qb, FH, wmo_l + (size_t)f * FH * E, E, nullptr, xb, E, xb, SS, E, FH);
                    else
                        gemm_legacy<2, float><<<dim3(E / 64, SS / 64), dim3(256), 0, stream>>>(
                            qb, FH, wmo_l + (size_t)f * FH * E, E, bmo + l * E, xb, E, xb, SS, E, FH);
                }
            }
        }
        ln_kernel<float><<<dim3(T), dim3(256), 0, stream>>>(x, (float*)d_out, lnfg, lnfb);
    }
}

// Round 4
// 1399.389 us; speedup vs baseline: 3.3935x; 1.0118x over previous
//
#include <hip/hip_runtime.h>
#include <hip/hip_bf16.h>
#include <math.h>

constexpr int LYR = 6;
constexpr int E   = 768;
constexpr int NH  = 12;
constexpr int FFD = 3072;
constexpr int HD  = 64;
constexpr int BB  = 2;
constexpr int SS  = 1024;
constexpr int T   = BB * SS;     // 2048 tokens
constexpr int E3  = 3 * E;       // 2304
constexpr int FH  = FFD / 2;     // 1536 (FFN slice width, legacy fast path)

#define LN_EPS 1e-5f

typedef __attribute__((ext_vector_type(8))) short    short8v;
typedef __attribute__((ext_vector_type(8))) unsigned short ushort8v;
typedef __attribute__((ext_vector_type(4))) unsigned short ushort4v;
typedef __attribute__((ext_vector_type(4))) float    f32x4;

__device__ __forceinline__ float bf2f(__hip_bfloat16 x) { return __bfloat162float(x); }
__device__ __forceinline__ float bfr2f(unsigned short u) {
    union { unsigned int i; float f; } v; v.i = ((unsigned int)u) << 16; return v.f;
}
__device__ __forceinline__ __hip_bfloat16 f2bf(float f) { return __float2bfloat16(f); }
// bf16 bits with round-to-nearest-even (finite inputs only)
__device__ __forceinline__ unsigned short f2bfbits(float f) {
    union { float f; unsigned int i; } v; v.f = f;
    unsigned int r = (v.i + 0x7fffu + ((v.i >> 16) & 1u)) >> 16;
    return (unsigned short)r;
}

// ---------------- block reductions (256 threads = 4 waves of 64) ----------------
__device__ __forceinline__ float block_sum(float v, float* sm) {
    #pragma unroll
    for (int o = 32; o > 0; o >>= 1) v += __shfl_down(v, o, 64);
    int lane = threadIdx.x & 63, wid = threadIdx.x >> 6;
    if (lane == 0) sm[wid] = v;
    __syncthreads();
    float r = sm[0] + sm[1] + sm[2] + sm[3];
    __syncthreads();
    return r;
}

__device__ __forceinline__ float block_max(float v, float* sm) {
    #pragma unroll
    for (int o = 32; o > 0; o >>= 1) v = fmaxf(v, __shfl_down(v, o, 64));
    int lane = threadIdx.x & 63, wid = threadIdx.x >> 6;
    if (lane == 0) sm[wid] = v;
    __syncthreads();
    float r = fmaxf(fmaxf(sm[0], sm[1]), fmaxf(sm[2], sm[3]));
    __syncthreads();
    return r;
}

// ---------------- f32 copy (embeddings -> residual stream), float4 ----------------
__global__ void copy4_kernel(const float4* __restrict__ in, float4* __restrict__ out, int n4) {
    int i = blockIdx.x * 256 + threadIdx.x;
    if (i < n4) out[i] = in[i];
}

// ---------------- per-row LN stats: musig[row] = (mu, rstd)  (legacy fast path) ---
__global__ void rowstat_kernel(const float* __restrict__ x, float2* __restrict__ musig) {
    __shared__ float sm[4];
    int row = blockIdx.x;
    const float* xr = x + (size_t)row * E;
    float s = 0.f;
    for (int i = threadIdx.x; i < E; i += 256) s += xr[i];
    float mu = block_sum(s, sm) * (1.0f / E);
    float v = 0.f;
    for (int i = threadIdx.x; i < E; i += 256) { float d = xr[i] - mu; v += d * d; }
    float rstd = rsqrtf(block_sum(v, sm) * (1.0f / E) + LN_EPS);
    if (threadIdx.x == 0) musig[row] = make_float2(mu, rstd);
}

// ---------------- LayerNorm: one block per row; x f32 -> out bf16 or f32 --------
template <typename OT>
__global__ void ln_kernel(const float* __restrict__ x, OT* __restrict__ out,
                          const float* __restrict__ g, const float* __restrict__ b) {
    __shared__ float sm[4];
    int row = blockIdx.x;
    const float* xr = x + (size_t)row * E;
    float s = 0.f;
    for (int i = threadIdx.x; i < E; i += 256) s += xr[i];
    float mu = block_sum(s, sm) * (1.0f / E);
    float v = 0.f;
    for (int i = threadIdx.x; i < E; i += 256) { float d = xr[i] - mu; v += d * d; }
    float rstd = rsqrtf(block_sum(v, sm) * (1.0f / E) + LN_EPS);
    for (int i = threadIdx.x; i < E; i += 256) {
        float o = (xr[i] - mu) * rstd * g[i] + b[i];
        if constexpr (sizeof(OT) == 2) out[(size_t)row * E + i] = f2bf(o);
        else                           out[(size_t)row * E + i] = o;
    }
}

// =================================================================================
// Weight transpose+convert: W f32 [K][N] -> Wt bf16 bits [N][K]
// =================================================================================
__global__ void transpose_cvt(const float* __restrict__ W, unsigned short* __restrict__ Wt,
                              int K, int N) {
    __shared__ float tile[32][33];
    int n0 = blockIdx.x * 32, k0 = blockIdx.y * 32;
    int tx = threadIdx.x & 31, ty = threadIdx.x >> 5;   // ty 0..7
    #pragma unroll
    for (int i = 0; i < 4; i++)
        tile[ty + i * 8][tx] = W[(size_t)(k0 + ty + i * 8) * N + n0 + tx];
    __syncthreads();
    #pragma unroll
    for (int i = 0; i < 4; i++)
        Wt[(size_t)(n0 + ty + i * 8) * K + k0 + tx] = f2bfbits(tile[tx][ty + i * 8]);
}

// =================================================================================
// MFMA GEMM, both operands bf16, B pre-transposed: C[M,N] = A @ Bt^T + epilogue.
// LDS rows padded to 80 ushorts = 160B (16B-aligned, conflict-floor b128).
// Split-K via gridDim.z (K must divide evenly; z>1 only valid with FUSE=2).
//   FUSE 0: C = A@B + bias -> bf16 | 1: gelu(...) -> bf16
//   FUSE 2: C += A@B + bias (f32, atomicAdd — safe under split-K; bias on z==0)
// =================================================================================
template <int FUSE, int BM, int BN>
__global__ __launch_bounds__(256) void gemm_bt(
        const unsigned short* __restrict__ A, int lda,
        const unsigned short* __restrict__ Bt, int ldb,
        const float* __restrict__ bias,
        void* __restrict__ Cptr, int ldc, int K) {
    constexpr int PAD = 80;
    constexpr int MFR = BM / 32, NFR = BN / 32;
    constexpr int AIT = BM / 32, BIT = BN / 32;
    __shared__ unsigned short As[BM * PAD];
    __shared__ unsigned short Bs[BN * PAD];

    int tid = threadIdx.x;
    int bm = blockIdx.y * BM, bn = blockIdx.x * BN;
    int kchunk = K / gridDim.z;
    int kbeg = blockIdx.z * kchunk, kend = kbeg + kchunk;
    int w = tid >> 6, lane = tid & 63, ln16 = lane & 15, q = lane >> 4;
    int wm = (w & 1) * (BM / 2), wn = (w >> 1) * (BN / 2);

    f32x4 acc[MFR][NFR];
    #pragma unroll
    for (int i = 0; i < MFR; i++)
        #pragma unroll
        for (int j = 0; j < NFR; j++) acc[i][j] = (f32x4){0.f, 0.f, 0.f, 0.f};

    for (int k0 = kbeg; k0 < kend; k0 += 64) {
        #pragma unroll
        for (int i = 0; i < AIT; i++) {
            int idx = tid + i * 256;
            int row = idx >> 3, ko = (idx & 7) * 8;
            *(ushort8v*)(&As[row * PAD + ko]) =
                *(const ushort8v*)(A + (size_t)(bm + row) * lda + k0 + ko);
        }
        #pragma unroll
        for (int i = 0; i < BIT; i++) {
            int idx = tid + i * 256;
            int row = idx >> 3, ko = (idx & 7) * 8;
            *(ushort8v*)(&Bs[row * PAD + ko]) =
                *(const ushort8v*)(Bt + (size_t)(bn + row) * ldb + k0 + ko);
        }
        __syncthreads();

        #pragma unroll
        for (int kk = 0; kk < 64; kk += 32) {
            short8v afr[MFR], bfr[NFR];
            #pragma unroll
            for (int i = 0; i < MFR; i++)
                afr[i] = *(const short8v*)(&As[(wm + i * 16 + ln16) * PAD + kk + q * 8]);
            #pragma unroll
            for (int j = 0; j < NFR; j++)
                bfr[j] = *(const short8v*)(&Bs[(wn + j * 16 + ln16) * PAD + kk + q * 8]);
            #pragma unroll
            for (int i = 0; i < MFR; i++)
                #pragma unroll
                for (int j = 0; j < NFR; j++)
                    acc[i][j] = __builtin_amdgcn_mfma_f32_16x16x32_bf16(afr[i], bfr[j], acc[i][j], 0, 0, 0);
        }
        __syncthreads();
    }

    #pragma unroll
    for (int j = 0; j < NFR; j++) {
        int col = bn + wn + j * 16 + ln16;
        float bv = (blockIdx.z == 0) ? bias[col] : 0.f;
        #pragma unroll
        for (int i = 0; i < MFR; i++) {
            #pragma unroll
            for (int r = 0; r < 4; r++) {
                int row = bm + wm + i * 16 + q * 4 + r;
                float v = acc[i][j][r] + bv;
                if (FUSE == 1) v = 0.5f * v * (1.0f + erff(v * 0.70710678118654752f));
                if (FUSE == 0 || FUSE == 1) {
                    ((unsigned short*)Cptr)[(size_t)row * ldc + col] = f2bfbits(v);
                } else {
                    atomicAdd(&((float*)Cptr)[(size_t)row * ldc + col], v);
                }
            }
        }
    }
}

// =================================================================================
// MFMA flash attention v2: one block per (b, h, 32-query tile); 2 waves x 16 q-rows.
// 768 blocks -> 3 resident blocks/CU (independent serial chains overlap).
// qkv bf16 bits [T][E3]; output written in place into the q-slot.
//   QK^T: A = Q frags (regs), B = K from LDS [j][d]    (k=d contiguous)
//   PV:   A = P from LDS [q][j],  B = Vt LDS [d][j]    (k=j contiguous)
// V transpose staged conflict-free: lane l writes column j=l -> banks l/2 (2-way floor).
// =================================================================================
__global__ __launch_bounds__(128) void attn_mfma(unsigned short* __restrict__ qkv,
                                                 const float* __restrict__ mask) {
    constexpr int KP = 80;   // Ks row pitch (ushorts)
    constexpr int VP = 80;   // Vt row pitch
    constexpr int PP = 82;   // Ps row pitch
    __shared__ unsigned short Ks[64 * KP];
    __shared__ unsigned short Vt[64 * VP];
    __shared__ unsigned short Ps[32 * PP];
    __shared__ float Ms[64];

    int bid = blockIdx.x;                 // b(2) x h(12) x qt(32)
    int qt = bid & 31;
    int h  = (bid >> 5) % NH;
    int b  = bid / (32 * NH);
    int tid = threadIdx.x;
    int w = tid >> 6, lane = tid & 63, ln16 = lane & 15, q4 = lane >> 4;

    // Q fragments in registers: wave w owns q-rows qt*32 + w*16 + ln16
    int qrow = b * SS + qt * 32 + w * 16 + ln16;
    const unsigned short* qbase = qkv + (size_t)qrow * E3 + h * HD;
    short8v qfr0 = *(const short8v*)(qbase + q4 * 8);
    short8v qfr1 = *(const short8v*)(qbase + 32 + q4 * 8);

    f32x4 sacc[4];           // QK^T acc: 4 j-frags (cols jf*16+ln16, rows q4*4+r)
    f32x4 oacc[4];           // PV acc:   4 d-frags
    float m_run[4], l_run[4];
    #pragma unroll
    for (int r = 0; r < 4; r++) { m_run[r] = -1e30f; l_run[r] = 0.f; }
    #pragma unroll
    for (int i = 0; i < 4; i++) oacc[i] = (f32x4){0.f, 0.f, 0.f, 0.f};

    for (int t = 0; t < 16; t++) {
        int j0 = t * 64;
        // ---- stage K rows (vector b128 writes) ----
        #pragma unroll
        for (int i = 0; i < 4; i++) {
            int idx = tid + i * 128;                  // 0..511
            int row = idx >> 3, ko = (idx & 7) * 8;
            size_t gb = (size_t)(b * SS + j0 + row) * E3 + h * HD;
            *(ushort8v*)(&Ks[row * KP + ko]) = *(const ushort8v*)(qkv + gb + E + ko);
        }
        // ---- stage V transposed, conflict-free: lane l owns column j = l ----
        // idx = tid + i*128: row(j) = lane, d-chunk = (w + 2i)*8
        #pragma unroll
        for (int i = 0; i < 4; i++) {
            int ko = (w + 2 * i) * 8;
            size_t gb = (size_t)(b * SS + j0 + lane) * E3 + h * HD + 2 * E + ko;
            ushort8v vv = *(const ushort8v*)(qkv + gb);
            #pragma unroll
            for (int e = 0; e < 8; e++)
                Vt[(ko + e) * VP + lane] = vv[e];     // banks = lane/2: 2-way floor
        }
        if (tid < 64) Ms[tid] = (1.0f - mask[b * SS + j0 + tid]) * -10000.0f;
        __syncthreads();

        // ---- QK^T ----
        #pragma unroll
        for (int jf = 0; jf < 4; jf++) sacc[jf] = (f32x4){0.f, 0.f, 0.f, 0.f};
        #pragma unroll
        for (int jf = 0; jf < 4; jf++) {
            short8v k0f = *(const short8v*)(&Ks[(jf * 16 + ln16) * KP + q4 * 8]);
            short8v k1f = *(const short8v*)(&Ks[(jf * 16 + ln16) * KP + 32 + q4 * 8]);
            sacc[jf] = __builtin_amdgcn_mfma_f32_16x16x32_bf16(qfr0, k0f, sacc[jf], 0, 0, 0);
            sacc[jf] = __builtin_amdgcn_mfma_f32_16x16x32_bf16(qfr1, k1f, sacc[jf], 0, 0, 0);
        }

        // ---- scale + mask ----
        float madd[4];
        #pragma unroll
        for (int jf = 0; jf < 4; jf++) madd[jf] = Ms[jf * 16 + ln16];
        #pragma unroll
        for (int jf = 0; jf < 4; jf++)
            #pragma unroll
            for (int r = 0; r < 4; r++)
                sacc[jf][r] = sacc[jf][r] * 0.125f + madd[jf];

        // ---- online softmax (per owned row r; 16-lane group reduce) ----
        #pragma unroll
        for (int r = 0; r < 4; r++) {
            float mx = fmaxf(fmaxf(sacc[0][r], sacc[1][r]), fmaxf(sacc[2][r], sacc[3][r]));
            mx = fmaxf(mx, __shfl_xor(mx, 1, 64));
            mx = fmaxf(mx, __shfl_xor(mx, 2, 64));
            mx = fmaxf(mx, __shfl_xor(mx, 4, 64));
            mx = fmaxf(mx, __shfl_xor(mx, 8, 64));
            float mnew = fmaxf(m_run[r], mx);
            float alpha = __expf(m_run[r] - mnew);
            m_run[r] = mnew;
            float ps = 0.f;
            #pragma unroll
            for (int jf = 0; jf < 4; jf++) {
                float p = __expf(sacc[jf][r] - mnew);
                sacc[jf][r] = p;
                ps += p;
            }
            ps += __shfl_xor(ps, 1, 64);
            ps += __shfl_xor(ps, 2, 64);
            ps += __shfl_xor(ps, 4, 64);
            ps += __shfl_xor(ps, 8, 64);
            l_run[r] = l_run[r] * alpha + ps;
            #pragma unroll
            for (int df = 0; df < 4; df++) oacc[df][r] *= alpha;
        }

        // ---- write P (bf16) to LDS; wave-local rows, no barrier needed ----
        #pragma unroll
        for (int jf = 0; jf < 4; jf++)
            #pragma unroll
            for (int r = 0; r < 4; r++)
                Ps[(w * 16 + q4 * 4 + r) * PP + jf * 16 + ln16] = f2bfbits(sacc[jf][r]);

        // ---- PV ----
        short8v pa0 = *(const short8v*)(&Ps[(w * 16 + ln16) * PP + q4 * 8]);
        short8v pa1 = *(const short8v*)(&Ps[(w * 16 + ln16) * PP + 32 + q4 * 8]);
        #pragma unroll
        for (int df = 0; df < 4; df++) {
            short8v v0f = *(const short8v*)(&Vt[(df * 16 + ln16) * VP + q4 * 8]);
            short8v v1f = *(const short8v*)(&Vt[(df * 16 + ln16) * VP + 32 + q4 * 8]);
            oacc[df] = __builtin_amdgcn_mfma_f32_16x16x32_bf16(pa0, v0f, oacc[df], 0, 0, 0);
            oacc[df] = __builtin_amdgcn_mfma_f32_16x16x32_bf16(pa1, v1f, oacc[df], 0, 0, 0);
        }
        __syncthreads();   // guard Ks/Vt overwrite next tile
    }

    // ---- normalize + write back into q-slot ----
    #pragma unroll
    for (int r = 0; r < 4; r++) {
        float inv = 1.0f / l_run[r];
        int row = b * SS + qt * 32 + w * 16 + q4 * 4 + r;
        size_t ob = (size_t)row * E3 + h * HD;
        #pragma unroll
        for (int df = 0; df < 4; df++)
            qkv[ob + df * 16 + ln16] = f2bfbits(oacc[df][r] * inv);
    }
}

// =================================================================================
// Legacy fast-path MFMA GEMM (f32 weights converted in-kernel) — fallback only.
// =================================================================================
template <int AMODE, int FUSE>
__global__ void gemm_mfma(const void* __restrict__ Aptr, int lda,
                          const float* __restrict__ W, int ldw,
                          const float* __restrict__ bias,
                          const float2* __restrict__ musig,
                          const float* __restrict__ lng, const float* __restrict__ lnb,
                          void* __restrict__ Cptr, int ldc, int K) {
    __shared__ unsigned short As[128 * 40];
    __shared__ unsigned short Bs[32 * 130];

    int tid = threadIdx.x;
    int bm = blockIdx.y * 128, bn = blockIdx.x * 128;
    int w = tid >> 6, lane = tid & 63, ln16 = lane & 15, q = lane >> 4;
    int wm = (w & 1) * 64, wn = (w >> 1) * 64;

    f32x4 acc[4][4];
    #pragma unroll
    for (int i = 0; i < 4; i++)
        #pragma unroll
        for (int j = 0; j < 4; j++) acc[i][j] = (f32x4){0.f, 0.f, 0.f, 0.f};

    for (int k0 = 0; k0 < K; k0 += 32) {
        if (AMODE == 0) {
            const unsigned short* A = (const unsigned short*)Aptr;
            #pragma unroll
            for (int i = 0; i < 2; i++) {
                int idx = tid + i * 256;
                int row = idx >> 2, ko = (idx & 3) * 8;
                ushort8v v = *(const ushort8v*)(A + (size_t)(bm + row) * lda + k0 + ko);
                *(ushort8v*)(&As[row * 40 + ko]) = v;
            }
        } else {
            const float* A = (const float*)Aptr;
            #pragma unroll
            for (int i = 0; i < 4; i++) {
                int idx = tid + i * 256;
                int row = idx >> 3, ko = (idx & 7) * 4;
                float4 xv = *(const float4*)(A + (size_t)(bm + row) * lda + k0 + ko);
                float2 ms = musig[bm + row];
                float4 gv = *(const float4*)(lng + k0 + ko);
                float4 bv = *(const float4*)(lnb + k0 + ko);
                ushort4v o;
                o[0] = f2bfbits((xv.x - ms.x) * ms.y * gv.x + bv.x);
                o[1] = f2bfbits((xv.y - ms.x) * ms.y * gv.y + bv.y);
                o[2] = f2bfbits((xv.z - ms.x) * ms.y * gv.z + bv.z);
                o[3] = f2bfbits((xv.w - ms.x) * ms.y * gv.w + bv.w);
                *(ushort4v*)(&As[row * 40 + ko]) = o;
            }
        }
        #pragma unroll
        for (int i = 0; i < 16; i++) {
            int idx = tid + i * 256;
            int kr = idx >> 7, n = idx & 127;
            float wv = W[(size_t)(k0 + kr) * ldw + bn + n];
            Bs[kr * 130 + n] = f2bfbits(wv);
        }
        __syncthreads();

        short8v afr[4], bfr[4];
        #pragma unroll
        for (int i = 0; i < 4; i++)
            afr[i] = *(const short8v*)(&As[(wm + i * 16 + ln16) * 40 + q * 8]);
        #pragma unroll
        for (int j = 0; j < 4; j++) {
            int n = wn + j * 16 + ln16;
            #pragma unroll
            for (int jj = 0; jj < 8; jj++)
                bfr[j][jj] = (short)Bs[(q * 8 + jj) * 130 + n];
        }
        #pragma unroll
        for (int i = 0; i < 4; i++)
            #pragma unroll
            for (int j = 0; j < 4; j++)
                acc[i][j] = __builtin_amdgcn_mfma_f32_16x16x32_bf16(afr[i], bfr[j], acc[i][j], 0, 0, 0);
        __syncthreads();
    }

    #pragma unroll
    for (int j = 0; j < 4; j++) {
        int col = bn + wn + j * 16 + ln16;
        float bv = (FUSE == 3) ? 0.f : bias[col];
        #pragma unroll
        for (int i = 0; i < 4; i++) {
            #pragma unroll
            for (int r = 0; r < 4; r++) {
                int row = bm + wm + i * 16 + q * 4 + r;
                float v = acc[i][j][r] + bv;
                if (FUSE == 1) v = 0.5f * v * (1.0f + erff(v * 0.70710678118654752f));
                if (FUSE == 0 || FUSE == 1) {
                    ((unsigned short*)Cptr)[(size_t)row * ldc + col] = f2bfbits(v);
                } else {
                    float* C = (float*)Cptr;
                    C[(size_t)row * ldc + col] += v;
                }
            }
        }
    }
}

// =================================================================================
// Legacy VALU flash attention (used by middle fallback path)
// =================================================================================
__global__ void attn_flash(unsigned short* __restrict__ qkv,
                           const float* __restrict__ mask) {
    __shared__ float Qs[32][68];
    __shared__ float Ks[64][68];
    __shared__ float Vs[64][68];
    __shared__ float Ps[32][68];

    int bid = blockIdx.x;                 // b(2) x h(12) x qt(32)
    int qt = bid & 31;
    int h  = (bid >> 5) % NH;
    int b  = bid / (32 * NH);
    int tid = threadIdx.x;
    int ql = tid >> 3, grp = tid & 7;

    #pragma unroll
    for (int i = 0; i < 8; i++) {
        int idx = tid + i * 256;
        int rq = idx >> 6, d = idx & 63;
        int grow = b * SS + qt * 32 + rq;
        Qs[rq][d] = bfr2f(qkv[(size_t)grow * E3 + h * HD + d]) * 0.125f;
    }

    float m_run = -1e30f, l_run = 0.f;
    float O[8] = {0.f, 0.f, 0.f, 0.f, 0.f, 0.f, 0.f, 0.f};

    for (int c = 0; c < 16; c++) {
        int j0 = c * 64;
        #pragma unroll
        for (int i = 0; i < 4; i++) {
            int idx = tid + i * 256;
            int jj = idx >> 4, d4 = (idx & 15) * 4;
            size_t base = (size_t)(b * SS + j0 + jj) * E3 + h * HD + d4;
            ushort4v kv = *(const ushort4v*)(qkv + base + E);
            ushort4v vv = *(const ushort4v*)(qkv + base + 2 * E);
            *(float4*)&Ks[jj][d4] = make_float4(bfr2f(kv[0]), bfr2f(kv[1]), bfr2f(kv[2]), bfr2f(kv[3]));
            *(float4*)&Vs[jj][d4] = make_float4(bfr2f(vv[0]), bfr2f(vv[1]), bfr2f(vv[2]), bfr2f(vv[3]));
        }
        __syncthreads();

        float s[8] = {0.f, 0.f, 0.f, 0.f, 0.f, 0.f, 0.f, 0.f};
        #pragma unroll
        for (int d0 = 0; d0 < 64; d0 += 4) {
            float4 q4 = *(const float4*)&Qs[ql][d0];
            #pragma unroll
            for (int jl = 0; jl < 8; jl++) {
                float4 k4 = *(const float4*)&Ks[grp + jl * 8][d0];
                s[jl] += q4.x * k4.x + q4.y * k4.y + q4.z * k4.z + q4.w * k4.w;
            }
        }
        #pragma unroll
        for (int jl = 0; jl < 8; jl++)
            s[jl] += (1.0f - mask[b * SS + j0 + grp + jl * 8]) * -10000.0f;

        float cm = s[0];
        #pragma unroll
        for (int jl = 1; jl < 8; jl++) cm = fmaxf(cm, s[jl]);
        cm = fmaxf(cm, __shfl_xor(cm, 1, 64));
        cm = fmaxf(cm, __shfl_xor(cm, 2, 64));
        cm = fmaxf(cm, __shfl_xor(cm, 4, 64));

        float mnew = fmaxf(m_run, cm);
        float alpha = __expf(m_run - mnew);
        float ps = 0.f;
        #pragma unroll
        for (int jl = 0; jl < 8; jl++) {
            float p = __expf(s[jl] - mnew);
            Ps[ql][grp + jl * 8] = p;
            ps += p;
        }
        ps += __shfl_xor(ps, 1, 64);
        ps += __shfl_xor(ps, 2, 64);
        ps += __shfl_xor(ps, 4, 64);
        l_run = l_run * alpha + ps;
        m_run = mnew;
        #pragma unroll
        for (int e = 0; e < 8; e++) O[e] *= alpha;

        #pragma unroll 4
        for (int jj = 0; jj < 64; jj++) {
            float p = Ps[ql][jj];
            float4 v0 = *(const float4*)&Vs[jj][grp * 8];
            float4 v1 = *(const float4*)&Vs[jj][grp * 8 + 4];
            O[0] += p * v0.x; O[1] += p * v0.y; O[2] += p * v0.z; O[3] += p * v0.w;
            O[4] += p * v1.x; O[5] += p * v1.y; O[6] += p * v1.z; O[7] += p * v1.w;
        }
        __syncthreads();
    }

    float inv = 1.0f / l_run;
    int grow = b * SS + qt * 32 + ql;
    size_t obase = (size_t)grow * E3 + h * HD + grp * 8;
    #pragma unroll
    for (int e = 0; e < 8; e++)
        qkv[obase + e] = f2bfbits(O[e] * inv);
}

// =================================================================================
// Legacy (R4-proven) kernels — deep fallback if workspace is tiny
// =================================================================================
template <int FUSE, typename CT>
__global__ void gemm_legacy(const __hip_bfloat16* __restrict__ A, int lda,
                            const float* __restrict__ W, int ldw,
                            const float* __restrict__ bias,
                            CT* __restrict__ C, int ldc,
                            const float* __restrict__ resid,
                            int M, int N, int K) {
    __shared__ float As[16][65];
    __shared__ float Bs[16][65];
    int bm = blockIdx.y * 64, bn = blockIdx.x * 64;
    int tid = threadIdx.x;
    int ty = tid >> 4, tx = tid & 15;
    int ar = tid >> 2, ak = (tid & 3) << 2;
    int wk = tid >> 4, wn = (tid & 15) << 2;

    float acc[4][4] = {};
    for (int k0 = 0; k0 < K; k0 += 16) {
        ushort4 av = *(const ushort4*)(A + (size_t)(bm + ar) * lda + k0 + ak);
        As[ak + 0][ar] = bfr2f(av.x);
        As[ak + 1][ar] = bfr2f(av.y);
        As[ak + 2][ar] = bfr2f(av.z);
        As[ak + 3][ar] = bfr2f(av.w);
        float4 wv = *(const float4*)(W + (size_t)(k0 + wk) * ldw + bn + wn);
        Bs[wk][wn + 0] = wv.x;
        Bs[wk][wn + 1] = wv.y;
        Bs[wk][wn + 2] = wv.z;
        Bs[wk][wn + 3] = wv.w;
        __syncthreads();
        #pragma unroll
        for (int kk = 0; kk < 16; kk++) {
            float a[4], bv[4];
            #pragma unroll
            for (int i = 0; i < 4; i++) { a[i] = As[kk][ty * 4 + i]; bv[i] = Bs[kk][tx * 4 + i]; }
            #pragma unroll
            for (int i = 0; i < 4; i++)
                #pragma unroll
                for (int j = 0; j < 4; j++) acc[i][j] += a[i] * bv[j];
        }
        __syncthreads();
    }
    #pragma unroll
    for (int i = 0; i < 4; i++) {
        int row = bm + ty * 4 + i;
        #pragma unroll
        for (int j = 0; j < 4; j++) {
            int col = bn + tx * 4 + j;
            float v = acc[i][j];
            if (FUSE != 3) v += bias[col];
            if (FUSE == 1) v = 0.5f * v * (1.0f + erff(v * 0.70710678118654752f));
            if (FUSE == 2 || FUSE == 3) v += resid[(size_t)row * ldc + col];
            if constexpr (sizeof(CT) == 2) C[(size_t)row * ldc + col] = f2bf(v);
            else                           C[(size_t)row * ldc + col] = v;
        }
    }
}

__global__ void attn_legacy(const __hip_bfloat16* __restrict__ qkv,
                            const float* __restrict__ mask,
                            __hip_bfloat16* __restrict__ out) {
    __shared__ float sc[SS];
    __shared__ float qv[HD];
    __shared__ float oacc[4][HD];
    __shared__ float redbuf[4];

    int q = blockIdx.x & (SS - 1);
    int h = blockIdx.x >> 10;
    int tid = threadIdx.x;

    const __hip_bfloat16* qrow = qkv + (size_t)q * E3 + h * HD;
    if (tid < HD) qv[tid] = bf2f(qrow[tid]) * 0.125f;
    __syncthreads();

    for (int j = tid; j < SS; j += 256) {
        const __hip_bfloat16* krow = qkv + (size_t)j * E3 + E + h * HD;
        float d = 0.f;
        #pragma unroll
        for (int t = 0; t < HD; t += 4) {
            ushort4 kv4 = *(const ushort4*)(krow + t);
            d += qv[t] * bfr2f(kv4.x) + qv[t + 1] * bfr2f(kv4.y)
               + qv[t + 2] * bfr2f(kv4.z) + qv[t + 3] * bfr2f(kv4.w);
        }
        d += (1.0f - mask[j]) * -10000.0f;
        sc[j] = d;
    }
    __syncthreads();

    float m = -1e30f;
    for (int j = tid; j < SS; j += 256) m = fmaxf(m, sc[j]);
    m = block_max(m, redbuf);
    float s = 0.f;
    for (int j = tid; j < SS; j += 256) { float e = __expf(sc[j] - m); sc[j] = e; s += e; }
    s = block_sum(s, redbuf);
    float inv = 1.0f / s;
    __syncthreads();

    int d = tid & 63, c = tid >> 6;
    float acc = 0.f;
    int j0 = c * 256;
    for (int j = j0; j < j0 + 256; j++) {
        const __hip_bfloat16* vrow = qkv + (size_t)j * E3 + 2 * E + h * HD;
        acc += sc[j] * bf2f(vrow[d]);
    }
    oacc[c][d] = acc;
    __syncthreads();
    if (tid < HD) {
        float o = (oacc[0][tid] + oacc[1][tid] + oacc[2][tid] + oacc[3][tid]) * inv;
        out[(size_t)q * E + h * HD + tid] = f2bf(o);
    }
}

__global__ void copy_kernel(const float* __restrict__ in, float* __restrict__ out, int n) {
    int i = blockIdx.x * 256 + threadIdx.x;
    if (i < n) out[i] = in[i];
}

// =================================================================================
extern "C" void kernel_launch(void* const* d_in, const int* in_sizes, int n_in,
                              void* d_out, int out_size, void* d_ws, size_t ws_size,
                              hipStream_t stream) {
    const float* emb   = (const float*)d_in[0];
    const float* mask  = (const float*)d_in[1];
    const float* Wqkv  = (const float*)d_in[2];
    const float* bqkv  = (const float*)d_in[3];
    const float* Wo    = (const float*)d_in[4];
    const float* bo    = (const float*)d_in[5];
    const float* ln1g  = (const float*)d_in[6];
    const float* ln1b  = (const float*)d_in[7];
    const float* ln2g  = (const float*)d_in[8];
    const float* ln2b  = (const float*)d_in[9];
    const float* Wfc   = (const float*)d_in[10];
    const float* bfc   = (const float*)d_in[11];
    const float* Wmo   = (const float*)d_in[12];
    const float* bmo   = (const float*)d_in[13];
    const float* lnfg  = (const float*)d_in[14];
    const float* lnfb  = (const float*)d_in[15];

    const size_t NEED_FAST2 = sizeof(float) * (size_t)T * E
                            + 2ull * (size_t)T * E
                            + 2ull * (size_t)T * FFD
                            + 2ull * (size_t)E * FFD;
    const size_t NEED_FAST = sizeof(float) * (size_t)T * E
                           + 2ull * (size_t)T * E3
                           + sizeof(float2) * (size_t)T;

    if (ws_size >= NEED_FAST2) {
        // ---------------- FAST2 PATH: bf16 transposed weights + MFMA attention ----
        float* x            = (float*)d_ws;
        unsigned short* h   = (unsigned short*)(x + (size_t)T * E);       // [T,E]
        unsigned short* buf = h + (size_t)T * E;                          // [T,FFD] union
        unsigned short* wt  = buf + (size_t)T * FFD;                      // [<=E*FFD]
        unsigned short* qkv = buf;                                        // [T,E3]
        unsigned short* ff  = buf;                                        // [T,FFD]

        copy4_kernel<<<dim3(T * E / 4 / 256), dim3(256), 0, stream>>>(
            (const float4*)emb, (float4*)x, T * E / 4);

        for (int l = 0; l < LYR; l++) {
            const float* wqkv_l = Wqkv + (size_t)l * E * E3;
            const float* wo_l   = Wo   + (size_t)l * E * E;
            const float* wfc_l  = Wfc  + (size_t)l * E * FFD;
            const float* wmo_l  = Wmo  + (size_t)l * FFD * E;

            ln_kernel<__hip_bfloat16><<<dim3(T), dim3(256), 0, stream>>>(
                x, (__hip_bfloat16*)h, ln1g + l * E, ln1b + l * E);
            transpose_cvt<<<dim3(E3 / 32, E / 32), dim3(256), 0, stream>>>(wqkv_l, wt, E, E3);
            // QKV: 64x128 tile -> 576 blocks
            gemm_bt<0, 64, 128><<<dim3(E3 / 128, T / 64), dim3(256), 0, stream>>>(
                h, E, wt, E, bqkv + l * E3, qkv, E3, E);
            // attention: 768 blocks x 128 thr (2 waves, QBLK=32)
            attn_mfma<<<dim3(BB * NH * 32), dim3(128), 0, stream>>>(qkv, mask);
            transpose_cvt<<<dim3(E / 32, E / 32), dim3(256), 0, stream>>>(wo_l, wt, E, E);
            // Wo: split-K x2 -> 384 blocks of 6 K-iters (atomic residual add)
            gemm_bt<2, 64, 128><<<dim3(E / 128, T / 64, 2), dim3(256), 0, stream>>>(
                qkv, E3, wt, E, bo + l * E, x, E, E);

            ln_kernel<__hip_bfloat16><<<dim3(T), dim3(256), 0, stream>>>(
                x, (__hip_bfloat16*)h, ln2g + l * E, ln2b + l * E);
            transpose_cvt<<<dim3(FFD / 32, E / 32), dim3(256), 0, stream>>>(wfc_l, wt, E, FFD);
            // FC: 64x128 tile -> 768 blocks
            gemm_bt<1, 64, 128><<<dim3(FFD / 128, T / 64), dim3(256), 0, stream>>>(
                h, E, wt, E, bfc + l * FFD, ff, FFD, E);
            transpose_cvt<<<dim3(E / 32, FFD / 32), dim3(256), 0, stream>>>(wmo_l, wt, FFD, E);
            // Wmo: split-K x4 -> 768 blocks of 12 K-iters (atomic residual add)
            gemm_bt<2, 64, 128><<<dim3(E / 128, T / 64, 4), dim3(256), 0, stream>>>(
                ff, FFD, wt, FFD, bmo + l * E, x, E, FFD);
        }
        ln_kernel<float><<<dim3(T), dim3(256), 0, stream>>>(x, (float*)d_out, lnfg, lnfb);
    } else if (ws_size >= NEED_FAST) {
        // ---------------- FAST PATH (previous session, proven) ----------------
        float* x              = (float*)d_ws;
        unsigned short* qkv   = (unsigned short*)(x + (size_t)T * E);
        float2* musig         = (float2*)(qkv + (size_t)T * E3);

        copy4_kernel<<<dim3(T * E / 4 / 256), dim3(256), 0, stream>>>(
            (const float4*)emb, (float4*)x, T * E / 4);

        for (int l = 0; l < LYR; l++) {
            const float* wqkv_l = Wqkv + (size_t)l * E * E3;
            const float* wo_l   = Wo   + (size_t)l * E * E;
            const float* wfc_l  = Wfc  + (size_t)l * E * FFD;
            const float* wmo_l  = Wmo  + (size_t)l * FFD * E;

            rowstat_kernel<<<dim3(T), dim3(256), 0, stream>>>(x, musig);
            gemm_mfma<1, 0><<<dim3(E3 / 128, T / 128), dim3(256), 0, stream>>>(
                x, E, wqkv_l, E3, bqkv + l * E3, musig, ln1g + l * E, ln1b + l * E,
                qkv, E3, E);
            attn_flash<<<dim3(BB * NH * 32), dim3(256), 0, stream>>>(qkv, mask);
            gemm_mfma<0, 2><<<dim3(E / 128, T / 128), dim3(256), 0, stream>>>(
                qkv, E3, wo_l, E, bo + l * E, nullptr, nullptr, nullptr, x, E, E);

            unsigned short* ffp = qkv;
            unsigned short* hp  = qkv + (size_t)T * FH;
            ln_kernel<__hip_bfloat16><<<dim3(T), dim3(256), 0, stream>>>(
                x, (__hip_bfloat16*)hp, ln2g + l * E, ln2b + l * E);
            for (int f = 0; f < 2; f++) {
                gemm_mfma<0, 1><<<dim3(FH / 128, T / 128), dim3(256), 0, stream>>>(
                    hp, E, wfc_l + f * FH, FFD, bfc + l * FFD + f * FH,
                    nullptr, nullptr, nullptr, ffp, FH, E);
                if (f == 0)
                    gemm_mfma<0, 3><<<dim3(E / 128, T / 128), dim3(256), 0, stream>>>(
                        ffp, FH, wmo_l + (size_t)f * FH * E, E, nullptr, nullptr, nullptr, nullptr,
                        x, E, FH);
                else
                    gemm_mfma<0, 2><<<dim3(E / 128, T / 128), dim3(256), 0, stream>>>(
                        ffp, FH, wmo_l + (size_t)f * FH * E, E, bmo + l * E, nullptr, nullptr, nullptr,
                        x, E, FH);
            }
        }
        ln_kernel<float><<<dim3(T), dim3(256), 0, stream>>>(x, (float*)d_out, lnfg, lnfb);
    } else {
        // ---------------- LEGACY PATH (R4-proven, 12.58 MB) ----------------
        float* x           = (float*)d_ws;
        __hip_bfloat16* hb = (__hip_bfloat16*)(x + (size_t)T * E);
        __hip_bfloat16* qb = hb + (size_t)SS * E;

        int n = T * E;
        copy_kernel<<<dim3((n + 255) / 256), dim3(256), 0, stream>>>(emb, x, n);

        for (int l = 0; l < LYR; l++) {
            const float* wqkv_l = Wqkv + (size_t)l * E * E3;
            const float* wo_l   = Wo   + (size_t)l * E * E;
            const float* wfc_l  = Wfc  + (size_t)l * E * FFD;
            const float* wmo_l  = Wmo  + (size_t)l * FFD * E;

            for (int b = 0; b < BB; b++) {
                float* xb = x + (size_t)b * SS * E;
                ln_kernel<__hip_bfloat16><<<dim3(SS), dim3(256), 0, stream>>>(
                    xb, hb, ln1g + l * E, ln1b + l * E);
                gemm_legacy<0, __hip_bfloat16><<<dim3(E3 / 64, SS / 64), dim3(256), 0, stream>>>(
                    hb, E, wqkv_l, E3, bqkv + l * E3, qb, E3, nullptr, SS, E3, E);
                attn_legacy<<<dim3(NH * SS), dim3(256), 0, stream>>>(qb, mask + b * SS, hb);
                gemm_legacy<2, float><<<dim3(E / 64, SS / 64), dim3(256), 0, stream>>>(
                    hb, E, wo_l, E, bo + l * E, xb, E, xb, SS, E, E);
            }
            for (int b = 0; b < BB; b++) {
                float* xb = x + (size_t)b * SS * E;
                ln_kernel<__hip_bfloat16><<<dim3(SS), dim3(256), 0, stream>>>(
                    xb, hb, ln2g + l * E, ln2b + l * E);
                for (int f = 0; f < 2; f++) {
                    gemm_legacy<1, __hip_bfloat16><<<dim3(FH / 64, SS / 64), dim3(256), 0, stream>>>(
                        hb, E, wfc_l + f * FH, FFD, bfc + l * FFD + f * FH, qb, FH, nullptr,
                        SS, FH, E);
                    if (f == 0)
                        gemm_legacy<3, float><<<dim3(E / 64, SS / 64), dim3(256), 0, stream>>>(
                            qb, FH, wmo_l + (size_t)f * FH * E, E, nullptr, xb, E, xb, SS, E, FH);
                    else
                        gemm_legacy<2, float><<<dim3(E / 64, SS / 64), dim3(256), 0, stream>>>(
                            qb, FH, wmo_l + (size_t)f * FH * E, E, bmo + l * E, xb, E, xb, SS, E, FH);
                }
            }
        }
        ln_kernel<float><<<dim3(T), dim3(256), 0, stream>>>(x, (float*)d_out, lnfg, lnfb);
    }
}

// Round 6
// 1109.637 us; speedup vs baseline: 4.2796x; 1.2611x over previous
//
#include <hip/hip_runtime.h>
#include <hip/hip_bf16.h>
#include <math.h>

constexpr int LYR = 6;
constexpr int E   = 768;
constexpr int NH  = 12;
constexpr int FFD = 3072;
constexpr int HD  = 64;
constexpr int BB  = 2;
constexpr int SS  = 1024;
constexpr int T   = BB * SS;     // 2048 tokens
constexpr int E3  = 3 * E;       // 2304
constexpr int FH  = FFD / 2;     // 1536 (FFN slice width, legacy fast path)

// per-layer transposed-weight slab (elements)
constexpr size_t SZ_QKV_T = (size_t)E3 * E;     // [E3][E]
constexpr size_t SZ_WO_T  = (size_t)E * E;      // [E][E]
constexpr size_t SZ_WFC_T = (size_t)FFD * E;    // [FFD][E]
constexpr size_t SZ_WMO_T = (size_t)E * FFD;    // [E][FFD]
constexpr size_t LSZ      = SZ_QKV_T + SZ_WO_T + SZ_WFC_T + SZ_WMO_T;  // 7,077,888
// 32x32 tile counts for the fused transpose
constexpr int TQ = (E3 / 32) * (E / 32);        // 1728
constexpr int TO = (E / 32) * (E / 32);         // 576
constexpr int TF = (FFD / 32) * (E / 32);       // 2304
constexpr int TM = (E / 32) * (FFD / 32);       // 2304
constexpr int TL = TQ + TO + TF + TM;           // 6912

#define LN_EPS 1e-5f

typedef __attribute__((ext_vector_type(8))) short    short8v;
typedef __attribute__((ext_vector_type(8))) unsigned short ushort8v;
typedef __attribute__((ext_vector_type(4))) unsigned short ushort4v;
typedef __attribute__((ext_vector_type(4))) float    f32x4;

__device__ __forceinline__ float bf2f(__hip_bfloat16 x) { return __bfloat162float(x); }
__device__ __forceinline__ float bfr2f(unsigned short u) {
    union { unsigned int i; float f; } v; v.i = ((unsigned int)u) << 16; return v.f;
}
__device__ __forceinline__ __hip_bfloat16 f2bf(float f) { return __float2bfloat16(f); }
// bf16 bits with round-to-nearest-even (finite inputs only)
__device__ __forceinline__ unsigned short f2bfbits(float f) {
    union { float f; unsigned int i; } v; v.f = f;
    unsigned int r = (v.i + 0x7fffu + ((v.i >> 16) & 1u)) >> 16;
    return (unsigned short)r;
}

// ---------------- block reductions (256 threads = 4 waves of 64) ----------------
__device__ __forceinline__ float block_sum(float v, float* sm) {
    #pragma unroll
    for (int o = 32; o > 0; o >>= 1) v += __shfl_down(v, o, 64);
    int lane = threadIdx.x & 63, wid = threadIdx.x >> 6;
    if (lane == 0) sm[wid] = v;
    __syncthreads();
    float r = sm[0] + sm[1] + sm[2] + sm[3];
    __syncthreads();
    return r;
}

__device__ __forceinline__ float block_max(float v, float* sm) {
    #pragma unroll
    for (int o = 32; o > 0; o >>= 1) v = fmaxf(v, __shfl_down(v, o, 64));
    int lane = threadIdx.x & 63, wid = threadIdx.x >> 6;
    if (lane == 0) sm[wid] = v;
    __syncthreads();
    float r = fmaxf(fmaxf(sm[0], sm[1]), fmaxf(sm[2], sm[3]));
    __syncthreads();
    return r;
}

// ---------------- f32 copy (embeddings -> residual stream), float4 ----------------
__global__ void copy4_kernel(const float4* __restrict__ in, float4* __restrict__ out, int n4) {
    int i = blockIdx.x * 256 + threadIdx.x;
    if (i < n4) out[i] = in[i];
}

// ---------------- per-row LN stats: musig[row] = (mu, rstd)  (legacy fast path) ---
__global__ void rowstat_kernel(const float* __restrict__ x, float2* __restrict__ musig) {
    __shared__ float sm[4];
    int row = blockIdx.x;
    const float* xr = x + (size_t)row * E;
    float s = 0.f;
    for (int i = threadIdx.x; i < E; i += 256) s += xr[i];
    float mu = block_sum(s, sm) * (1.0f / E);
    float v = 0.f;
    for (int i = threadIdx.x; i < E; i += 256) { float d = xr[i] - mu; v += d * d; }
    float rstd = rsqrtf(block_sum(v, sm) * (1.0f / E) + LN_EPS);
    if (threadIdx.x == 0) musig[row] = make_float2(mu, rstd);
}

// ---------------- LayerNorm: one block per row; x f32 -> out bf16 or f32 --------
template <typename OT>
__global__ void ln_kernel(const float* __restrict__ x, OT* __restrict__ out,
                          const float* __restrict__ g, const float* __restrict__ b) {
    __shared__ float sm[4];
    int row = blockIdx.x;
    const float* xr = x + (size_t)row * E;
    float s = 0.f;
    for (int i = threadIdx.x; i < E; i += 256) s += xr[i];
    float mu = block_sum(s, sm) * (1.0f / E);
    float v = 0.f;
    for (int i = threadIdx.x; i < E; i += 256) { float d = xr[i] - mu; v += d * d; }
    float rstd = rsqrtf(block_sum(v, sm) * (1.0f / E) + LN_EPS);
    for (int i = threadIdx.x; i < E; i += 256) {
        float o = (xr[i] - mu) * rstd * g[i] + b[i];
        if constexpr (sizeof(OT) == 2) out[(size_t)row * E + i] = f2bf(o);
        else                           out[(size_t)row * E + i] = o;
    }
}

// ---------------- transpose tile body: W f32 [K][N] -> Wt bf16 [N][K], 32x32 ------
__device__ __forceinline__ void transpose_tile(const float* __restrict__ W,
                                               unsigned short* __restrict__ Wt,
                                               int K, int N, int n0, int k0) {
    __shared__ float tile[32][33];
    int tx = threadIdx.x & 31, ty = threadIdx.x >> 5;   // ty 0..7
    #pragma unroll
    for (int i = 0; i < 4; i++)
        tile[ty + i * 8][tx] = W[(size_t)(k0 + ty + i * 8) * N + n0 + tx];
    __syncthreads();
    #pragma unroll
    for (int i = 0; i < 4; i++)
        Wt[(size_t)(n0 + ty + i * 8) * K + k0 + tx] = f2bfbits(tile[tx][ty + i * 8]);
}

// per-layer single-weight transpose (FAST2 tier)
__global__ void transpose_cvt(const float* __restrict__ W, unsigned short* __restrict__ Wt,
                              int K, int N) {
    transpose_tile(W, Wt, K, N, blockIdx.x * 32, blockIdx.y * 32);
}

// fused all-layers all-weights transpose (FAST3 tier): one dispatch.
__global__ void transpose_all(const float* __restrict__ Wqkv, const float* __restrict__ Wo,
                              const float* __restrict__ Wfc, const float* __restrict__ Wmo,
                              unsigned short* __restrict__ wt_all) {
    int bid = blockIdx.x;
    int layer = bid / TL, lid = bid % TL;
    unsigned short* dst = wt_all + (size_t)layer * LSZ;
    const float* W; int K, N, t;
    if (lid < TQ)                { W = Wqkv + (size_t)layer * E * E3;  K = E;   N = E3;  t = lid; }
    else if (lid < TQ + TO)      { W = Wo   + (size_t)layer * E * E;   K = E;   N = E;   t = lid - TQ;
                                   dst += SZ_QKV_T; }
    else if (lid < TQ + TO + TF) { W = Wfc  + (size_t)layer * E * FFD; K = E;   N = FFD; t = lid - TQ - TO;
                                   dst += SZ_QKV_T + SZ_WO_T; }
    else                         { W = Wmo  + (size_t)layer * FFD * E; K = FFD; N = E;   t = lid - TQ - TO - TF;
                                   dst += SZ_QKV_T + SZ_WO_T + SZ_WFC_T; }
    int nt = N / 32;
    transpose_tile(W, dst, K, N, (t % nt) * 32, (t / nt) * 32);
}

// =================================================================================
// MFMA GEMM, 8 waves (512 thr), tile 64x128, wave-tile 32x32. Both operands bf16,
// B pre-transposed: C[M,N] = A @ Bt^T + epilogue. LDS rows padded to 80 ushorts
// (160B, 16B-aligned; measured conflict-free). Split-K via gridDim.z (FUSE=2 only).
//   FUSE 0: C = A@B + bias -> bf16 | 1: gelu(...) -> bf16
//   FUSE 2: C += A@B + bias (f32 atomicAdd; bias applied by z==0)
// Grid geometry unchanged vs 4-wave version; waves/CU doubles (latency hiding).
// =================================================================================
template <int FUSE>
__global__ __launch_bounds__(512) void gemm_bt(
        const unsigned short* __restrict__ A, int lda,
        const unsigned short* __restrict__ Bt, int ldb,
        const float* __restrict__ bias,
        void* __restrict__ Cptr, int ldc, int K) {
    constexpr int BM = 64, BN = 128, PAD = 80;
    constexpr int MFR = 2, NFR = 2;
    __shared__ unsigned short As[BM * PAD];
    __shared__ unsigned short Bs[BN * PAD];

    int tid = threadIdx.x;
    int bm = blockIdx.y * BM, bn = blockIdx.x * BN;
    int kchunk = K / gridDim.z;
    int kbeg = blockIdx.z * kchunk, kend = kbeg + kchunk;
    int w = tid >> 6, lane = tid & 63, ln16 = lane & 15, q = lane >> 4;
    int wm = (w & 1) * 32, wn = (w >> 1) * 32;

    f32x4 acc[MFR][NFR];
    #pragma unroll
    for (int i = 0; i < MFR; i++)
        #pragma unroll
        for (int j = 0; j < NFR; j++) acc[i][j] = (f32x4){0.f, 0.f, 0.f, 0.f};

    for (int k0 = kbeg; k0 < kend; k0 += 64) {
        // ---- stage A: 64x64 elems, 512 thr x 8 ----
        {
            int row = tid >> 3, ko = (tid & 7) * 8;
            *(ushort8v*)(&As[row * PAD + ko]) =
                *(const ushort8v*)(A + (size_t)(bm + row) * lda + k0 + ko);
        }
        // ---- stage B: 128x64 elems ----
        #pragma unroll
        for (int i = 0; i < 2; i++) {
            int idx = tid + i * 512;
            int row = idx >> 3, ko = (idx & 7) * 8;
            *(ushort8v*)(&Bs[row * PAD + ko]) =
                *(const ushort8v*)(Bt + (size_t)(bn + row) * ldb + k0 + ko);
        }
        __syncthreads();

        #pragma unroll
        for (int kk = 0; kk < 64; kk += 32) {
            short8v afr[MFR], bfr[NFR];
            #pragma unroll
            for (int i = 0; i < MFR; i++)
                afr[i] = *(const short8v*)(&As[(wm + i * 16 + ln16) * PAD + kk + q * 8]);
            #pragma unroll
            for (int j = 0; j < NFR; j++)
                bfr[j] = *(const short8v*)(&Bs[(wn + j * 16 + ln16) * PAD + kk + q * 8]);
            #pragma unroll
            for (int i = 0; i < MFR; i++)
                #pragma unroll
                for (int j = 0; j < NFR; j++)
                    acc[i][j] = __builtin_amdgcn_mfma_f32_16x16x32_bf16(afr[i], bfr[j], acc[i][j], 0, 0, 0);
        }
        __syncthreads();
    }

    #pragma unroll
    for (int j = 0; j < NFR; j++) {
        int col = bn + wn + j * 16 + ln16;
        float bv = (blockIdx.z == 0) ? bias[col] : 0.f;
        #pragma unroll
        for (int i = 0; i < MFR; i++) {
            #pragma unroll
            for (int r = 0; r < 4; r++) {
                int row = bm + wm + i * 16 + q * 4 + r;
                float v = acc[i][j][r] + bv;
                if (FUSE == 1) v = 0.5f * v * (1.0f + erff(v * 0.70710678118654752f));
                if (FUSE == 0 || FUSE == 1) {
                    ((unsigned short*)Cptr)[(size_t)row * ldc + col] = f2bfbits(v);
                } else {
                    atomicAdd(&((float*)Cptr)[(size_t)row * ldc + col], v);
                }
            }
        }
    }
}

// =================================================================================
// MFMA flash attention v2 (R4-proven): one block per (b, h, 32-query tile);
// 2 waves x 16 q-rows; conflict-free V transpose staging.
// =================================================================================
__global__ __launch_bounds__(128) void attn_mfma(unsigned short* __restrict__ qkv,
                                                 const float* __restrict__ mask) {
    constexpr int KP = 80;   // Ks row pitch (ushorts)
    constexpr int VP = 80;   // Vt row pitch
    constexpr int PP = 82;   // Ps row pitch
    __shared__ unsigned short Ks[64 * KP];
    __shared__ unsigned short Vt[64 * VP];
    __shared__ unsigned short Ps[32 * PP];
    __shared__ float Ms[64];

    int bid = blockIdx.x;                 // b(2) x h(12) x qt(32)
    int qt = bid & 31;
    int h  = (bid >> 5) % NH;
    int b  = bid / (32 * NH);
    int tid = threadIdx.x;
    int w = tid >> 6, lane = tid & 63, ln16 = lane & 15, q4 = lane >> 4;

    int qrow = b * SS + qt * 32 + w * 16 + ln16;
    const unsigned short* qbase = qkv + (size_t)qrow * E3 + h * HD;
    short8v qfr0 = *(const short8v*)(qbase + q4 * 8);
    short8v qfr1 = *(const short8v*)(qbase + 32 + q4 * 8);

    f32x4 sacc[4];
    f32x4 oacc[4];
    float m_run[4], l_run[4];
    #pragma unroll
    for (int r = 0; r < 4; r++) { m_run[r] = -1e30f; l_run[r] = 0.f; }
    #pragma unroll
    for (int i = 0; i < 4; i++) oacc[i] = (f32x4){0.f, 0.f, 0.f, 0.f};

    for (int t = 0; t < 16; t++) {
        int j0 = t * 64;
        #pragma unroll
        for (int i = 0; i < 4; i++) {
            int idx = tid + i * 128;                  // 0..511
            int row = idx >> 3, ko = (idx & 7) * 8;
            size_t gb = (size_t)(b * SS + j0 + row) * E3 + h * HD;
            *(ushort8v*)(&Ks[row * KP + ko]) = *(const ushort8v*)(qkv + gb + E + ko);
        }
        #pragma unroll
        for (int i = 0; i < 4; i++) {
            int ko = (w + 2 * i) * 8;
            size_t gb = (size_t)(b * SS + j0 + lane) * E3 + h * HD + 2 * E + ko;
            ushort8v vv = *(const ushort8v*)(qkv + gb);
            #pragma unroll
            for (int e = 0; e < 8; e++)
                Vt[(ko + e) * VP + lane] = vv[e];     // banks = lane/2: 2-way floor
        }
        if (tid < 64) Ms[tid] = (1.0f - mask[b * SS + j0 + tid]) * -10000.0f;
        __syncthreads();

        #pragma unroll
        for (int jf = 0; jf < 4; jf++) sacc[jf] = (f32x4){0.f, 0.f, 0.f, 0.f};
        #pragma unroll
        for (int jf = 0; jf < 4; jf++) {
            short8v k0f = *(const short8v*)(&Ks[(jf * 16 + ln16) * KP + q4 * 8]);
            short8v k1f = *(const short8v*)(&Ks[(jf * 16 + ln16) * KP + 32 + q4 * 8]);
            sacc[jf] = __builtin_amdgcn_mfma_f32_16x16x32_bf16(qfr0, k0f, sacc[jf], 0, 0, 0);
            sacc[jf] = __builtin_amdgcn_mfma_f32_16x16x32_bf16(qfr1, k1f, sacc[jf], 0, 0, 0);
        }

        float madd[4];
        #pragma unroll
        for (int jf = 0; jf < 4; jf++) madd[jf] = Ms[jf * 16 + ln16];
        #pragma unroll
        for (int jf = 0; jf < 4; jf++)
            #pragma unroll
            for (int r = 0; r < 4; r++)
                sacc[jf][r] = sacc[jf][r] * 0.125f + madd[jf];

        #pragma unroll
        for (int r = 0; r < 4; r++) {
            float mx = fmaxf(fmaxf(sacc[0][r], sacc[1][r]), fmaxf(sacc[2][r], sacc[3][r]));
            mx = fmaxf(mx, __shfl_xor(mx, 1, 64));
            mx = fmaxf(mx, __shfl_xor(mx, 2, 64));
            mx = fmaxf(mx, __shfl_xor(mx, 4, 64));
            mx = fmaxf(mx, __shfl_xor(mx, 8, 64));
            float mnew = fmaxf(m_run[r], mx);
            float alpha = __expf(m_run[r] - mnew);
            m_run[r] = mnew;
            float ps = 0.f;
            #pragma unroll
            for (int jf = 0; jf < 4; jf++) {
                float p = __expf(sacc[jf][r] - mnew);
                sacc[jf][r] = p;
                ps += p;
            }
            ps += __shfl_xor(ps, 1, 64);
            ps += __shfl_xor(ps, 2, 64);
            ps += __shfl_xor(ps, 4, 64);
            ps += __shfl_xor(ps, 8, 64);
            l_run[r] = l_run[r] * alpha + ps;
            #pragma unroll
            for (int df = 0; df < 4; df++) oacc[df][r] *= alpha;
        }

        #pragma unroll
        for (int jf = 0; jf < 4; jf++)
            #pragma unroll
            for (int r = 0; r < 4; r++)
                Ps[(w * 16 + q4 * 4 + r) * PP + jf * 16 + ln16] = f2bfbits(sacc[jf][r]);

        short8v pa0 = *(const short8v*)(&Ps[(w * 16 + ln16) * PP + q4 * 8]);
        short8v pa1 = *(const short8v*)(&Ps[(w * 16 + ln16) * PP + 32 + q4 * 8]);
        #pragma unroll
        for (int df = 0; df < 4; df++) {
            short8v v0f = *(const short8v*)(&Vt[(df * 16 + ln16) * VP + q4 * 8]);
            short8v v1f = *(const short8v*)(&Vt[(df * 16 + ln16) * VP + 32 + q4 * 8]);
            oacc[df] = __builtin_amdgcn_mfma_f32_16x16x32_bf16(pa0, v0f, oacc[df], 0, 0, 0);
            oacc[df] = __builtin_amdgcn_mfma_f32_16x16x32_bf16(pa1, v1f, oacc[df], 0, 0, 0);
        }
        __syncthreads();   // guard Ks/Vt overwrite next tile
    }

    #pragma unroll
    for (int r = 0; r < 4; r++) {
        float inv = 1.0f / l_run[r];
        int row = b * SS + qt * 32 + w * 16 + q4 * 4 + r;
        size_t ob = (size_t)row * E3 + h * HD;
        #pragma unroll
        for (int df = 0; df < 4; df++)
            qkv[ob + df * 16 + ln16] = f2bfbits(oacc[df][r] * inv);
    }
}

// =================================================================================
// Legacy fast-path MFMA GEMM (f32 weights converted in-kernel) — fallback only.
// =================================================================================
template <int AMODE, int FUSE>
__global__ void gemm_mfma(const void* __restrict__ Aptr, int lda,
                          const float* __restrict__ W, int ldw,
                          const float* __restrict__ bias,
                          const float2* __restrict__ musig,
                          const float* __restrict__ lng, const float* __restrict__ lnb,
                          void* __restrict__ Cptr, int ldc, int K) {
    __shared__ unsigned short As[128 * 40];
    __shared__ unsigned short Bs[32 * 130];

    int tid = threadIdx.x;
    int bm = blockIdx.y * 128, bn = blockIdx.x * 128;
    int w = tid >> 6, lane = tid & 63, ln16 = lane & 15, q = lane >> 4;
    int wm = (w & 1) * 64, wn = (w >> 1) * 64;

    f32x4 acc[4][4];
    #pragma unroll
    for (int i = 0; i < 4; i++)
        #pragma unroll
        for (int j = 0; j < 4; j++) acc[i][j] = (f32x4){0.f, 0.f, 0.f, 0.f};

    for (int k0 = 0; k0 < K; k0 += 32) {
        if (AMODE == 0) {
            const unsigned short* A = (const unsigned short*)Aptr;
            #pragma unroll
            for (int i = 0; i < 2; i++) {
                int idx = tid + i * 256;
                int row = idx >> 2, ko = (idx & 3) * 8;
                ushort8v v = *(const ushort8v*)(A + (size_t)(bm + row) * lda + k0 + ko);
                *(ushort8v*)(&As[row * 40 + ko]) = v;
            }
        } else {
            const float* A = (const float*)Aptr;
            #pragma unroll
            for (int i = 0; i < 4; i++) {
                int idx = tid + i * 256;
                int row = idx >> 3, ko = (idx & 7) * 4;
                float4 xv = *(const float4*)(A + (size_t)(bm + row) * lda + k0 + ko);
                float2 ms = musig[bm + row];
                float4 gv = *(const float4*)(lng + k0 + ko);
                float4 bv = *(const float4*)(lnb + k0 + ko);
                ushort4v o;
                o[0] = f2bfbits((xv.x - ms.x) * ms.y * gv.x + bv.x);
                o[1] = f2bfbits((xv.y - ms.x) * ms.y * gv.y + bv.y);
                o[2] = f2bfbits((xv.z - ms.x) * ms.y * gv.z + bv.z);
                o[3] = f2bfbits((xv.w - ms.x) * ms.y * gv.w + bv.w);
                *(ushort4v*)(&As[row * 40 + ko]) = o;
            }
        }
        #pragma unroll
        for (int i = 0; i < 16; i++) {
            int idx = tid + i * 256;
            int kr = idx >> 7, n = idx & 127;
            float wv = W[(size_t)(k0 + kr) * ldw + bn + n];
            Bs[kr * 130 + n] = f2bfbits(wv);
        }
        __syncthreads();

        short8v afr[4], bfr[4];
        #pragma unroll
        for (int i = 0; i < 4; i++)
            afr[i] = *(const short8v*)(&As[(wm + i * 16 + ln16) * 40 + q * 8]);
        #pragma unroll
        for (int j = 0; j < 4; j++) {
            int n = wn + j * 16 + ln16;
            #pragma unroll
            for (int jj = 0; jj < 8; jj++)
                bfr[j][jj] = (short)Bs[(q * 8 + jj) * 130 + n];
        }
        #pragma unroll
        for (int i = 0; i < 4; i++)
            #pragma unroll
            for (int j = 0; j < 4; j++)
                acc[i][j] = __builtin_amdgcn_mfma_f32_16x16x32_bf16(afr[i], bfr[j], acc[i][j], 0, 0, 0);
        __syncthreads();
    }

    #pragma unroll
    for (int j = 0; j < 4; j++) {
        int col = bn + wn + j * 16 + ln16;
        float bv = (FUSE == 3) ? 0.f : bias[col];
        #pragma unroll
        for (int i = 0; i < 4; i++) {
            #pragma unroll
            for (int r = 0; r < 4; r++) {
                int row = bm + wm + i * 16 + q * 4 + r;
                float v = acc[i][j][r] + bv;
                if (FUSE == 1) v = 0.5f * v * (1.0f + erff(v * 0.70710678118654752f));
                if (FUSE == 0 || FUSE == 1) {
                    ((unsigned short*)Cptr)[(size_t)row * ldc + col] = f2bfbits(v);
                } else {
                    float* C = (float*)Cptr;
                    C[(size_t)row * ldc + col] += v;
                }
            }
        }
    }
}

// =================================================================================
// Legacy VALU flash attention (used by middle fallback path)
// =================================================================================
__global__ void attn_flash(unsigned short* __restrict__ qkv,
                           const float* __restrict__ mask) {
    __shared__ float Qs[32][68];
    __shared__ float Ks[64][68];
    __shared__ float Vs[64][68];
    __shared__ float Ps[32][68];

    int bid = blockIdx.x;                 // b(2) x h(12) x qt(32)
    int qt = bid & 31;
    int h  = (bid >> 5) % NH;
    int b  = bid / (32 * NH);
    int tid = threadIdx.x;
    int ql = tid >> 3, grp = tid & 7;

    #pragma unroll
    for (int i = 0; i < 8; i++) {
        int idx = tid + i * 256;
        int rq = idx >> 6, d = idx & 63;
        int grow = b * SS + qt * 32 + rq;
        Qs[rq][d] = bfr2f(qkv[(size_t)grow * E3 + h * HD + d]) * 0.125f;
    }

    float m_run = -1e30f, l_run = 0.f;
    float O[8] = {0.f, 0.f, 0.f, 0.f, 0.f, 0.f, 0.f, 0.f};

    for (int c = 0; c < 16; c++) {
        int j0 = c * 64;
        #pragma unroll
        for (int i = 0; i < 4; i++) {
            int idx = tid + i * 256;
            int jj = idx >> 4, d4 = (idx & 15) * 4;
            size_t base = (size_t)(b * SS + j0 + jj) * E3 + h * HD + d4;
            ushort4v kv = *(const ushort4v*)(qkv + base + E);
            ushort4v vv = *(const ushort4v*)(qkv + base + 2 * E);
            *(float4*)&Ks[jj][d4] = make_float4(bfr2f(kv[0]), bfr2f(kv[1]), bfr2f(kv[2]), bfr2f(kv[3]));
            *(float4*)&Vs[jj][d4] = make_float4(bfr2f(vv[0]), bfr2f(vv[1]), bfr2f(vv[2]), bfr2f(vv[3]));
        }
        __syncthreads();

        float s[8] = {0.f, 0.f, 0.f, 0.f, 0.f, 0.f, 0.f, 0.f};
        #pragma unroll
        for (int d0 = 0; d0 < 64; d0 += 4) {
            float4 q4 = *(const float4*)&Qs[ql][d0];
            #pragma unroll
            for (int jl = 0; jl < 8; jl++) {
                float4 k4 = *(const float4*)&Ks[grp + jl * 8][d0];
                s[jl] += q4.x * k4.x + q4.y * k4.y + q4.z * k4.z + q4.w * k4.w;
            }
        }
        #pragma unroll
        for (int jl = 0; jl < 8; jl++)
            s[jl] += (1.0f - mask[b * SS + j0 + grp + jl * 8]) * -10000.0f;

        float cm = s[0];
        #pragma unroll
        for (int jl = 1; jl < 8; jl++) cm = fmaxf(cm, s[jl]);
        cm = fmaxf(cm, __shfl_xor(cm, 1, 64));
        cm = fmaxf(cm, __shfl_xor(cm, 2, 64));
        cm = fmaxf(cm, __shfl_xor(cm, 4, 64));

        float mnew = fmaxf(m_run, cm);
        float alpha = __expf(m_run - mnew);
        float ps = 0.f;
        #pragma unroll
        for (int jl = 0; jl < 8; jl++) {
            float p = __expf(s[jl] - mnew);
            Ps[ql][grp + jl * 8] = p;
            ps += p;
        }
        ps += __shfl_xor(ps, 1, 64);
        ps += __shfl_xor(ps, 2, 64);
        ps += __shfl_xor(ps, 4, 64);
        l_run = l_run * alpha + ps;
        m_run = mnew;
        #pragma unroll
        for (int e = 0; e < 8; e++) O[e] *= alpha;

        #pragma unroll 4
        for (int jj = 0; jj < 64; jj++) {
            float p = Ps[ql][jj];
            float4 v0 = *(const float4*)&Vs[jj][grp * 8];
            float4 v1 = *(const float4*)&Vs[jj][grp * 8 + 4];
            O[0] += p * v0.x; O[1] += p * v0.y; O[2] += p * v0.z; O[3] += p * v0.w;
            O[4] += p * v1.x; O[5] += p * v1.y; O[6] += p * v1.z; O[7] += p * v1.w;
        }
        __syncthreads();
    }

    float inv = 1.0f / l_run;
    int grow = b * SS + qt * 32 + ql;
    size_t obase = (size_t)grow * E3 + h * HD + grp * 8;
    #pragma unroll
    for (int e = 0; e < 8; e++)
        qkv[obase + e] = f2bfbits(O[e] * inv);
}

// =================================================================================
// Legacy (R4-proven) kernels — deep fallback if workspace is tiny
// =================================================================================
template <int FUSE, typename CT>
__global__ void gemm_legacy(const __hip_bfloat16* __restrict__ A, int lda,
                            const float* __restrict__ W, int ldw,
                            const float* __restrict__ bias,
                            CT* __restrict__ C, int ldc,
                            const float* __restrict__ resid,
                            int M, int N, int K) {
    __shared__ float As[16][65];
    __shared__ float Bs[16][65];
    int bm = blockIdx.y * 64, bn = blockIdx.x * 64;
    int tid = threadIdx.x;
    int ty = tid >> 4, tx = tid & 15;
    int ar = tid >> 2, ak = (tid & 3) << 2;
    int wk = tid >> 4, wn = (tid & 15) << 2;

    float acc[4][4] = {};
    for (int k0 = 0; k0 < K; k0 += 16) {
        ushort4 av = *(const ushort4*)(A + (size_t)(bm + ar) * lda + k0 + ak);
        As[ak + 0][ar] = bfr2f(av.x);
        As[ak + 1][ar] = bfr2f(av.y);
        As[ak + 2][ar] = bfr2f(av.z);
        As[ak + 3][ar] = bfr2f(av.w);
        float4 wv = *(const float4*)(W + (size_t)(k0 + wk) * ldw + bn + wn);
        Bs[wk][wn + 0] = wv.x;
        Bs[wk][wn + 1] = wv.y;
        Bs[wk][wn + 2] = wv.z;
        Bs[wk][wn + 3] = wv.w;
        __syncthreads();
        #pragma unroll
        for (int kk = 0; kk < 16; kk++) {
            float a[4], bv[4];
            #pragma unroll
            for (int i = 0; i < 4; i++) { a[i] = As[kk][ty * 4 + i]; bv[i] = Bs[kk][tx * 4 + i]; }
            #pragma unroll
            for (int i = 0; i < 4; i++)
                #pragma unroll
                for (int j = 0; j < 4; j++) acc[i][j] += a[i] * bv[j];
        }
        __syncthreads();
    }
    #pragma unroll
    for (int i = 0; i < 4; i++) {
        int row = bm + ty * 4 + i;
        #pragma unroll
        for (int j = 0; j < 4; j++) {
            int col = bn + tx * 4 + j;
            float v = acc[i][j];
            if (FUSE != 3) v += bias[col];
            if (FUSE == 1) v = 0.5f * v * (1.0f + erff(v * 0.70710678118654752f));
            if (FUSE == 2 || FUSE == 3) v += resid[(size_t)row * ldc + col];
            if constexpr (sizeof(CT) == 2) C[(size_t)row * ldc + col] = f2bf(v);
            else                           C[(size_t)row * ldc + col] = v;
        }
    }
}

__global__ void attn_legacy(const __hip_bfloat16* __restrict__ qkv,
                            const float* __restrict__ mask,
                            __hip_bfloat16* __restrict__ out) {
    __shared__ float sc[SS];
    __shared__ float qv[HD];
    __shared__ float oacc[4][HD];
    __shared__ float redbuf[4];

    int q = blockIdx.x & (SS - 1);
    int h = blockIdx.x >> 10;
    int tid = threadIdx.x;

    const __hip_bfloat16* qrow = qkv + (size_t)q * E3 + h * HD;
    if (tid < HD) qv[tid] = bf2f(qrow[tid]) * 0.125f;
    __syncthreads();

    for (int j = tid; j < SS; j += 256) {
        const __hip_bfloat16* krow = qkv + (size_t)j * E3 + E + h * HD;
        float d = 0.f;
        #pragma unroll
        for (int t = 0; t < HD; t += 4) {
            ushort4 kv4 = *(const ushort4*)(krow + t);
            d += qv[t] * bfr2f(kv4.x) + qv[t + 1] * bfr2f(kv4.y)
               + qv[t + 2] * bfr2f(kv4.z) + qv[t + 3] * bfr2f(kv4.w);
        }
        d += (1.0f - mask[j]) * -10000.0f;
        sc[j] = d;
    }
    __syncthreads();

    float m = -1e30f;
    for (int j = tid; j < SS; j += 256) m = fmaxf(m, sc[j]);
    m = block_max(m, redbuf);
    float s = 0.f;
    for (int j = tid; j < SS; j += 256) { float e = __expf(sc[j] - m); sc[j] = e; s += e; }
    s = block_sum(s, redbuf);
    float inv = 1.0f / s;
    __syncthreads();

    int d = tid & 63, c = tid >> 6;
    float acc = 0.f;
    int j0 = c * 256;
    for (int j = j0; j < j0 + 256; j++) {
        const __hip_bfloat16* vrow = qkv + (size_t)j * E3 + 2 * E + h * HD;
        acc += sc[j] * bf2f(vrow[d]);
    }
    oacc[c][d] = acc;
    __syncthreads();
    if (tid < HD) {
        float o = (oacc[0][tid] + oacc[1][tid] + oacc[2][tid] + oacc[3][tid]) * inv;
        out[(size_t)q * E + h * HD + tid] = f2bf(o);
    }
}

__global__ void copy_kernel(const float* __restrict__ in, float* __restrict__ out, int n) {
    int i = blockIdx.x * 256 + threadIdx.x;
    if (i < n) out[i] = in[i];
}

// =================================================================================
extern "C" void kernel_launch(void* const* d_in, const int* in_sizes, int n_in,
                              void* d_out, int out_size, void* d_ws, size_t ws_size,
                              hipStream_t stream) {
    const float* emb   = (const float*)d_in[0];
    const float* mask  = (const float*)d_in[1];
    const float* Wqkv  = (const float*)d_in[2];
    const float* bqkv  = (const float*)d_in[3];
    const float* Wo    = (const float*)d_in[4];
    const float* bo    = (const float*)d_in[5];
    const float* ln1g  = (const float*)d_in[6];
    const float* ln1b  = (const float*)d_in[7];
    const float* ln2g  = (const float*)d_in[8];
    const float* ln2b  = (const float*)d_in[9];
    const float* Wfc   = (const float*)d_in[10];
    const float* bfc   = (const float*)d_in[11];
    const float* Wmo   = (const float*)d_in[12];
    const float* bmo   = (const float*)d_in[13];
    const float* lnfg  = (const float*)d_in[14];
    const float* lnfb  = (const float*)d_in[15];

    // FAST3: x + h + buf + ALL transposed weights (6 layers)
    const size_t NEED_FAST3 = sizeof(float) * (size_t)T * E
                            + 2ull * (size_t)T * E
                            + 2ull * (size_t)T * FFD
                            + 2ull * 6 * LSZ;                 // ~107 MB
    // FAST2: x + h + buf + one-weight scratch
    const size_t NEED_FAST2 = sizeof(float) * (size_t)T * E
                            + 2ull * (size_t)T * E
                            + 2ull * (size_t)T * FFD
                            + 2ull * (size_t)E * FFD;         // ~26.7 MB
    const size_t NEED_FAST = sizeof(float) * (size_t)T * E
                           + 2ull * (size_t)T * E3
                           + sizeof(float2) * (size_t)T;

    if (ws_size >= NEED_FAST2) {
        // ---------------- FAST2/FAST3: bf16 transposed weights + MFMA everything ----
        const bool allw = (ws_size >= NEED_FAST3);
        float* x            = (float*)d_ws;
        unsigned short* h   = (unsigned short*)(x + (size_t)T * E);       // [T,E]
        unsigned short* buf = h + (size_t)T * E;                          // [T,FFD] union
        unsigned short* wt  = buf + (size_t)T * FFD;                      // scratch / wt_all
        unsigned short* qkv = buf;                                        // [T,E3]
        unsigned short* ff  = buf;                                        // [T,FFD]

        copy4_kernel<<<dim3(T * E / 4 / 256), dim3(256), 0, stream>>>(
            (const float4*)emb, (float4*)x, T * E / 4);

        if (allw) {
            // one dispatch: transpose+convert all 24 weight matrices
            transpose_all<<<dim3(6 * TL), dim3(256), 0, stream>>>(Wqkv, Wo, Wfc, Wmo, wt);
        }

        for (int l = 0; l < LYR; l++) {
            const float* wqkv_l = Wqkv + (size_t)l * E * E3;
            const float* wo_l   = Wo   + (size_t)l * E * E;
            const float* wfc_l  = Wfc  + (size_t)l * E * FFD;
            const float* wmo_l  = Wmo  + (size_t)l * FFD * E;

            const unsigned short* wq_t, *wo_t, *wfc_t, *wmo_t;
            if (allw) {
                const unsigned short* base = wt + (size_t)l * LSZ;
                wq_t  = base;
                wo_t  = base + SZ_QKV_T;
                wfc_t = base + SZ_QKV_T + SZ_WO_T;
                wmo_t = base + SZ_QKV_T + SZ_WO_T + SZ_WFC_T;
            } else {
                wq_t = wo_t = wfc_t = wmo_t = wt;   // reuse scratch sequentially
            }

            ln_kernel<__hip_bfloat16><<<dim3(T), dim3(256), 0, stream>>>(
                x, (__hip_bfloat16*)h, ln1g + l * E, ln1b + l * E);
            if (!allw)
                transpose_cvt<<<dim3(E3 / 32, E / 32), dim3(256), 0, stream>>>(wqkv_l, wt, E, E3);
            // QKV: 576 blocks x 8 waves
            gemm_bt<0><<<dim3(E3 / 128, T / 64), dim3(512), 0, stream>>>(
                h, E, wq_t, E, bqkv + l * E3, qkv, E3, E);
            // attention: 768 blocks x 2 waves
            attn_mfma<<<dim3(BB * NH * 32), dim3(128), 0, stream>>>(qkv, mask);
            if (!allw)
                transpose_cvt<<<dim3(E / 32, E / 32), dim3(256), 0, stream>>>(wo_l, wt, E, E);
            // Wo: split-K x4 -> 768 blocks x 8 waves (atomic residual add)
            gemm_bt<2><<<dim3(E / 128, T / 64, 4), dim3(512), 0, stream>>>(
                qkv, E3, wo_t, E, bo + l * E, x, E, E);

            ln_kernel<__hip_bfloat16><<<dim3(T), dim3(256), 0, stream>>>(
                x, (__hip_bfloat16*)h, ln2g + l * E, ln2b + l * E);
            if (!allw)
                transpose_cvt<<<dim3(FFD / 32, E / 32), dim3(256), 0, stream>>>(wfc_l, wt, E, FFD);
            // FC: 768 blocks x 8 waves
            gemm_bt<1><<<dim3(FFD / 128, T / 64), dim3(512), 0, stream>>>(
                h, E, wfc_t, E, bfc + l * FFD, ff, FFD, E);
            if (!allw)
                transpose_cvt<<<dim3(E / 32, FFD / 32), dim3(256), 0, stream>>>(wmo_l, wt, FFD, E);
            // Wmo: split-K x4 -> 768 blocks x 8 waves (atomic residual add)
            gemm_bt<2><<<dim3(E / 128, T / 64, 4), dim3(512), 0, stream>>>(
                ff, FFD, wmo_t, FFD, bmo + l * E, x, E, FFD);
        }
        ln_kernel<float><<<dim3(T), dim3(256), 0, stream>>>(x, (float*)d_out, lnfg, lnfb);
    } else if (ws_size >= NEED_FAST) {
        // ---------------- FAST PATH (previous session, proven) ----------------
        float* x              = (float*)d_ws;
        unsigned short* qkv   = (unsigned short*)(x + (size_t)T * E);
        float2* musig         = (float2*)(qkv + (size_t)T * E3);

        copy4_kernel<<<dim3(T * E / 4 / 256), dim3(256), 0, stream>>>(
            (const float4*)emb, (float4*)x, T * E / 4);

        for (int l = 0; l < LYR; l++) {
            const float* wqkv_l = Wqkv + (size_t)l * E * E3;
            const float* wo_l   = Wo   + (size_t)l * E * E;
            const float* wfc_l  = Wfc  + (size_t)l * E * FFD;
            const float* wmo_l  = Wmo  + (size_t)l * FFD * E;

            rowstat_kernel<<<dim3(T), dim3(256), 0, stream>>>(x, musig);
            gemm_mfma<1, 0><<<dim3(E3 / 128, T / 128), dim3(256), 0, stream>>>(
                x, E, wqkv_l, E3, bqkv + l * E3, musig, ln1g + l * E, ln1b + l * E,
                qkv, E3, E);
            attn_flash<<<dim3(BB * NH * 32), dim3(256), 0, stream>>>(qkv, mask);
            gemm_mfma<0, 2><<<dim3(E / 128, T / 128), dim3(256), 0, stream>>>(
                qkv, E3, wo_l, E, bo + l * E, nullptr, nullptr, nullptr, x, E, E);

            unsigned short* ffp = qkv;
            unsigned short* hp  = qkv + (size_t)T * FH;
            ln_kernel<__hip_bfloat16><<<dim3(T), dim3(256), 0, stream>>>(
                x, (__hip_bfloat16*)hp, ln2g + l * E, ln2b + l * E);
            for (int f = 0; f < 2; f++) {
                gemm_mfma<0, 1><<<dim3(FH / 128, T / 128), dim3(256), 0, stream>>>(
                    hp, E, wfc_l + f * FH, FFD, bfc + l * FFD + f * FH,
                    nullptr, nullptr, nullptr, ffp, FH, E);
                if (f == 0)
                    gemm_mfma<0, 3><<<dim3(E / 128, T / 128), dim3(256), 0, stream>>>(
                        ffp, FH, wmo_l + (size_t)f * FH * E, E, nullptr, nullptr, nullptr, nullptr,
                        x, E, FH);
                else
                    gemm_mfma<0, 2><<<dim3(E / 128, T / 128), dim3(256), 0, stream>>>(
                        ffp, FH, wmo_l + (size_t)f * FH * E, E, bmo + l * E, nullptr, nullptr, nullptr,
                        x, E, FH);
            }
        }
        ln_kernel<float><<<dim3(T), dim3(256), 0, stream>>>(x, (float*)d_out, lnfg, lnfb);
    } else {
        // ---------------- LEGACY PATH (R4-proven, 12.58 MB) ----------------
        float* x           = (float*)d_ws;
        __hip_bfloat16* hb = (__hip_bfloat16*)(x + (size_t)T * E);
        __hip_bfloat16* qb = hb + (size_t)SS * E;

        int n = T * E;
        copy_kernel<<<dim3((n + 255) / 256), dim3(256), 0, stream>>>(emb, x, n);

        for (int l = 0; l < LYR; l++) {
            const float* wqkv_l = Wqkv + (size_t)l * E * E3;
            const float* wo_l   = Wo   + (size_t)l * E * E;
            const float* wfc_l  = Wfc  + (size_t)l * E * FFD;
            const float* wmo_l  = Wmo  + (size_t)l * FFD * E;

            for (int b = 0; b < BB; b++) {
                float* xb = x + (size_t)b * SS * E;
                ln_kernel<__hip_bfloat16><<<dim3(SS), dim3(256), 0, stream>>>(
                    xb, hb, ln1g + l * E, ln1b + l * E);
                gemm_legacy<0, __hip_bfloat16><<<dim3(E3 / 64, SS / 64), dim3(256), 0, stream>>>(
                    hb, E, wqkv_l, E3, bqkv + l * E3, qb, E3, nullptr, SS, E3, E);
                attn_legacy<<<dim3(NH * SS), dim3(256), 0, stream>>>(qb, mask + b * SS, hb);
                gemm_legacy<2, float><<<dim3(E / 64, SS / 64), dim3(256), 0, stream>>>(
                    hb, E, wo_l, E, bo + l * E, xb, E, xb, SS, E, E);
            }
            for (int b = 0; b < BB; b++) {
                float* xb = x + (size_t)b * SS * E;
                ln_kernel<__hip_bfloat16><<<dim3(SS), dim3(256), 0, stream>>>(
                    xb, hb, ln2g + l * E, ln2b + l * E);
                for (int f = 0; f < 2; f++) {
                    gemm_legacy<1, __hip_bfloat16><<<dim3(FH / 64, SS / 64), dim3(256), 0, stream>>>(
                        hb, E, wfc_l + f * FH, FFD, bfc + l * FFD + f * FH, qb, FH, nullptr,
                        SS, FH, E);
                    if (f == 0)
                        gemm_legacy<3, float><<<dim3(E / 64, SS / 64), dim3(256), 0, stream>>>(
                            qb, FH, wmo_l + (size_t)f * FH * E, E, nullptr, xb, E, xb, SS, E, FH);
                    else
                        gemm_legacy<2, float><<<dim3(E / 64, SS / 64), dim3(256), 0, stream>>>(
                            qb, FH, wmo_l + (size_t)f * FH * E, E, bmo + l * E, xb, E, xb, SS, E, FH);
                }
            }
        }
        ln_kernel<float><<<dim3(T), dim3(256), 0, stream>>>(x, (float*)d_out, lnfg, lnfb);
    }
}

// Round 7
// 1091.635 us; speedup vs baseline: 4.3502x; 1.0165x over previous
//
#include <hip/hip_runtime.h>
#include <hip/hip_bf16.h>
#include <math.h>

constexpr int LYR = 6;
constexpr int E   = 768;
constexpr int NH  = 12;
constexpr int FFD = 3072;
constexpr int HD  = 64;
constexpr int BB  = 2;
constexpr int SS  = 1024;
constexpr int T   = BB * SS;     // 2048 tokens
constexpr int E3  = 3 * E;       // 2304
constexpr int FH  = FFD / 2;     // 1536 (FFN slice width, legacy fast path)

// per-layer transposed-weight slab (elements)
constexpr size_t SZ_QKV_T = (size_t)E3 * E;     // [E3][E]
constexpr size_t SZ_WO_T  = (size_t)E * E;      // [E][E]
constexpr size_t SZ_WFC_T = (size_t)FFD * E;    // [FFD][E]
constexpr size_t SZ_WMO_T = (size_t)E * FFD;    // [E][FFD]
constexpr size_t LSZ      = SZ_QKV_T + SZ_WO_T + SZ_WFC_T + SZ_WMO_T;  // 7,077,888
// 64x64 tile counts for the fused transpose
constexpr int TQ = (E3 / 64) * (E / 64);        // 432
constexpr int TO = (E / 64) * (E / 64);         // 144
constexpr int TF = (FFD / 64) * (E / 64);       // 576
constexpr int TM = (E / 64) * (FFD / 64);       // 576
constexpr int TL = TQ + TO + TF + TM;           // 1728

#define LN_EPS 1e-5f

typedef __attribute__((ext_vector_type(8))) short    short8v;
typedef __attribute__((ext_vector_type(8))) unsigned short ushort8v;
typedef __attribute__((ext_vector_type(4))) unsigned short ushort4v;
typedef __attribute__((ext_vector_type(4))) float    f32x4;

__device__ __forceinline__ float bf2f(__hip_bfloat16 x) { return __bfloat162float(x); }
__device__ __forceinline__ float bfr2f(unsigned short u) {
    union { unsigned int i; float f; } v; v.i = ((unsigned int)u) << 16; return v.f;
}
__device__ __forceinline__ __hip_bfloat16 f2bf(float f) { return __float2bfloat16(f); }
// bf16 bits with round-to-nearest-even (finite inputs only)
__device__ __forceinline__ unsigned short f2bfbits(float f) {
    union { float f; unsigned int i; } v; v.f = f;
    unsigned int r = (v.i + 0x7fffu + ((v.i >> 16) & 1u)) >> 16;
    return (unsigned short)r;
}

// ---------------- block reductions (256 threads = 4 waves of 64) ----------------
__device__ __forceinline__ float block_sum(float v, float* sm) {
    #pragma unroll
    for (int o = 32; o > 0; o >>= 1) v += __shfl_down(v, o, 64);
    int lane = threadIdx.x & 63, wid = threadIdx.x >> 6;
    if (lane == 0) sm[wid] = v;
    __syncthreads();
    float r = sm[0] + sm[1] + sm[2] + sm[3];
    __syncthreads();
    return r;
}

__device__ __forceinline__ float block_max(float v, float* sm) {
    #pragma unroll
    for (int o = 32; o > 0; o >>= 1) v = fmaxf(v, __shfl_down(v, o, 64));
    int lane = threadIdx.x & 63, wid = threadIdx.x >> 6;
    if (lane == 0) sm[wid] = v;
    __syncthreads();
    float r = fmaxf(fmaxf(sm[0], sm[1]), fmaxf(sm[2], sm[3]));
    __syncthreads();
    return r;
}

// ---------------- f32 copy (embeddings -> residual stream), float4 ----------------
__global__ void copy4_kernel(const float4* __restrict__ in, float4* __restrict__ out, int n4) {
    int i = blockIdx.x * 256 + threadIdx.x;
    if (i < n4) out[i] = in[i];
}

// ---------------- per-row LN stats: musig[row] = (mu, rstd)  (legacy fast path) ---
__global__ void rowstat_kernel(const float* __restrict__ x, float2* __restrict__ musig) {
    __shared__ float sm[4];
    int row = blockIdx.x;
    const float* xr = x + (size_t)row * E;
    float s = 0.f;
    for (int i = threadIdx.x; i < E; i += 256) s += xr[i];
    float mu = block_sum(s, sm) * (1.0f / E);
    float v = 0.f;
    for (int i = threadIdx.x; i < E; i += 256) { float d = xr[i] - mu; v += d * d; }
    float rstd = rsqrtf(block_sum(v, sm) * (1.0f / E) + LN_EPS);
    if (threadIdx.x == 0) musig[row] = make_float2(mu, rstd);
}

// ---------------- LayerNorm: one block per row; x f32 -> out bf16 or f32 --------
template <typename OT>
__global__ void ln_kernel(const float* __restrict__ x, OT* __restrict__ out,
                          const float* __restrict__ g, const float* __restrict__ b) {
    __shared__ float sm[4];
    int row = blockIdx.x;
    const float* xr = x + (size_t)row * E;
    float s = 0.f;
    for (int i = threadIdx.x; i < E; i += 256) s += xr[i];
    float mu = block_sum(s, sm) * (1.0f / E);
    float v = 0.f;
    for (int i = threadIdx.x; i < E; i += 256) { float d = xr[i] - mu; v += d * d; }
    float rstd = rsqrtf(block_sum(v, sm) * (1.0f / E) + LN_EPS);
    for (int i = threadIdx.x; i < E; i += 256) {
        float o = (xr[i] - mu) * rstd * g[i] + b[i];
        if constexpr (sizeof(OT) == 2) out[(size_t)row * E + i] = f2bf(o);
        else                           out[(size_t)row * E + i] = o;
    }
}

// ---------------- transpose tile body (32x32, FAST2 tier) -------------------------
__device__ __forceinline__ void transpose_tile(const float* __restrict__ W,
                                               unsigned short* __restrict__ Wt,
                                               int K, int N, int n0, int k0) {
    __shared__ float tile[32][33];
    int tx = threadIdx.x & 31, ty = threadIdx.x >> 5;   // ty 0..7
    #pragma unroll
    for (int i = 0; i < 4; i++)
        tile[ty + i * 8][tx] = W[(size_t)(k0 + ty + i * 8) * N + n0 + tx];
    __syncthreads();
    #pragma unroll
    for (int i = 0; i < 4; i++)
        Wt[(size_t)(n0 + ty + i * 8) * K + k0 + tx] = f2bfbits(tile[tx][ty + i * 8]);
}

// per-layer single-weight transpose (FAST2 tier)
__global__ void transpose_cvt(const float* __restrict__ W, unsigned short* __restrict__ Wt,
                              int K, int N) {
    transpose_tile(W, Wt, K, N, blockIdx.x * 32, blockIdx.y * 32);
}

// ---------------- 64x64 transpose tile (FAST3): f4 reads, b128 writes -------------
// LDS pad 65 (odd): column reads stride 65 dwords -> 8*65%32=8 -> 2-way (free);
// scalar f32 writes (r+c) pattern -> 2-way (free). Global: 256B read rows, 128B
// write rows (vs 64B in the 32x32 version — the measured 2.07 TB/s bottleneck).
__device__ __forceinline__ void transpose_tile64(const float* __restrict__ W,
                                                 unsigned short* __restrict__ Wt,
                                                 int K, int N, int n0, int k0) {
    __shared__ float tile[64][65];
    int tid = threadIdx.x;
    int rr = tid >> 4, c4 = (tid & 15) * 4;      // read: 16 rows/iter, float4 cols
    #pragma unroll
    for (int i = 0; i < 4; i++) {
        float4 v = *(const float4*)&W[(size_t)(k0 + rr + i * 16) * N + n0 + c4];
        tile[rr + i * 16][c4 + 0] = v.x;
        tile[rr + i * 16][c4 + 1] = v.y;
        tile[rr + i * 16][c4 + 2] = v.z;
        tile[rr + i * 16][c4 + 3] = v.w;
    }
    __syncthreads();
    int nr = tid >> 3, kc = (tid & 7) * 8;       // write: 32 n-rows/iter, 8-k chunks
    #pragma unroll
    for (int i = 0; i < 2; i++) {
        int n = nr + i * 32;
        ushort8v o;
        #pragma unroll
        for (int e = 0; e < 8; e++) o[e] = f2bfbits(tile[kc + e][n]);
        *(ushort8v*)&Wt[(size_t)(n0 + n) * K + k0 + kc] = o;
    }
}

// fused all-layers all-weights transpose (FAST3 tier): one dispatch, 64x64 tiles.
__global__ void transpose_all(const float* __restrict__ Wqkv, const float* __restrict__ Wo,
                              const float* __restrict__ Wfc, const float* __restrict__ Wmo,
                              unsigned short* __restrict__ wt_all) {
    int bid = blockIdx.x;
    int layer = bid / TL, lid = bid % TL;
    unsigned short* dst = wt_all + (size_t)layer * LSZ;
    const float* W; int K, N, t;
    if (lid < TQ)                { W = Wqkv + (size_t)layer * E * E3;  K = E;   N = E3;  t = lid; }
    else if (lid < TQ + TO)      { W = Wo   + (size_t)layer * E * E;   K = E;   N = E;   t = lid - TQ;
                                   dst += SZ_QKV_T; }
    else if (lid < TQ + TO + TF) { W = Wfc  + (size_t)layer * E * FFD; K = E;   N = FFD; t = lid - TQ - TO;
                                   dst += SZ_QKV_T + SZ_WO_T; }
    else                         { W = Wmo  + (size_t)layer * FFD * E; K = FFD; N = E;   t = lid - TQ - TO - TF;
                                   dst += SZ_QKV_T + SZ_WO_T + SZ_WFC_T; }
    int nt = N / 64;
    transpose_tile64(W, dst, K, N, (t % nt) * 64, (t / nt) * 64);
}

// =================================================================================
// MFMA GEMM, 8 waves (512 thr), tile 64x128, wave-tile 32x32, bf16 operands,
// B pre-transposed. T14 async-STAGE split: next K-tile's global loads issue right
// after the barrier, land during the MFMA phase (HBM latency hidden under compute).
// LDS rows padded to 80 ushorts (160B, measured conflict-free). Split-K via
// gridDim.z (FUSE=2 only).
//   FUSE 0: C = A@B + bias -> bf16 | 1: gelu(...) -> bf16
//   FUSE 2: C += A@B + bias (f32 atomicAdd; bias applied by z==0)
// =================================================================================
template <int FUSE>
__global__ __launch_bounds__(512) void gemm_bt(
        const unsigned short* __restrict__ A, int lda,
        const unsigned short* __restrict__ Bt, int ldb,
        const float* __restrict__ bias,
        void* __restrict__ Cptr, int ldc, int K) {
    constexpr int BM = 64, BN = 128, PAD = 80;
    constexpr int MFR = 2, NFR = 2;
    __shared__ unsigned short As[BM * PAD];
    __shared__ unsigned short Bs[BN * PAD];

    int tid = threadIdx.x;
    int bm = blockIdx.y * BM, bn = blockIdx.x * BN;
    int kchunk = K / gridDim.z;
    int kbeg = blockIdx.z * kchunk, kend = kbeg + kchunk;
    int w = tid >> 6, lane = tid & 63, ln16 = lane & 15, q = lane >> 4;
    int wm = (w & 1) * 32, wn = (w >> 1) * 32;

    int rowA = tid >> 3, koA = (tid & 7) * 8;
    int rowB0 = tid >> 3, koB = (tid & 7) * 8;
    int rowB1 = (tid + 512) >> 3;

    f32x4 acc[MFR][NFR];
    #pragma unroll
    for (int i = 0; i < MFR; i++)
        #pragma unroll
        for (int j = 0; j < NFR; j++) acc[i][j] = (f32x4){0.f, 0.f, 0.f, 0.f};

    // register-staged tile (T14): prologue load, per-iter write/prefetch
    ushort8v aR, bR0, bR1;
    aR  = *(const ushort8v*)(A  + (size_t)(bm + rowA)  * lda + kbeg + koA);
    bR0 = *(const ushort8v*)(Bt + (size_t)(bn + rowB0) * ldb + kbeg + koB);
    bR1 = *(const ushort8v*)(Bt + (size_t)(bn + rowB1) * ldb + kbeg + koB);

    for (int k0 = kbeg; k0 < kend; k0 += 64) {
        *(ushort8v*)(&As[rowA * PAD + koA])  = aR;
        *(ushort8v*)(&Bs[rowB0 * PAD + koB]) = bR0;
        *(ushort8v*)(&Bs[rowB1 * PAD + koB]) = bR1;
        __syncthreads();

        if (k0 + 64 < kend) {   // issue next-tile loads; land during MFMA below
            aR  = *(const ushort8v*)(A  + (size_t)(bm + rowA)  * lda + k0 + 64 + koA);
            bR0 = *(const ushort8v*)(Bt + (size_t)(bn + rowB0) * ldb + k0 + 64 + koB);
            bR1 = *(const ushort8v*)(Bt + (size_t)(bn + rowB1) * ldb + k0 + 64 + koB);
        }

        #pragma unroll
        for (int kk = 0; kk < 64; kk += 32) {
            short8v afr[MFR], bfr[NFR];
            #pragma unroll
            for (int i = 0; i < MFR; i++)
                afr[i] = *(const short8v*)(&As[(wm + i * 16 + ln16) * PAD + kk + q * 8]);
            #pragma unroll
            for (int j = 0; j < NFR; j++)
                bfr[j] = *(const short8v*)(&Bs[(wn + j * 16 + ln16) * PAD + kk + q * 8]);
            #pragma unroll
            for (int i = 0; i < MFR; i++)
                #pragma unroll
                for (int j = 0; j < NFR; j++)
                    acc[i][j] = __builtin_amdgcn_mfma_f32_16x16x32_bf16(afr[i], bfr[j], acc[i][j], 0, 0, 0);
        }
        __syncthreads();
    }

    #pragma unroll
    for (int j = 0; j < NFR; j++) {
        int col = bn + wn + j * 16 + ln16;
        float bv = (blockIdx.z == 0) ? bias[col] : 0.f;
        #pragma unroll
        for (int i = 0; i < MFR; i++) {
            #pragma unroll
            for (int r = 0; r < 4; r++) {
                int row = bm + wm + i * 16 + q * 4 + r;
                float v = acc[i][j][r] + bv;
                if (FUSE == 1) v = 0.5f * v * (1.0f + erff(v * 0.70710678118654752f));
                if (FUSE == 0 || FUSE == 1) {
                    ((unsigned short*)Cptr)[(size_t)row * ldc + col] = f2bfbits(v);
                } else {
                    atomicAdd(&((float*)Cptr)[(size_t)row * ldc + col], v);
                }
            }
        }
    }
}

// =================================================================================
// MFMA flash attention v3: one block per (b, h, 32-query tile); 2 waves x 16 q-rows.
// Double-buffered K/V/M staging with register prefetch: ONE barrier per KV-tile,
// HBM latency hidden under QK^T/softmax/PV compute. Conflict-free V transpose.
// =================================================================================
__global__ __launch_bounds__(128) void attn_mfma(unsigned short* __restrict__ qkv,
                                                 const float* __restrict__ mask) {
    constexpr int KP = 80;   // Ks row pitch (ushorts)
    constexpr int VP = 80;   // Vt row pitch
    constexpr int PP = 82;   // Ps row pitch
    __shared__ unsigned short Ks[2][64 * KP];
    __shared__ unsigned short Vt[2][64 * VP];
    __shared__ unsigned short Ps[32 * PP];
    __shared__ float Ms[2][64];

    int bid = blockIdx.x;                 // b(2) x h(12) x qt(32)
    int qt = bid & 31;
    int h  = (bid >> 5) % NH;
    int b  = bid / (32 * NH);
    int tid = threadIdx.x;
    int w = tid >> 6, lane = tid & 63, ln16 = lane & 15, q4 = lane >> 4;

    // Q fragments in registers
    int qrow = b * SS + qt * 32 + w * 16 + ln16;
    const unsigned short* qbase = qkv + (size_t)qrow * E3 + h * HD;
    short8v qfr0 = *(const short8v*)(qbase + q4 * 8);
    short8v qfr1 = *(const short8v*)(qbase + 32 + q4 * 8);

    // staging registers (tile t+1 in flight during compute of t)
    ushort8v kR[4], vR[4];
    float mR = 1.0f;

    f32x4 sacc[4];
    f32x4 oacc[4];
    float m_run[4], l_run[4];
    #pragma unroll
    for (int r = 0; r < 4; r++) { m_run[r] = -1e30f; l_run[r] = 0.f; }
    #pragma unroll
    for (int i = 0; i < 4; i++) oacc[i] = (f32x4){0.f, 0.f, 0.f, 0.f};

    // ---- prologue: load + write tile 0 ----
    {
        int j0 = 0;
        #pragma unroll
        for (int i = 0; i < 4; i++) {
            int idx = tid + i * 128; int row = idx >> 3, ko = (idx & 7) * 8;
            kR[i] = *(const ushort8v*)(qkv + (size_t)(b * SS + j0 + row) * E3 + h * HD + E + ko);
        }
        #pragma unroll
        for (int i = 0; i < 4; i++) {
            int ko = (w + 2 * i) * 8;
            vR[i] = *(const ushort8v*)(qkv + (size_t)(b * SS + j0 + lane) * E3 + h * HD + 2 * E + ko);
        }
        if (tid < 64) mR = mask[b * SS + j0 + tid];
        #pragma unroll
        for (int i = 0; i < 4; i++) {
            int idx = tid + i * 128; int row = idx >> 3, ko = (idx & 7) * 8;
            *(ushort8v*)(&Ks[0][row * KP + ko]) = kR[i];
        }
        #pragma unroll
        for (int i = 0; i < 4; i++) {
            int ko = (w + 2 * i) * 8;
            #pragma unroll
            for (int e = 0; e < 8; e++)
                Vt[0][(ko + e) * VP + lane] = vR[i][e];   // banks = lane/2: 2-way floor
        }
        if (tid < 64) Ms[0][tid] = (1.0f - mR) * -10000.0f;
    }
    __syncthreads();

    for (int t = 0; t < 16; t++) {
        int cur = t & 1;
        // ---- issue next tile's global loads (land during compute) ----
        if (t < 15) {
            int j0 = (t + 1) * 64;
            #pragma unroll
            for (int i = 0; i < 4; i++) {
                int idx = tid + i * 128; int row = idx >> 3, ko = (idx & 7) * 8;
                kR[i] = *(const ushort8v*)(qkv + (size_t)(b * SS + j0 + row) * E3 + h * HD + E + ko);
            }
            #pragma unroll
            for (int i = 0; i < 4; i++) {
                int ko = (w + 2 * i) * 8;
                vR[i] = *(const ushort8v*)(qkv + (size_t)(b * SS + j0 + lane) * E3 + h * HD + 2 * E + ko);
            }
            if (tid < 64) mR = mask[b * SS + j0 + tid];
        }

        // ---- QK^T ----
        #pragma unroll
        for (int jf = 0; jf < 4; jf++) sacc[jf] = (f32x4){0.f, 0.f, 0.f, 0.f};
        #pragma unroll
        for (int jf = 0; jf < 4; jf++) {
            short8v k0f = *(const short8v*)(&Ks[cur][(jf * 16 + ln16) * KP + q4 * 8]);
            short8v k1f = *(const short8v*)(&Ks[cur][(jf * 16 + ln16) * KP + 32 + q4 * 8]);
            sacc[jf] = __builtin_amdgcn_mfma_f32_16x16x32_bf16(qfr0, k0f, sacc[jf], 0, 0, 0);
            sacc[jf] = __builtin_amdgcn_mfma_f32_16x16x32_bf16(qfr1, k1f, sacc[jf], 0, 0, 0);
        }

        // ---- scale + mask ----
        float madd[4];
        #pragma unroll
        for (int jf = 0; jf < 4; jf++) madd[jf] = Ms[cur][jf * 16 + ln16];
        #pragma unroll
        for (int jf = 0; jf < 4; jf++)
            #pragma unroll
            for (int r = 0; r < 4; r++)
                sacc[jf][r] = sacc[jf][r] * 0.125f + madd[jf];

        // ---- online softmax ----
        #pragma unroll
        for (int r = 0; r < 4; r++) {
            float mx = fmaxf(fmaxf(sacc[0][r], sacc[1][r]), fmaxf(sacc[2][r], sacc[3][r]));
            mx = fmaxf(mx, __shfl_xor(mx, 1, 64));
            mx = fmaxf(mx, __shfl_xor(mx, 2, 64));
            mx = fmaxf(mx, __shfl_xor(mx, 4, 64));
            mx = fmaxf(mx, __shfl_xor(mx, 8, 64));
            float mnew = fmaxf(m_run[r], mx);
            float alpha = __expf(m_run[r] - mnew);
            m_run[r] = mnew;
            float ps = 0.f;
            #pragma unroll
            for (int jf = 0; jf < 4; jf++) {
                float p = __expf(sacc[jf][r] - mnew);
                sacc[jf][r] = p;
                ps += p;
            }
            ps += __shfl_xor(ps, 1, 64);
            ps += __shfl_xor(ps, 2, 64);
            ps += __shfl_xor(ps, 4, 64);
            ps += __shfl_xor(ps, 8, 64);
            l_run[r] = l_run[r] * alpha + ps;
            #pragma unroll
            for (int df = 0; df < 4; df++) oacc[df][r] *= alpha;
        }

        // ---- write P (bf16) to LDS; wave-local rows, no barrier needed ----
        #pragma unroll
        for (int jf = 0; jf < 4; jf++)
            #pragma unroll
            for (int r = 0; r < 4; r++)
                Ps[(w * 16 + q4 * 4 + r) * PP + jf * 16 + ln16] = f2bfbits(sacc[jf][r]);

        // ---- PV ----
        short8v pa0 = *(const short8v*)(&Ps[(w * 16 + ln16) * PP + q4 * 8]);
        short8v pa1 = *(const short8v*)(&Ps[(w * 16 + ln16) * PP + 32 + q4 * 8]);
        #pragma unroll
        for (int df = 0; df < 4; df++) {
            short8v v0f = *(const short8v*)(&Vt[cur][(df * 16 + ln16) * VP + q4 * 8]);
            short8v v1f = *(const short8v*)(&Vt[cur][(df * 16 + ln16) * VP + 32 + q4 * 8]);
            oacc[df] = __builtin_amdgcn_mfma_f32_16x16x32_bf16(pa0, v0f, oacc[df], 0, 0, 0);
            oacc[df] = __builtin_amdgcn_mfma_f32_16x16x32_bf16(pa1, v1f, oacc[df], 0, 0, 0);
        }

        // ---- write prefetched tile into the other buffer (disjoint; no hazard) ----
        if (t < 15) {
            int nb = cur ^ 1;
            #pragma unroll
            for (int i = 0; i < 4; i++) {
                int idx = tid + i * 128; int row = idx >> 3, ko = (idx & 7) * 8;
                *(ushort8v*)(&Ks[nb][row * KP + ko]) = kR[i];
            }
            #pragma unroll
            for (int i = 0; i < 4; i++) {
                int ko = (w + 2 * i) * 8;
                #pragma unroll
                for (int e = 0; e < 8; e++)
                    Vt[nb][(ko + e) * VP + lane] = vR[i][e];
            }
            if (tid < 64) Ms[nb][tid] = (1.0f - mR) * -10000.0f;
        }
        __syncthreads();   // tile t fully consumed by all waves; tile t+1 staged
    }

    // ---- normalize + write back into q-slot ----
    #pragma unroll
    for (int r = 0; r < 4; r++) {
        float inv = 1.0f / l_run[r];
        int row = b * SS + qt * 32 + w * 16 + q4 * 4 + r;
        size_t ob = (size_t)row * E3 + h * HD;
        #pragma unroll
        for (int df = 0; df < 4; df++)
            qkv[ob + df * 16 + ln16] = f2bfbits(oacc[df][r] * inv);
    }
}

// =================================================================================
// Legacy fast-path MFMA GEMM (f32 weights converted in-kernel) — fallback only.
// =================================================================================
template <int AMODE, int FUSE>
__global__ void gemm_mfma(const void* __restrict__ Aptr, int lda,
                          const float* __restrict__ W, int ldw,
                          const float* __restrict__ bias,
                          const float2* __restrict__ musig,
                          const float* __restrict__ lng, const float* __restrict__ lnb,
                          void* __restrict__ Cptr, int ldc, int K) {
    __shared__ unsigned short As[128 * 40];
    __shared__ unsigned short Bs[32 * 130];

    int tid = threadIdx.x;
    int bm = blockIdx.y * 128, bn = blockIdx.x * 128;
    int w = tid >> 6, lane = tid & 63, ln16 = lane & 15, q = lane >> 4;
    int wm = (w & 1) * 64, wn = (w >> 1) * 64;

    f32x4 acc[4][4];
    #pragma unroll
    for (int i = 0; i < 4; i++)
        #pragma unroll
        for (int j = 0; j < 4; j++) acc[i][j] = (f32x4){0.f, 0.f, 0.f, 0.f};

    for (int k0 = 0; k0 < K; k0 += 32) {
        if (AMODE == 0) {
            const unsigned short* A = (const unsigned short*)Aptr;
            #pragma unroll
            for (int i = 0; i < 2; i++) {
                int idx = tid + i * 256;
                int row = idx >> 2, ko = (idx & 3) * 8;
                ushort8v v = *(const ushort8v*)(A + (size_t)(bm + row) * lda + k0 + ko);
                *(ushort8v*)(&As[row * 40 + ko]) = v;
            }
        } else {
            const float* A = (const float*)Aptr;
            #pragma unroll
            for (int i = 0; i < 4; i++) {
                int idx = tid + i * 256;
                int row = idx >> 3, ko = (idx & 7) * 4;
                float4 xv = *(const float4*)(A + (size_t)(bm + row) * lda + k0 + ko);
                float2 ms = musig[bm + row];
                float4 gv = *(const float4*)(lng + k0 + ko);
                float4 bv = *(const float4*)(lnb + k0 + ko);
                ushort4v o;
                o[0] = f2bfbits((xv.x - ms.x) * ms.y * gv.x + bv.x);
                o[1] = f2bfbits((xv.y - ms.x) * ms.y * gv.y + bv.y);
                o[2] = f2bfbits((xv.z - ms.x) * ms.y * gv.z + bv.z);
                o[3] = f2bfbits((xv.w - ms.x) * ms.y * gv.w + bv.w);
                *(ushort4v*)(&As[row * 40 + ko]) = o;
            }
        }
        #pragma unroll
        for (int i = 0; i < 16; i++) {
            int idx = tid + i * 256;
            int kr = idx >> 7, n = idx & 127;
            float wv = W[(size_t)(k0 + kr) * ldw + bn + n];
            Bs[kr * 130 + n] = f2bfbits(wv);
        }
        __syncthreads();

        short8v afr[4], bfr[4];
        #pragma unroll
        for (int i = 0; i < 4; i++)
            afr[i] = *(const short8v*)(&As[(wm + i * 16 + ln16) * 40 + q * 8]);
        #pragma unroll
        for (int j = 0; j < 4; j++) {
            int n = wn + j * 16 + ln16;
            #pragma unroll
            for (int jj = 0; jj < 8; jj++)
                bfr[j][jj] = (short)Bs[(q * 8 + jj) * 130 + n];
        }
        #pragma unroll
        for (int i = 0; i < 4; i++)
            #pragma unroll
            for (int j = 0; j < 4; j++)
                acc[i][j] = __builtin_amdgcn_mfma_f32_16x16x32_bf16(afr[i], bfr[j], acc[i][j], 0, 0, 0);
        __syncthreads();
    }

    #pragma unroll
    for (int j = 0; j < 4; j++) {
        int col = bn + wn + j * 16 + ln16;
        float bv = (FUSE == 3) ? 0.f : bias[col];
        #pragma unroll
        for (int i = 0; i < 4; i++) {
            #pragma unroll
            for (int r = 0; r < 4; r++) {
                int row = bm + wm + i * 16 + q * 4 + r;
                float v = acc[i][j][r] + bv;
                if (FUSE == 1) v = 0.5f * v * (1.0f + erff(v * 0.70710678118654752f));
                if (FUSE == 0 || FUSE == 1) {
                    ((unsigned short*)Cptr)[(size_t)row * ldc + col] = f2bfbits(v);
                } else {
                    float* C = (float*)Cptr;
                    C[(size_t)row * ldc + col] += v;
                }
            }
        }
    }
}

// =================================================================================
// Legacy VALU flash attention (used by middle fallback path)
// =================================================================================
__global__ void attn_flash(unsigned short* __restrict__ qkv,
                           const float* __restrict__ mask) {
    __shared__ float Qs[32][68];
    __shared__ float Ks[64][68];
    __shared__ float Vs[64][68];
    __shared__ float Ps[32][68];

    int bid = blockIdx.x;                 // b(2) x h(12) x qt(32)
    int qt = bid & 31;
    int h  = (bid >> 5) % NH;
    int b  = bid / (32 * NH);
    int tid = threadIdx.x;
    int ql = tid >> 3, grp = tid & 7;

    #pragma unroll
    for (int i = 0; i < 8; i++) {
        int idx = tid + i * 256;
        int rq = idx >> 6, d = idx & 63;
        int grow = b * SS + qt * 32 + rq;
        Qs[rq][d] = bfr2f(qkv[(size_t)grow * E3 + h * HD + d]) * 0.125f;
    }

    float m_run = -1e30f, l_run = 0.f;
    float O[8] = {0.f, 0.f, 0.f, 0.f, 0.f, 0.f, 0.f, 0.f};

    for (int c = 0; c < 16; c++) {
        int j0 = c * 64;
        #pragma unroll
        for (int i = 0; i < 4; i++) {
            int idx = tid + i * 256;
            int jj = idx >> 4, d4 = (idx & 15) * 4;
            size_t base = (size_t)(b * SS + j0 + jj) * E3 + h * HD + d4;
            ushort4v kv = *(const ushort4v*)(qkv + base + E);
            ushort4v vv = *(const ushort4v*)(qkv + base + 2 * E);
            *(float4*)&Ks[jj][d4] = make_float4(bfr2f(kv[0]), bfr2f(kv[1]), bfr2f(kv[2]), bfr2f(kv[3]));
            *(float4*)&Vs[jj][d4] = make_float4(bfr2f(vv[0]), bfr2f(vv[1]), bfr2f(vv[2]), bfr2f(vv[3]));
        }
        __syncthreads();

        float s[8] = {0.f, 0.f, 0.f, 0.f, 0.f, 0.f, 0.f, 0.f};
        #pragma unroll
        for (int d0 = 0; d0 < 64; d0 += 4) {
            float4 q4 = *(const float4*)&Qs[ql][d0];
            #pragma unroll
            for (int jl = 0; jl < 8; jl++) {
                float4 k4 = *(const float4*)&Ks[grp + jl * 8][d0];
                s[jl] += q4.x * k4.x + q4.y * k4.y + q4.z * k4.z + q4.w * k4.w;
            }
        }
        #pragma unroll
        for (int jl = 0; jl < 8; jl++)
            s[jl] += (1.0f - mask[b * SS + j0 + grp + jl * 8]) * -10000.0f;

        float cm = s[0];
        #pragma unroll
        for (int jl = 1; jl < 8; jl++) cm = fmaxf(cm, s[jl]);
        cm = fmaxf(cm, __shfl_xor(cm, 1, 64));
        cm = fmaxf(cm, __shfl_xor(cm, 2, 64));
        cm = fmaxf(cm, __shfl_xor(cm, 4, 64));

        float mnew = fmaxf(m_run, cm);
        float alpha = __expf(m_run - mnew);
        float ps = 0.f;
        #pragma unroll
        for (int jl = 0; jl < 8; jl++) {
            float p = __expf(s[jl] - mnew);
            Ps[ql][grp + jl * 8] = p;
            ps += p;
        }
        ps += __shfl_xor(ps, 1, 64);
        ps += __shfl_xor(ps, 2, 64);
        ps += __shfl_xor(ps, 4, 64);
        l_run = l_run * alpha + ps;
        m_run = mnew;
        #pragma unroll
        for (int e = 0; e < 8; e++) O[e] *= alpha;

        #pragma unroll 4
        for (int jj = 0; jj < 64; jj++) {
            float p = Ps[ql][jj];
            float4 v0 = *(const float4*)&Vs[jj][grp * 8];
            float4 v1 = *(const float4*)&Vs[jj][grp * 8 + 4];
            O[0] += p * v0.x; O[1] += p * v0.y; O[2] += p * v0.z; O[3] += p * v0.w;
            O[4] += p * v1.x; O[5] += p * v1.y; O[6] += p * v1.z; O[7] += p * v1.w;
        }
        __syncthreads();
    }

    float inv = 1.0f / l_run;
    int grow = b * SS + qt * 32 + ql;
    size_t obase = (size_t)grow * E3 + h * HD + grp * 8;
    #pragma unroll
    for (int e = 0; e < 8; e++)
        qkv[obase + e] = f2bfbits(O[e] * inv);
}

// =================================================================================
// Legacy (R4-proven) kernels — deep fallback if workspace is tiny
// =================================================================================
template <int FUSE, typename CT>
__global__ void gemm_legacy(const __hip_bfloat16* __restrict__ A, int lda,
                            const float* __restrict__ W, int ldw,
                            const float* __restrict__ bias,
                            CT* __restrict__ C, int ldc,
                            const float* __restrict__ resid,
                            int M, int N, int K) {
    __shared__ float As[16][65];
    __shared__ float Bs[16][65];
    int bm = blockIdx.y * 64, bn = blockIdx.x * 64;
    int tid = threadIdx.x;
    int ty = tid >> 4, tx = tid & 15;
    int ar = tid >> 2, ak = (tid & 3) << 2;
    int wk = tid >> 4, wn = (tid & 15) << 2;

    float acc[4][4] = {};
    for (int k0 = 0; k0 < K; k0 += 16) {
        ushort4 av = *(const ushort4*)(A + (size_t)(bm + ar) * lda + k0 + ak);
        As[ak + 0][ar] = bfr2f(av.x);
        As[ak + 1][ar] = bfr2f(av.y);
        As[ak + 2][ar] = bfr2f(av.z);
        As[ak + 3][ar] = bfr2f(av.w);
        float4 wv = *(const float4*)(W + (size_t)(k0 + wk) * ldw + bn + wn);
        Bs[wk][wn + 0] = wv.x;
        Bs[wk][wn + 1] = wv.y;
        Bs[wk][wn + 2] = wv.z;
        Bs[wk][wn + 3] = wv.w;
        __syncthreads();
        #pragma unroll
        for (int kk = 0; kk < 16; kk++) {
            float a[4], bv[4];
            #pragma unroll
            for (int i = 0; i < 4; i++) { a[i] = As[kk][ty * 4 + i]; bv[i] = Bs[kk][tx * 4 + i]; }
            #pragma unroll
            for (int i = 0; i < 4; i++)
                #pragma unroll
                for (int j = 0; j < 4; j++) acc[i][j] += a[i] * bv[j];
        }
        __syncthreads();
    }
    #pragma unroll
    for (int i = 0; i < 4; i++) {
        int row = bm + ty * 4 + i;
        #pragma unroll
        for (int j = 0; j < 4; j++) {
            int col = bn + tx * 4 + j;
            float v = acc[i][j];
            if (FUSE != 3) v += bias[col];
            if (FUSE == 1) v = 0.5f * v * (1.0f + erff(v * 0.70710678118654752f));
            if (FUSE == 2 || FUSE == 3) v += resid[(size_t)row * ldc + col];
            if constexpr (sizeof(CT) == 2) C[(size_t)row * ldc + col] = f2bf(v);
            else                           C[(size_t)row * ldc + col] = v;
        }
    }
}

__global__ void attn_legacy(const __hip_bfloat16* __restrict__ qkv,
                            const float* __restrict__ mask,
                            __hip_bfloat16* __restrict__ out) {
    __shared__ float sc[SS];
    __shared__ float qv[HD];
    __shared__ float oacc[4][HD];
    __shared__ float redbuf[4];

    int q = blockIdx.x & (SS - 1);
    int h = blockIdx.x >> 10;
    int tid = threadIdx.x;

    const __hip_bfloat16* qrow = qkv + (size_t)q * E3 + h * HD;
    if (tid < HD) qv[tid] = bf2f(qrow[tid]) * 0.125f;
    __syncthreads();

    for (int j = tid; j < SS; j += 256) {
        const __hip_bfloat16* krow = qkv + (size_t)j * E3 + E + h * HD;
        float d = 0.f;
        #pragma unroll
        for (int t = 0; t < HD; t += 4) {
            ushort4 kv4 = *(const ushort4*)(krow + t);
            d += qv[t] * bfr2f(kv4.x) + qv[t + 1] * bfr2f(kv4.y)
               + qv[t + 2] * bfr2f(kv4.z) + qv[t + 3] * bfr2f(kv4.w);
        }
        d += (1.0f - mask[j]) * -10000.0f;
        sc[j] = d;
    }
    __syncthreads();

    float m = -1e30f;
    for (int j = tid; j < SS; j += 256) m = fmaxf(m, sc[j]);
    m = block_max(m, redbuf);
    float s = 0.f;
    for (int j = tid; j < SS; j += 256) { float e = __expf(sc[j] - m); sc[j] = e; s += e; }
    s = block_sum(s, redbuf);
    float inv = 1.0f / s;
    __syncthreads();

    int d = tid & 63, c = tid >> 6;
    float acc = 0.f;
    int j0 = c * 256;
    for (int j = j0; j < j0 + 256; j++) {
        const __hip_bfloat16* vrow = qkv + (size_t)j * E3 + 2 * E + h * HD;
        acc += sc[j] * bf2f(vrow[d]);
    }
    oacc[c][d] = acc;
    __syncthreads();
    if (tid < HD) {
        float o = (oacc[0][tid] + oacc[1][tid] + oacc[2][tid] + oacc[3][tid]) * inv;
        out[(size_t)q * E + h * HD + tid] = f2bf(o);
    }
}

__global__ void copy_kernel(const float* __restrict__ in, float* __restrict__ out, int n) {
    int i = blockIdx.x * 256 + threadIdx.x;
    if (i < n) out[i] = in[i];
}

// =================================================================================
extern "C" void kernel_launch(void* const* d_in, const int* in_sizes, int n_in,
                              void* d_out, int out_size, void* d_ws, size_t ws_size,
                              hipStream_t stream) {
    const float* emb   = (const float*)d_in[0];
    const float* mask  = (const float*)d_in[1];
    const float* Wqkv  = (const float*)d_in[2];
    const float* bqkv  = (const float*)d_in[3];
    const float* Wo    = (const float*)d_in[4];
    const float* bo    = (const float*)d_in[5];
    const float* ln1g  = (const float*)d_in[6];
    const float* ln1b  = (const float*)d_in[7];
    const float* ln2g  = (const float*)d_in[8];
    const float* ln2b  = (const float*)d_in[9];
    const float* Wfc   = (const float*)d_in[10];
    const float* bfc   = (const float*)d_in[11];
    const float* Wmo   = (const float*)d_in[12];
    const float* bmo   = (const float*)d_in[13];
    const float* lnfg  = (const float*)d_in[14];
    const float* lnfb  = (const float*)d_in[15];

    // FAST3: x + h + buf + ALL transposed weights (6 layers)
    const size_t NEED_FAST3 = sizeof(float) * (size_t)T * E
                            + 2ull * (size_t)T * E
                            + 2ull * (size_t)T * FFD
                            + 2ull * 6 * LSZ;                 // ~107 MB
    // FAST2: x + h + buf + one-weight scratch
    const size_t NEED_FAST2 = sizeof(float) * (size_t)T * E
                            + 2ull * (size_t)T * E
                            + 2ull * (size_t)T * FFD
                            + 2ull * (size_t)E * FFD;         // ~26.7 MB
    const size_t NEED_FAST = sizeof(float) * (size_t)T * E
                           + 2ull * (size_t)T * E3
                           + sizeof(float2) * (size_t)T;

    if (ws_size >= NEED_FAST2) {
        // ---------------- FAST2/FAST3: bf16 transposed weights + MFMA everything ----
        const bool allw = (ws_size >= NEED_FAST3);
        float* x            = (float*)d_ws;
        unsigned short* h   = (unsigned short*)(x + (size_t)T * E);       // [T,E]
        unsigned short* buf = h + (size_t)T * E;                          // [T,FFD] union
        unsigned short* wt  = buf + (size_t)T * FFD;                      // scratch / wt_all
        unsigned short* qkv = buf;                                        // [T,E3]
        unsigned short* ff  = buf;                                        // [T,FFD]

        copy4_kernel<<<dim3(T * E / 4 / 256), dim3(256), 0, stream>>>(
            (const float4*)emb, (float4*)x, T * E / 4);

        if (allw) {
            // one dispatch: transpose+convert all 24 weight matrices (64x64 tiles)
            transpose_all<<<dim3(6 * TL), dim3(256), 0, stream>>>(Wqkv, Wo, Wfc, Wmo, wt);
        }

        for (int l = 0; l < LYR; l++) {
            const float* wqkv_l = Wqkv + (size_t)l * E * E3;
            const float* wo_l   = Wo   + (size_t)l * E * E;
            const float* wfc_l  = Wfc  + (size_t)l * E * FFD;
            const float* wmo_l  = Wmo  + (size_t)l * FFD * E;

            const unsigned short* wq_t, *wo_t, *wfc_t, *wmo_t;
            if (allw) {
                const unsigned short* base = wt + (size_t)l * LSZ;
                wq_t  = base;
                wo_t  = base + SZ_QKV_T;
                wfc_t = base + SZ_QKV_T + SZ_WO_T;
                wmo_t = base + SZ_QKV_T + SZ_WO_T + SZ_WFC_T;
            } else {
                wq_t = wo_t = wfc_t = wmo_t = wt;   // reuse scratch sequentially
            }

            ln_kernel<__hip_bfloat16><<<dim3(T), dim3(256), 0, stream>>>(
                x, (__hip_bfloat16*)h, ln1g + l * E, ln1b + l * E);
            if (!allw)
                transpose_cvt<<<dim3(E3 / 32, E / 32), dim3(256), 0, stream>>>(wqkv_l, wt, E, E3);
            // QKV: 576 blocks x 8 waves
            gemm_bt<0><<<dim3(E3 / 128, T / 64), dim3(512), 0, stream>>>(
                h, E, wq_t, E, bqkv + l * E3, qkv, E3, E);
            // attention: 768 blocks x 2 waves, double-buffered
            attn_mfma<<<dim3(BB * NH * 32), dim3(128), 0, stream>>>(qkv, mask);
            if (!allw)
                transpose_cvt<<<dim3(E / 32, E / 32), dim3(256), 0, stream>>>(wo_l, wt, E, E);
            // Wo: split-K x4 -> 768 blocks x 8 waves (atomic residual add)
            gemm_bt<2><<<dim3(E / 128, T / 64, 4), dim3(512), 0, stream>>>(
                qkv, E3, wo_t, E, bo + l * E, x, E, E);

            ln_kernel<__hip_bfloat16><<<dim3(T), dim3(256), 0, stream>>>(
                x, (__hip_bfloat16*)h, ln2g + l * E, ln2b + l * E);
            if (!allw)
                transpose_cvt<<<dim3(FFD / 32, E / 32), dim3(256), 0, stream>>>(wfc_l, wt, E, FFD);
            // FC: 768 blocks x 8 waves
            gemm_bt<1><<<dim3(FFD / 128, T / 64), dim3(512), 0, stream>>>(
                h, E, wfc_t, E, bfc + l * FFD, ff, FFD, E);
            if (!allw)
                transpose_cvt<<<dim3(E / 32, FFD / 32), dim3(256), 0, stream>>>(wmo_l, wt, FFD, E);
            // Wmo: split-K x6 -> 1152 blocks x 8 waves (atomic residual add)
            gemm_bt<2><<<dim3(E / 128, T / 64, 6), dim3(512), 0, stream>>>(
                ff, FFD, wmo_t, FFD, bmo + l * E, x, E, FFD);
        }
        ln_kernel<float><<<dim3(T), dim3(256), 0, stream>>>(x, (float*)d_out, lnfg, lnfb);
    } else if (ws_size >= NEED_FAST) {
        // ---------------- FAST PATH (previous session, proven) ----------------
        float* x              = (float*)d_ws;
        unsigned short* qkv   = (unsigned short*)(x + (size_t)T * E);
        float2* musig         = (float2*)(qkv + (size_t)T * E3);

        copy4_kernel<<<dim3(T * E / 4 / 256), dim3(256), 0, stream>>>(
            (const float4*)emb, (float4*)x, T * E / 4);

        for (int l = 0; l < LYR; l++) {
            const float* wqkv_l = Wqkv + (size_t)l * E * E3;
            const float* wo_l   = Wo   + (size_t)l * E * E;
            const float* wfc_l  = Wfc  + (size_t)l * E * FFD;
            const float* wmo_l  = Wmo  + (size_t)l * FFD * E;

            rowstat_kernel<<<dim3(T), dim3(256), 0, stream>>>(x, musig);
            gemm_mfma<1, 0><<<dim3(E3 / 128, T / 128), dim3(256), 0, stream>>>(
                x, E, wqkv_l, E3, bqkv + l * E3, musig, ln1g + l * E, ln1b + l * E,
                qkv, E3, E);
            attn_flash<<<dim3(BB * NH * 32), dim3(256), 0, stream>>>(qkv, mask);
            gemm_mfma<0, 2><<<dim3(E / 128, T / 128), dim3(256), 0, stream>>>(
                qkv, E3, wo_l, E, bo + l * E, nullptr, nullptr, nullptr, x, E, E);

            unsigned short* ffp = qkv;
            unsigned short* hp  = qkv + (size_t)T * FH;
            ln_kernel<__hip_bfloat16><<<dim3(T), dim3(256), 0, stream>>>(
                x, (__hip_bfloat16*)hp, ln2g + l * E, ln2b + l * E);
            for (int f = 0; f < 2; f++) {
                gemm_mfma<0, 1><<<dim3(FH / 128, T / 128), dim3(256), 0, stream>>>(
                    hp, E, wfc_l + f * FH, FFD, bfc + l * FFD + f * FH,
                    nullptr, nullptr, nullptr, ffp, FH, E);
                if (f == 0)
                    gemm_mfma<0, 3><<<dim3(E / 128, T / 128), dim3(256), 0, stream>>>(
                        ffp, FH, wmo_l + (size_t)f * FH * E, E, nullptr, nullptr, nullptr, nullptr,
                        x, E, FH);
                else
                    gemm_mfma<0, 2><<<dim3(E / 128, T / 128), dim3(256), 0, stream>>>(
                        ffp, FH, wmo_l + (size_t)f * FH * E, E, bmo + l * E, nullptr, nullptr, nullptr,
                        x, E, FH);
            }
        }
        ln_kernel<float><<<dim3(T), dim3(256), 0, stream>>>(x, (float*)d_out, lnfg, lnfb);
    } else {
        // ---------------- LEGACY PATH (R4-proven, 12.58 MB) ----------------
        float* x           = (float*)d_ws;
        __hip_bfloat16* hb = (__hip_bfloat16*)(x + (size_t)T * E);
        __hip_bfloat16* qb = hb + (size_t)SS * E;

        int n = T * E;
        copy_kernel<<<dim3((n + 255) / 256), dim3(256), 0, stream>>>(emb, x, n);

        for (int l = 0; l < LYR; l++) {
            const float* wqkv_l = Wqkv + (size_t)l * E * E3;
            const float* wo_l   = Wo   + (size_t)l * E * E;
            const float* wfc_l  = Wfc  + (size_t)l * E * FFD;
            const float* wmo_l  = Wmo  + (size_t)l * FFD * E;

            for (int b = 0; b < BB; b++) {
                float* xb = x + (size_t)b * SS * E;
                ln_kernel<__hip_bfloat16><<<dim3(SS), dim3(256), 0, stream>>>(
                    xb, hb, ln1g + l * E, ln1b + l * E);
                gemm_legacy<0, __hip_bfloat16><<<dim3(E3 / 64, SS / 64), dim3(256), 0, stream>>>(
                    hb, E, wqkv_l, E3, bqkv + l * E3, qb, E3, nullptr, SS, E3, E);
                attn_legacy<<<dim3(NH * SS), dim3(256), 0, stream>>>(qb, mask + b * SS, hb);
                gemm_legacy<2, float><<<dim3(E / 64, SS / 64), dim3(256), 0, stream>>>(
                    hb, E, wo_l, E, bo + l * E, xb, E, xb, SS, E, E);
            }
            for (int b = 0; b < BB; b++) {
                float* xb = x + (size_t)b * SS * E;
                ln_kernel<__hip_bfloat16><<<dim3(SS), dim3(256), 0, stream>>>(
                    xb, hb, ln2g + l * E, ln2b + l * E);
                for (int f = 0; f < 2; f++) {
                    gemm_legacy<1, __hip_bfloat16><<<dim3(FH / 64, SS / 64), dim3(256), 0, stream>>>(
                        hb, E, wfc_l + f * FH, FFD, bfc + l * FFD + f * FH, qb, FH, nullptr,
                        SS, FH, E);
                    if (f == 0)
                        gemm_legacy<3, float><<<dim3(E / 64, SS / 64), dim3(256), 0, stream>>>(
                            qb, FH, wmo_l + (size_t)f * FH * E, E, nullptr, xb, E, xb, SS, E, FH);
                    else
                        gemm_legacy<2, float><<<dim3(E / 64, SS / 64), dim3(256), 0, stream>>>(
                            qb, FH, wmo_l + (size_t)f * FH * E, E, bmo + l * E, xb, E, xb, SS, E, FH);
                }
            }
        }
        ln_kernel<float><<<dim3(T), dim3(256), 0, stream>>>(x, (float*)d_out, lnfg, lnfb);
    }
}